// Round 9
// baseline (689.131 us; speedup 1.0000x reference)
//
#include <hip/hip_runtime.h>
#include <math.h>

// ---------------- problem constants ----------------
// T=16, NC=NQ=32, DW=256, DR=256, DZ=128, NH=8, F=1419
#define F_FEAT 1419
static constexpr float DN    = 0.25f;                 // 256^-0.25

typedef short short8 __attribute__((ext_vector_type(8)));
typedef float f32x4  __attribute__((ext_vector_type(4)));

// ---------------- workspace layout ----------------
// floats offsets unless noted "ush"
static constexpr long OFF_XDQ  = 0;                  // [4096][1419] f32 (performer phase, RAW)
static constexpr long OFF_XDK  = 5812224;            // [4096][1419] f32 (RAW)
static constexpr long U_WQH = 0;                     // W planes ush — POOL REGION: write only AFTER conv3m
static constexpr long U_WQL = 524288;
static constexpr long U_WKH = 1048576;
static constexpr long U_WKL = 1572864;
static constexpr long U_WVH = 2097152;
static constexpr long U_WVL = 2621440;               // ends ush 3,145,728
static constexpr long OFF_ENCT = 4000000;            // enc split-K temp: 8 x 262144 f32 (xd region, time-disjoint)
static constexpr long OFF_REPT = 6200000;            // rep split-K temp: 8 x 131072 f32 (xd dead by then)
static constexpr long OFF_PA   = 11624448;           // partial A: [128][4][1024] f32 (dead region after step 13)
static constexpr long U_PH  = 23248896;              // [1472][256] ush — POOL REGION: after conv3m
static constexpr long U_PL  = 23625728;
static constexpr long U_XCH = 24002560;              // [1024][256] ush — pool region, written step 5
static constexpr long U_XCL = 24264704;
static constexpr long U_RSH = 24526848;              // [512][256] ush
static constexpr long U_RSL = 24657920;
static constexpr long U_C3H = 25165824;              // [1024][4096] ush (starts at pool end)
static constexpr long U_C3L = 29360128;
static constexpr long U_WOH = 25165824;              // wo planes reuse C3 region after enc GEMM
static constexpr long U_WOL = 25690112;
static constexpr long BASE     = 16777216;
static constexpr long OFF_XCTX = BASE + 0;           // [1024][256] f32 (ctx rows 0..511, qry 512..1023)
static constexpr long OFF_XQRY = BASE + 131072;
static constexpr long OFF_XCAT = BASE + 262144;      // [512][320]
static constexpr long OFF_H1   = BASE + 425984;      // [512][256]
static constexpr long OFF_H2   = BASE + 557056;      // [512][256]
static constexpr long OFF_RS   = BASE + 688128;      // [512][256]
static constexpr long U_QH  = (BASE + 819200) * 2;   // Q planes ush
static constexpr long U_QL  = U_QH + 1048576;
static constexpr long U_KH  = (BASE + 1867776) * 2;  // K planes ush (Q->K stride 2,097,152 ush)
static constexpr long U_KL  = U_KH + 1048576;
static constexpr long OFF_VA   = BASE + 2916352;     // [8][512][256] f32
static constexpr long OFF_AW1  = BASE + 3964928;     // Aw1 (1024 ush)
static constexpr long U_ELH = (BASE + 3977344) * 2;  // EL planes ush (REPIN region); REP planes reuse
static constexpr long U_ELL = U_ELH + 1048576;
static constexpr long U_REPH = U_ELH;                // [512][2048] ush
static constexpr long U_REPL = U_ELL;
static constexpr long OFF_REP  = BASE + 5025920;     // [512][256]
static constexpr long OFF_XZ   = BASE + 5156992;     // [512][384]
static constexpr long OFF_DH1  = BASE + 5353600;     // [512][100]
static constexpr long OFF_DH2  = BASE + 5404800;     // [512][100]
static constexpr long OFF_MD   = BASE + 5456000;     // dq[4096] mqe[4096u] dk[4096] mke[128u] (dead Aw region)
static constexpr long OFF_AW   = 22233216;           // conv2 A-weights (13824 ush)
static constexpr long OFF_AW3  = 22240128;           // conv3 A-weights (73728 ush)

__device__ inline unsigned short f2bf(float f) {
    unsigned int x = __float_as_uint(f);
    unsigned int r = x + 0x7fffu + ((x >> 16) & 1u);
    return (unsigned short)(r >> 16);
}
__device__ inline float bf2f(unsigned short h) {
    return __uint_as_float((unsigned int)h << 16);
}
// packed RNE f32->bf16 pair: low16 = bf16(a), high16 = bf16(b)  (gfx950)
__device__ inline unsigned int cvtpk(float a, float b) {
    unsigned int r;
    asm("v_cvt_pk_bf16_f32 %0, %1, %2" : "=v"(r) : "v"(a), "v"(b));
    return r;
}
// monotonic f32 <-> u32 encoding for atomicMax over signed floats
__device__ inline unsigned encf(float f) {
    unsigned u = __float_as_uint(f);
    return (u & 0x80000000u) ? ~u : (u | 0x80000000u);
}
__device__ inline float decf(unsigned u) {
    return __uint_as_float((u & 0x80000000u) ? (u & 0x7fffffffu) : ~u);
}

// ============================================================
// Prep A (runs FIRST — only touches non-pool regions):
// Aw(conv2), Aw1(conv1), Aw3(conv3 hi/lo), EL planes.
// ============================================================
static constexpr int NA1 = 13824;                 // Aw
static constexpr int NA2 = NA1 + 1024;            // Aw1
static constexpr int NA3 = NA2 + 73728;           // Aw3
static constexpr int NA4 = NA3 + 1048576;         // EL

__global__ void k_wprepA(const float* __restrict__ w2, const float* __restrict__ w1,
                         const float* __restrict__ w3, const float* __restrict__ elw,
                         unsigned short* __restrict__ Aw, unsigned short* __restrict__ Aw1,
                         unsigned short* __restrict__ Aw3,
                         unsigned short* __restrict__ ELh, unsigned short* __restrict__ ELl)
{
    int i = blockIdx.x * 256 + threadIdx.x;
    if (i < NA1) {
        int ic  = i & 31;
        int m16 = (i >> 5) & 15;
        int emt = i >> 9;
        int mt  = emt % 3, e = emt / 3;
        Aw[i] = f2bf(w2[((mt * 16 + m16) * 32 + ic) * 9 + e]);
    } else if (i < NA2) {
        int j = i - NA1;
        int k = j & 31, m = (j >> 5) & 15, mt = j >> 9;
        Aw1[j] = (k < 9) ? f2bf(w1[(mt * 16 + m) * 9 + k]) : (unsigned short)0;
    } else if (i < NA3) {
        int j = i - NA2;
        int k  = j & 63;
        int m  = (j >> 6) & 15;
        int hl = (j >> 10) & 1;
        int mt = (j >> 11) & 3;
        int e  = j >> 13;
        unsigned short v = 0;
        if (k < 48) {
            float w = w3[((mt * 16 + m) * 48 + k) * 9 + e];
            unsigned short hi = f2bf(w);
            v = hl == 0 ? hi : f2bf(w - bf2f(hi));
        }
        Aw3[j] = v;
    } else if (i < NA4) {
        int j = i - NA3;
        float v = elw[j];
        unsigned short h = f2bf(v);
        ELh[j] = h; ELl[j] = f2bf(v - bf2f(h));
    }
}

// ============================================================
// Prep B (runs AFTER conv3m — targets live in the then-dead pool region):
// P planes (padded to 1472 rows), WQ/WK/WV planes.
// ============================================================
static constexpr int NB1 = 376832;                // P
static constexpr int NB2 = NB1 + 1572864;         // WQ/WK/WV

__global__ void k_wprepB(const float* __restrict__ proj,
                         const float* __restrict__ wq, const float* __restrict__ wk,
                         const float* __restrict__ wv,
                         unsigned short* __restrict__ Ph, unsigned short* __restrict__ Pl,
                         unsigned short* __restrict__ Wqkv)
{
    int i = blockIdx.x * 256 + threadIdx.x;
    if (i < NB1) {
        float v = (i < 363264) ? proj[i] : 0.f;
        unsigned short h = f2bf(v);
        Ph[i] = h; Pl[i] = f2bf(v - bf2f(h));
    } else if (i < NB2) {
        int j = i - NB1;
        int y = j / 524288, jj = j % 524288;
        const float* s = (y == 0) ? wq : (y == 1) ? wk : wv;
        float v = s[jj];
        unsigned short h = f2bf(v);
        Wqkv[(long)y * 1048576 + jj] = h;
        Wqkv[(long)y * 1048576 + 524288 + jj] = f2bf(v - bf2f(h));
    }
}

// ============================================================
// Fused conv1 (MFMA, LDS-staged im2col) -> bf16 ring -> conv2 MFMA
// -> bias/relu/maxpool (LDS scratch exchange) -> bf16 hi/lo pool.
// R8: SAME block work/LDS as R7, but 512 threads (8 waves): conv1's 36
// (slice x px-group) units round-robin over waves; conv2 wave = one
// conv2 row x half. LDS 52688 B -> 3 blocks/CU -> 24 waves/CU (75%)
// vs 12 — the kernel is latency-bound with 85% stalled issue slots;
// this doubles latency-hiding with ZERO extra per-block overhead
// (unlike R2's smaller-block attempt, which scaled overhead up).
// ============================================================
#define TP 136
__launch_bounds__(512)
__global__ void k_conv12m(const float* __restrict__ train, const float* __restrict__ test,
                          const float* __restrict__ b1,
                          const unsigned short* __restrict__ Aw,
                          const unsigned short* __restrict__ Aw1,
                          const float* __restrict__ b2,
                          unsigned short* __restrict__ pool_out)
{
    const int g   = blockIdx.x;    // 0..7 (pool rows 2g, 2g+1; conv2 rows 4g..4g+3)
    const int img = blockIdx.y;
    const float* in = (img < 512) ? (train + (long)img * 16384)
                                  : (test  + (long)(img - 512) * 16384);

    __shared__ unsigned short ring[9 * 66 * 40];   // 47520 B
    __shared__ unsigned short tile[19 * TP];       // 5168 B: input rows 16g-3..16g+15
    float* scratch = (float*)ring;                 // epilogue alias (26.6 KB used)

    const int t = threadIdx.x;

    if (t < 9 * 40) {
        int sl = t / 40, icp = t % 40;
        ring[(sl * 66 + 0) * 40 + icp] = 0;
    }
    if (g == 0)
        for (int i = t; i < 66 * 40; i += 512) ring[i] = 0;
    // zero the left halo (cols -2,-1 at tc 2,3) for all 19 rows
    if (t >= 64 && t < 83) *(unsigned int*)&tile[(t - 64) * TP + 2] = 0u;

    // ---- stage: 19 rows x 32 float4 (cols 0..127), packed bf16 ----
    {
        const float4 z4 = make_float4(0.f, 0.f, 0.f, 0.f);
        for (int u = t; u < 19 * 32; u += 512) {
            int row = u >> 5, k = u & 31;
            int r2 = 16 * g - 3 + row;             // never > 127
            float4 v = (r2 >= 0) ? *(const float4*)(in + r2 * 128 + k * 4) : z4;
            uint2 d;
            d.x = cvtpk(v.x, v.y);
            d.y = cvtpk(v.z, v.w);
            *(uint2*)&tile[row * TP + 4 + k * 4] = d;   // tc = c+4, 8B aligned
        }
    }
    __syncthreads();

    const int w    = t >> 6;       // 0..7
    const int lane = t & 63;
    const int cn   = lane & 15;
    const int quad = lane >> 4;

    // conv1 A-frags + per-lane biases (vector loads)
    short8 a1f0 = *(const short8*)&Aw1[(0 * 16 + cn) * 32 + quad * 8];
    short8 a1f1 = *(const short8*)&Aw1[(16 + cn) * 32 + quad * 8];
    float4 bsa = *(const float4*)&b1[quad * 4];
    float4 bsb = *(const float4*)&b1[16 + quad * 4];

    // ---- conv1 via MFMA: 36 units (slice sl 0..8, px-group pg 0..3)
    //      round-robin across 8 waves; slice sl = conv1 row 8g+sl-1 ----
    auto do_slice = [&](int sl, int px2) {
        const int rb = 2 * sl * TP + 2 * px2 + 2;
        uint4 pk = make_uint4(0u, 0u, 0u, 0u);
        if (quad == 0) {
            unsigned int w00 = *(const unsigned int*)&tile[rb];
            unsigned int w10 = *(const unsigned int*)&tile[rb + 2];
            unsigned int w01 = *(const unsigned int*)&tile[rb + TP];
            unsigned int w11 = *(const unsigned int*)&tile[rb + TP + 2];
            unsigned int w02 = *(const unsigned int*)&tile[rb + 2 * TP];
            unsigned int w12 = *(const unsigned int*)&tile[rb + 2 * TP + 2];
            pk.x = (w00 >> 16) | (w10 << 16);              // taps (0,0),(0,1)
            pk.y = (w10 >> 16) | (w01 & 0xffff0000u);      // taps (0,2),(1,0)
            pk.z = w11;                                    // taps (1,1),(1,2)
            pk.w = (w02 >> 16) | (w12 << 16);              // taps (2,0),(2,1)
        } else if (quad == 1) {
            pk.x = (*(const unsigned int*)&tile[rb + 2 * TP + 2]) >> 16;  // tap (2,2)
        }                                          // quads 2,3: taps 16..31 zero
        short8 bfr = *(const short8*)&pk;
        f32x4 z = (f32x4){0.f, 0.f, 0.f, 0.f};
        f32x4 c0 = __builtin_amdgcn_mfma_f32_16x16x32_bf16(a1f0, bfr, z, 0, 0, 0);
        f32x4 c1 = __builtin_amdgcn_mfma_f32_16x16x32_bf16(a1f1, bfr, z, 0, 0, 0);
        uint2 u0, u1;
        u0.x = cvtpk(fmaxf(c0[0] + bsa.x, 0.f), fmaxf(c0[1] + bsa.y, 0.f));
        u0.y = cvtpk(fmaxf(c0[2] + bsa.z, 0.f), fmaxf(c0[3] + bsa.w, 0.f));
        u1.x = cvtpk(fmaxf(c1[0] + bsb.x, 0.f), fmaxf(c1[1] + bsb.y, 0.f));
        u1.y = cvtpk(fmaxf(c1[2] + bsb.z, 0.f), fmaxf(c1[3] + bsb.w, 0.f));
        *(uint2*)&ring[(sl * 66 + px2 + 1) * 40 + quad * 4]      = u0;
        *(uint2*)&ring[(sl * 66 + px2 + 1) * 40 + 16 + quad * 4] = u1;
    };
    for (int u = w; u < 36; u += 8) {
        int sl = u >> 2, pg = u & 3;
        if (!(g == 0 && sl == 0)) do_slice(sl, pg * 16 + cn);
    }
    __syncthreads();

    // ---- conv2 MFMA: wave w -> conv2 row cr=w>>1 (local 0..3), half xh=w&1 ----
    const int cr = w >> 1, xh = w & 1;
    f32x4 acc[3];
    acc[0] = acc[1] = acc[2] = (f32x4){0.f, 0.f, 0.f, 0.f};

    #pragma unroll
    for (int e = 0; e < 9; e++) {
        int dy = e / 3, dx = e - 3 * dy;
        short8 a0 = *(const short8*)&Aw[((e * 3 + 0) * 16 + cn) * 32 + quad * 8];
        short8 a1 = *(const short8*)&Aw[((e * 3 + 1) * 16 + cn) * 32 + quad * 8];
        short8 a2 = *(const short8*)&Aw[((e * 3 + 2) * 16 + cn) * 32 + quad * 8];
        int c  = 2 * (xh * 16 + cn) + dx;
        short8 bfr = *(const short8*)&ring[((2 * cr + dy) * 66 + c) * 40 + quad * 8];
        acc[0] = __builtin_amdgcn_mfma_f32_16x16x32_bf16(a0, bfr, acc[0], 0, 0, 0);
        acc[1] = __builtin_amdgcn_mfma_f32_16x16x32_bf16(a1, bfr, acc[1], 0, 0, 0);
        acc[2] = __builtin_amdgcn_mfma_f32_16x16x32_bf16(a2, bfr, acc[2], 0, 0, 0);
    }
    __syncthreads();   // all ring reads done -> safe to alias as scratch

    #pragma unroll
    for (int mt = 0; mt < 3; mt++) {
        float4 bv = *(const float4*)&b2[mt * 16 + quad * 4];
        int x = xh * 16 + cn;
        float* sr = &scratch[(cr * 32 + x) * 52 + mt * 16 + quad * 4];
        sr[0] = fmaxf(acc[mt][0] + bv.x, 0.f);
        sr[1] = fmaxf(acc[mt][1] + bv.y, 0.f);
        sr[2] = fmaxf(acc[mt][2] + bv.z, 0.f);
        sr[3] = fmaxf(acc[mt][3] + bv.w, 0.f);
    }
    __syncthreads();

    for (int i = t; i < 1536; i += 512) {
        int oc = i % 48; int pp = i / 48; int px = pp & 15, pr = pp >> 4;
        const float* b0 = &scratch[((2 * pr) * 32 + 2 * px) * 52 + oc];
        float m = fmaxf(fmaxf(b0[0], b0[52]), fmaxf(b0[32 * 52], b0[33 * 52]));
        unsigned short hi = f2bf(m);
        unsigned short lo = f2bf(m - bf2f(hi));
        long base = ((long)img * 256 + (2 * g + pr) * 16 + px) * 96;
        pool_out[base + oc] = hi;
        pool_out[base + 48 + oc] = lo;
    }
}

// ============================================================
// conv3 via MFMA hi/lo -> bf16 hi/lo planes [1024][4096]
// ============================================================
#define C3PITCH 104
__launch_bounds__(512)
__global__ void k_conv3m(const unsigned short* __restrict__ pool,
                         const unsigned short* __restrict__ Aw3,
                         const float* __restrict__ b3,
                         unsigned short* __restrict__ C3h, unsigned short* __restrict__ C3l)
{
    const int img = blockIdx.x;
    __shared__ unsigned short s_in[30120];
    const int t = threadIdx.x;

    uint4* s4 = (uint4*)s_in;
    const uint4 zz = make_uint4(0, 0, 0, 0);
    for (int i = t; i < 3765; i += 512) s4[i] = zz;
    __syncthreads();
    {
        int p = t >> 1, half = t & 1;
        const uint4* src = (const uint4*)(pool + ((long)img * 256 + p) * 96 + half * 48);
        int r = p >> 4, c = p & 15;
        uint4* dst = (uint4*)(s_in + ((r + 1) * 17 + (c + 1)) * C3PITCH + half * 48);
        #pragma unroll
        for (int j = 0; j < 6; j++) dst[j] = src[j];
    }
    __syncthreads();

    const int w = t >> 6, lane = t & 63;
    const int n = lane & 15, quad = lane >> 4;
    const int mt = w >> 1, ntb = (w & 1) * 2;

    f32x4 acc[2];
    acc[0] = (f32x4){0.f, 0.f, 0.f, 0.f};
    acc[1] = (f32x4){0.f, 0.f, 0.f, 0.f};

    for (int e = 0; e < 9; e++) {
        int dy = e / 3, dx = e - 3 * dy;
        const unsigned short* A0 = Aw3 + (long)(((e * 4 + mt) * 2 + 0) * 16 + n) * 64 + quad * 8;
        const unsigned short* A1 = Aw3 + (long)(((e * 4 + mt) * 2 + 1) * 16 + n) * 64 + quad * 8;
        short8 ah0 = *(const short8*)(A0);
        short8 ah1 = *(const short8*)(A0 + 32);
        short8 al0 = *(const short8*)(A1);
        short8 al1 = *(const short8*)(A1 + 32);
        #pragma unroll
        for (int j = 0; j < 2; j++) {
            int p = (ntb + j) * 16 + n;
            int y = p >> 3, x = p & 7;
            const unsigned short* Bp = s_in + ((2 * y + dy) * 17 + (2 * x + dx)) * C3PITCH + quad * 8;
            short8 bh0 = *(const short8*)(Bp);
            short8 bh1 = *(const short8*)(Bp + 32);
            short8 bl0 = *(const short8*)(Bp + 48);
            short8 bl1 = *(const short8*)(Bp + 48 + 32);
            acc[j] = __builtin_amdgcn_mfma_f32_16x16x32_bf16(ah0, bh0, acc[j], 0, 0, 0);
            acc[j] = __builtin_amdgcn_mfma_f32_16x16x32_bf16(ah1, bh1, acc[j], 0, 0, 0);
            acc[j] = __builtin_amdgcn_mfma_f32_16x16x32_bf16(ah0, bl0, acc[j], 0, 0, 0);
            acc[j] = __builtin_amdgcn_mfma_f32_16x16x32_bf16(ah1, bl1, acc[j], 0, 0, 0);
            acc[j] = __builtin_amdgcn_mfma_f32_16x16x32_bf16(al0, bh0, acc[j], 0, 0, 0);
            acc[j] = __builtin_amdgcn_mfma_f32_16x16x32_bf16(al1, bh1, acc[j], 0, 0, 0);
        }
    }

    unsigned short* oh = C3h + (long)img * 4096;
    unsigned short* ol = C3l + (long)img * 4096;
    #pragma unroll
    for (int reg = 0; reg < 4; reg++) {
        int oc = mt * 16 + quad * 4 + reg;
        float bias = b3[oc];
        #pragma unroll
        for (int j = 0; j < 2; j++) {
            int p = (ntb + j) * 16 + n;
            float v = fmaxf(acc[j][reg] + bias, 0.f);
            unsigned short h = f2bf(v);
            oh[oc * 64 + p] = h;
            ol[oc * 64 + p] = f2bf(v - bf2f(h));
        }
    }
}

// ============================================================
// bf16 hi/lo MFMA GEMM (3-term, ~fp32). OUTMODE 0: f32 out (z-batch over
// X/W/B/Y strides); 1: hi/lo plane out (z-batch); 3: split-K chunks;
// 5: f32 out + fused max (z=0: per-row -> mqe; z=1: per-32row-tile -> mke).
// ============================================================
template<int OUTMODE>
__launch_bounds__(256)
__global__ void mgemm(const unsigned short* __restrict__ Xh0, const unsigned short* __restrict__ Xl0,
                      const unsigned short* __restrict__ Wph, const unsigned short* __restrict__ Wpl,
                      const float* __restrict__ Bb, float* __restrict__ Yf,
                      unsigned short* __restrict__ Yh, unsigned short* __restrict__ Yl,
                      int M, int N, int K, int ldY, float scale,
                      long sX, long sW, long sB, long sY, int kChunk,
                      unsigned* __restrict__ mqe, unsigned* __restrict__ mke)
{
    const int z = blockIdx.z;
    const unsigned short* Xh = Xh0 + (OUTMODE == 3 ? 0 : (long)z * sX);
    const unsigned short* Xl = Xl0 + (OUTMODE == 3 ? 0 : (long)z * sX);
    const unsigned short* Wh = Wph + (OUTMODE == 3 ? 0 : (long)z * sW);
    const unsigned short* Wl = Wpl + (OUTMODE == 3 ? 0 : (long)z * sW);
    const float* B = Bb ? (Bb + (OUTMODE == 3 ? 0 : (long)z * sB)) : nullptr;
    int k0 = 0, k1 = K;
    if (OUTMODE == 3) { k0 = z * kChunk; k1 = min(K, k0 + kChunk); }

    __shared__ unsigned short sAh[64 * 40], sAl[64 * 40], sBh[64 * 40], sBl[64 * 40];

    const int t = threadIdx.x;
    const int m0 = blockIdx.y * 64, n0 = blockIdx.x * 64;
    const int r = t >> 2, kq = (t & 3) * 8;

    const int w = t >> 6, lane = t & 63;
    const int wm = (w & 1) * 32, wn = (w >> 1) * 32;
    const int cn = lane & 15, quad = lane >> 4;

    f32x4 acc[2][2];
    acc[0][0] = acc[0][1] = acc[1][0] = acc[1][1] = (f32x4){0.f, 0.f, 0.f, 0.f};

    for (int kb = k0; kb < k1; kb += 32) {
        *(uint4*)&sAh[r * 40 + kq] = *(const uint4*)&Xh[(long)(m0 + r) * K + kb + kq];
        *(uint4*)&sAl[r * 40 + kq] = *(const uint4*)&Xl[(long)(m0 + r) * K + kb + kq];
        *(uint4*)&sBh[r * 40 + kq] = *(const uint4*)&Wh[(long)(n0 + r) * K + kb + kq];
        *(uint4*)&sBl[r * 40 + kq] = *(const uint4*)&Wl[(long)(n0 + r) * K + kb + kq];
        __syncthreads();
        short8 axh[2], axl[2], bxh[2], bxl[2];
        #pragma unroll
        for (int i = 0; i < 2; i++) {
            axh[i] = *(const short8*)&sAh[(wm + i * 16 + cn) * 40 + quad * 8];
            axl[i] = *(const short8*)&sAl[(wm + i * 16 + cn) * 40 + quad * 8];
            bxh[i] = *(const short8*)&sBh[(wn + i * 16 + cn) * 40 + quad * 8];
            bxl[i] = *(const short8*)&sBl[(wn + i * 16 + cn) * 40 + quad * 8];
        }
        #pragma unroll
        for (int i = 0; i < 2; i++)
            #pragma unroll
            for (int j = 0; j < 2; j++) {
                acc[i][j] = __builtin_amdgcn_mfma_f32_16x16x32_bf16(axh[i], bxh[j], acc[i][j], 0, 0, 0);
                acc[i][j] = __builtin_amdgcn_mfma_f32_16x16x32_bf16(axh[i], bxl[j], acc[i][j], 0, 0, 0);
                acc[i][j] = __builtin_amdgcn_mfma_f32_16x16x32_bf16(axl[i], bxh[j], acc[i][j], 0, 0, 0);
            }
        __syncthreads();
    }

    float gmax = -3e38f;
    #pragma unroll
    for (int i = 0; i < 2; i++) {
        #pragma unroll
        for (int reg = 0; reg < 4; reg++) {
            int row = m0 + wm + i * 16 + quad * 4 + reg;
            float rmax = -3e38f;
            #pragma unroll
            for (int j = 0; j < 2; j++) {
                int col = n0 + wn + j * 16 + cn;
                if (col >= N) continue;
                float v = acc[i][j][reg] * scale;
                if (OUTMODE == 3) {
                    (Yf + (long)z * sY)[(long)row * ldY + col] = v;
                } else if (OUTMODE == 0 || OUTMODE == 5) {
                    if (B) v += B[col];
                    (Yf + (long)z * sY)[(long)row * ldY + col] = v;
                    if (OUTMODE == 5) rmax = fmaxf(rmax, v);
                } else {
                    if (B) v += B[col];
                    unsigned short h = f2bf(v);
                    (Yh + (long)z * sY)[(long)row * ldY + col] = h;
                    (Yl + (long)z * sY)[(long)row * ldY + col] = f2bf(v - bf2f(h));
                }
            }
            if (OUTMODE == 5) {
                if (z == 0) {
                    rmax = fmaxf(rmax, __shfl_xor(rmax, 1));
                    rmax = fmaxf(rmax, __shfl_xor(rmax, 2));
                    rmax = fmaxf(rmax, __shfl_xor(rmax, 4));
                    rmax = fmaxf(rmax, __shfl_xor(rmax, 8));
                    if (cn == 0) atomicMax(&mqe[row], encf(rmax));
                } else {
                    gmax = fmaxf(gmax, rmax);
                }
            }
        }
    }
    if (OUTMODE == 5 && z == 1) {
        for (int d = 1; d < 64; d <<= 1) gmax = fmaxf(gmax, __shfl_xor(gmax, d));
        if (lane == 0) atomicMax(&mke[(m0 + wm) >> 5], encf(gmax));
    }
}

// ============================================================
// k_qkv: Q/K/V projections in ONE launch, grid (4, 8, 24).
// z 0..7 = Q heads (x_qry, planes out + diag), 8..15 = K heads (x_ctx,
// planes + diag), 16..23 = V heads (rs, f32 out). diag = sum(v^2)/32
// atomicAdd'd per token row (MD region zeroed in k_red_enc).
// ============================================================
__launch_bounds__(256)
__global__ void k_qkv(const unsigned short* __restrict__ XCh, const unsigned short* __restrict__ XCl,
                      const unsigned short* __restrict__ RSh, const unsigned short* __restrict__ RSl,
                      const unsigned short* __restrict__ Wqkv,
                      const float* __restrict__ wqb, const float* __restrict__ wkb,
                      const float* __restrict__ wvb,
                      unsigned short* __restrict__ Qh, unsigned short* __restrict__ Ql,
                      unsigned short* __restrict__ Kh, unsigned short* __restrict__ Kl,
                      float* __restrict__ v_all, float* __restrict__ dq, float* __restrict__ dk)
{
    const int z = blockIdx.z, y = z >> 3, zh = z & 7;
    const unsigned short* Xh = (y == 0) ? XCh + 512 * 256 : (y == 1) ? XCh : RSh;
    const unsigned short* Xl = (y == 0) ? XCl + 512 * 256 : (y == 1) ? XCl : RSl;
    const unsigned short* Wh = Wqkv + (long)y * 1048576 + (long)zh * 65536;
    const unsigned short* Wl = Wh + 524288;
    const float* B = ((y == 0) ? wqb : (y == 1) ? wkb : wvb) + zh * 256;

    __shared__ unsigned short sAh[64 * 40], sAl[64 * 40], sBh[64 * 40], sBl[64 * 40];

    const int t = threadIdx.x;
    const int m0 = blockIdx.y * 64, n0 = blockIdx.x * 64;
    const int r = t >> 2, kq = (t & 3) * 8;
    const int w = t >> 6, lane = t & 63;
    const int wm = (w & 1) * 32, wn = (w >> 1) * 32;
    const int cn = lane & 15, quad = lane >> 4;

    f32x4 acc[2][2];
    acc[0][0] = acc[0][1] = acc[1][0] = acc[1][1] = (f32x4){0.f, 0.f, 0.f, 0.f};

    for (int kb = 0; kb < 256; kb += 32) {
        *(uint4*)&sAh[r * 40 + kq] = *(const uint4*)&Xh[(long)(m0 + r) * 256 + kb + kq];
        *(uint4*)&sAl[r * 40 + kq] = *(const uint4*)&Xl[(long)(m0 + r) * 256 + kb + kq];
        *(uint4*)&sBh[r * 40 + kq] = *(const uint4*)&Wh[(long)(n0 + r) * 256 + kb + kq];
        *(uint4*)&sBl[r * 40 + kq] = *(const uint4*)&Wl[(long)(n0 + r) * 256 + kb + kq];
        __syncthreads();
        short8 axh[2], axl[2], bxh[2], bxl[2];
        #pragma unroll
        for (int i = 0; i < 2; i++) {
            axh[i] = *(const short8*)&sAh[(wm + i * 16 + cn) * 40 + quad * 8];
            axl[i] = *(const short8*)&sAl[(wm + i * 16 + cn) * 40 + quad * 8];
            bxh[i] = *(const short8*)&sBh[(wn + i * 16 + cn) * 40 + quad * 8];
            bxl[i] = *(const short8*)&sBl[(wn + i * 16 + cn) * 40 + quad * 8];
        }
        #pragma unroll
        for (int i = 0; i < 2; i++)
            #pragma unroll
            for (int j = 0; j < 2; j++) {
                acc[i][j] = __builtin_amdgcn_mfma_f32_16x16x32_bf16(axh[i], bxh[j], acc[i][j], 0, 0, 0);
                acc[i][j] = __builtin_amdgcn_mfma_f32_16x16x32_bf16(axh[i], bxl[j], acc[i][j], 0, 0, 0);
                acc[i][j] = __builtin_amdgcn_mfma_f32_16x16x32_bf16(axl[i], bxh[j], acc[i][j], 0, 0, 0);
            }
        __syncthreads();
    }

    unsigned short* Yh = ((y == 0) ? Qh : Kh) + (long)zh * 131072;
    unsigned short* Yl = ((y == 0) ? Ql : Kl) + (long)zh * 131072;
    float* Yf = v_all + (long)zh * 131072;
    float* dacc = ((y == 0) ? dq : dk) + zh * 512;

    #pragma unroll
    for (int i = 0; i < 2; i++) {
        #pragma unroll
        for (int reg = 0; reg < 4; reg++) {
            int row = m0 + wm + i * 16 + quad * 4 + reg;
            float s = 0.f;
            #pragma unroll
            for (int j = 0; j < 2; j++) {
                int col = n0 + wn + j * 16 + cn;
                float v = acc[i][j][reg] + B[col];
                if (y == 2) {
                    Yf[(long)row * 256 + col] = v;
                } else {
                    unsigned short h = f2bf(v);
                    Yh[(long)row * 256 + col] = h;
                    Yl[(long)row * 256 + col] = f2bf(v - bf2f(h));
                    s += v * v;
                }
            }
            if (y < 2) {
                s += __shfl_xor(s, 1); s += __shfl_xor(s, 2);
                s += __shfl_xor(s, 4); s += __shfl_xor(s, 8);
                if (cn == 0) atomicAdd(&dacc[row], s * (1.f / 32.f));
            }
        }
    }
}

// ============================================================
// reducers for split-K temps (fused with small jobs to cut launches)
// k_red_enc grid 3249: [0,1024) enc reduce; [1024,1152) label embed;
// [1152,3200) wo -> hi/lo planes; [3200,3249) zero MD (diag/max buffers).
// ============================================================
__global__ void k_red_enc(const float* __restrict__ tmp, const float* __restrict__ elb,
                          float* __restrict__ x_ctx, unsigned short* __restrict__ XCh,
                          unsigned short* __restrict__ XCl, float* __restrict__ xcat,
                          const float* __restrict__ label, const float* __restrict__ tyw,
                          const float* __restrict__ tyb,
                          const float* __restrict__ wow, unsigned short* __restrict__ WOh,
                          unsigned short* __restrict__ WOl, unsigned* __restrict__ md)
{
    int b = blockIdx.x;
    int tt = threadIdx.x;
    if (b < 1024) {
        int i = b * 256 + tt;                 // 262144
        int r = i >> 8, c = i & 255;
        float v = elb[c];
        #pragma unroll
        for (int z = 0; z < 8; z++) v += tmp[(long)z * 262144 + i];
        x_ctx[i] = v;
        unsigned short h = f2bf(v);
        XCh[i] = h; XCl[i] = f2bf(v - bf2f(h));
        if (r < 512) xcat[r * 320 + c] = v;
    } else if (b < 1152) {
        int i = (b - 1024) * 256 + tt;        // 32768
        int r = i >> 6, e = i & 63;
        xcat[r * 320 + 256 + e] = tyb[e] + label[r * 2] * tyw[e * 2] + label[r * 2 + 1] * tyw[e * 2 + 1];
    } else if (b < 3200) {
        int i = (b - 1152) * 256 + tt;        // 524288
        float v = wow[i];
        unsigned short h = f2bf(v);
        WOh[i] = h; WOl[i] = f2bf(v - bf2f(h));
    } else {
        int i = (b - 3200) * 256 + tt;        // 12416 (dq,mqe,dk,mke)
        if (i < 12416) md[i] = 0u;
    }
}

// k_red_rep grid 1024: [0,512) rep reduce (8 chunks); [512,1024) xz col copy.
__global__ void k_red_rep(const float* __restrict__ tmp, const float* __restrict__ wob,
                          float* __restrict__ rep,
                          const float* __restrict__ xq, float* __restrict__ xz)
{
    int b = blockIdx.x;
    int tt = threadIdx.x;
    if (b < 512) {
        int i = b * 256 + tt;                 // 131072
        int c = i & 255;
        float v = wob[c];
        #pragma unroll
        for (int z = 0; z < 8; z++) v += tmp[(long)z * 131072 + i];
        rep[i] = v;
    } else {
        int i = (b - 512) * 256 + tt;         // 131072
        int r = i >> 8, c = i & 255;
        xz[r * 384 + c] = xq[i];
    }
}

// ============================================================
// Generic fp32 GEMM (small layers), float2 inner loads.
// WP: also emit bf16 hi/lo planes of the output (used for rs).
// ============================================================
template<int BM, int BN, int BK, int ACT, bool FIN, bool WP>
__launch_bounds__(256)
__global__ void gemm_k(const float* __restrict__ X, const float* __restrict__ W,
                       const float* __restrict__ B, float* __restrict__ Y,
                       int M, int N, int K, int ldY,
                       unsigned short* __restrict__ Ph2, unsigned short* __restrict__ Pl2)
{
    __shared__ float As[BK][BM + 4];
    __shared__ float Bs[BK][BN + 4];
    const int t = threadIdx.x;
    const int tx = t & 15, ty = t >> 4;
    const int m0 = blockIdx.y * BM, n0 = blockIdx.x * BN;
    float acc[2][2] = {{0.f, 0.f}, {0.f, 0.f}};

    for (int kb = 0; kb < K; kb += BK) {
        for (int i = t; i < BM * BK; i += 256) {
            int rr = i / BK, c = i % BK;
            int mm = m0 + rr, kk = kb + c;
            As[c][rr] = (mm < M && kk < K) ? X[(long)mm * K + kk] : 0.f;
        }
        for (int i = t; i < BN * BK; i += 256) {
            int rr = i / BK, c = i % BK;
            int nn = n0 + rr, kk = kb + c;
            Bs[c][rr] = (nn < N && kk < K) ? W[(long)nn * K + kk] : 0.f;
        }
        __syncthreads();
        #pragma unroll
        for (int kk = 0; kk < BK; kk++) {
            float2 a2 = *(const float2*)&As[kk][ty * 2];
            float2 b2 = *(const float2*)&Bs[kk][tx * 2];
            acc[0][0] += a2.x * b2.x; acc[0][1] += a2.x * b2.y;
            acc[1][0] += a2.y * b2.x; acc[1][1] += a2.y * b2.y;
        }
        __syncthreads();
    }

    #pragma unroll
    for (int i = 0; i < 2; i++) {
        int mm = m0 + ty * 2 + i;
        if (mm >= M) continue;
        #pragma unroll
        for (int j = 0; j < 2; j++) {
            int nn = n0 + tx * 2 + j;
            if (nn >= N) continue;
            float v = acc[i][j] + (B ? B[nn] : 0.f);
            if (ACT == 1) v = fmaxf(v, 0.f);
            if (ACT == 2) v = tanhf(v);
            Y[(long)mm * ldY + nn] = v;
            if (WP) {
                unsigned short h = f2bf(v);
                Ph2[(long)mm * ldY + nn] = h;
                Pl2[(long)mm * ldY + nn] = f2bf(v - bf2f(h));
            }
        }
    }
    if (FIN && t == 0 && blockIdx.x == 0 && blockIdx.y == 0) Y[1024] = 0.f;
}

// ============================================================
// k_attn1: feature-split QK^T with fused exp. grid (NSPLIT=4, 128).
// Each block: features [s*355, min(1419,(s+1)*355)) of one (h,t) tile;
// partial A[32][32] -> pA[kb][s][1024]. LDS pitch 65 (conflict-free).
// shifts: dq + decode(mqe) per q-row; dk + decode(mke[kb]) per k-row.
// ============================================================
#define NSPLIT 4
#define FCH 355
__launch_bounds__(256)
__global__ void k_attn1(const float* __restrict__ qp, const float* __restrict__ kp,
                        const float* __restrict__ dq, const unsigned* __restrict__ mqe,
                        const float* __restrict__ dk, const unsigned* __restrict__ mke,
                        float* __restrict__ pA)
{
    const int s  = blockIdx.x;        // 0..3 feature split
    const int kb = blockIdx.y;        // 0..127 tile
    const long row0 = (long)kb * 32;
    const int f0 = s * FCH;
    const int f1 = min(F_FEAT, f0 + FCH);

    __shared__ float s_q[32 * 65];
    __shared__ float s_k[32 * 65];
    __shared__ float s_cq[32], s_ck[32];

    const int t = threadIdx.x;
    const int n = t >> 3;
    const int mq_ = (t & 7) * 4;

    if (t < 32) {
        s_cq[t] = dq[row0 + t] + decf(mqe[row0 + t]);
        s_ck[t] = dk[row0 + t] + decf(mke[kb]);
    }
    __syncthreads();

    float acc[4] = {0.f, 0.f, 0.f, 0.f};
    for (int fc = f0; fc < f1; fc += 64) {
        for (int i = t; i < 2048; i += 256) {
            int rr = i >> 6, ff = i & 63;
            int fg = fc + ff;
            float qv = 0.f, kv = 0.f;
            if (fg < f1) {
                qv = __expf(qp[(row0 + rr) * F_FEAT + fg] - s_cq[rr]) + 1e-4f;
                kv = __expf(kp[(row0 + rr) * F_FEAT + fg] - s_ck[rr]) + 1e-4f;
            }
            s_q[rr * 65 + ff] = qv;
            s_k[rr * 65 + ff] = kv;
        }
        __syncthreads();
        #pragma unroll 8
        for (int ff = 0; ff < 64; ff++) {
            float a = s_q[n * 65 + ff];
            #pragma unroll
            for (int j = 0; j < 4; j++) acc[j] += a * s_k[(mq_ + j) * 65 + ff];
        }
        __syncthreads();
    }

    float* dst = pA + ((long)kb * NSPLIT + s) * 1024;
    #pragma unroll
    for (int j = 0; j < 4; j++) dst[n * 32 + mq_ + j] = acc[j];
}

// ============================================================
// k_attn2: reduce partial A + rowsum + PV chunk -> REP planes.
// grid (4 e-chunks, 128 tiles).
// ============================================================
__launch_bounds__(256)
__global__ void k_attn2(const float* __restrict__ pA, const float* __restrict__ va,
                        unsigned short* __restrict__ REPh, unsigned short* __restrict__ REPl)
{
    const int ec = blockIdx.x;        // 0..3, 64 output cols each
    const int kb = blockIdx.y;        // 0..127
    const int h = kb >> 4, tt = kb & 15;
    const long row0 = (long)kb * 32;

    __shared__ float s_A[32][33];
    __shared__ float s_di[32];
    __shared__ float s_v[32 * 64];

    const int t = threadIdx.x;

    // reduce NSPLIT partials, 4 A-elements per thread (float4 loads)
    {
        const float* base = pA + (long)kb * NSPLIT * 1024 + t * 4;
        float4 v0 = *(const float4*)(base);
        float4 v1 = *(const float4*)(base + 1024);
        float4 v2 = *(const float4*)(base + 2048);
        float4 v3 = *(const float4*)(base + 3072);
        int r = t >> 3, c = (t & 7) * 4;
        s_A[r][c]     = v0.x + v1.x + v2.x + v3.x;
        s_A[r][c + 1] = v0.y + v1.y + v2.y + v3.y;
        s_A[r][c + 2] = v0.z + v1.z + v2.z + v3.z;
        s_A[r][c + 3] = v0.w + v1.w + v2.w + v3.w;
    }
    // stage V chunk (coalesced)
    for (int i = t; i < 2048; i += 256) {
        int m = i >> 6, e = i & 63;
        s_v[m * 64 + e] = va[row0 * 256 + m * 256 + ec * 64 + e];
    }
    __syncthreads();
    if (t < 32) {
        float s = 0.f;
        #pragma unroll
        for (int m = 0; m < 32; m++) s += s_A[t][m];
        s_di[t] = 1.f / s;
    }
    __syncthreads();

    const int n = t >> 3, e0 = t & 7;
    float out[8];
    #pragma unroll
    for (int j = 0; j < 8; j++) out[j] = 0.f;
    for (int m = 0; m < 32; m++) {
        float a = s_A[n][m];
        #pragma unroll
        for (int j = 0; j < 8; j++) out[j] += a * s_v[m * 64 + e0 + 8 * j];
    }
    float di = s_di[n];
    unsigned short* dsth = REPh + ((long)tt * 32 + n) * 2048;
    unsigned short* dstl = REPl + ((long)tt * 32 + n) * 2048;
    #pragma unroll
    for (int j = 0; j < 8; j++) {
        int e = ec * 64 + e0 + 8 * j;
        float val = out[j] * di;
        unsigned short hh = f2bf(val);
        dsth[e * 8 + h] = hh;
        dstl[e * 8 + h] = f2bf(val - bf2f(hh));
    }
}

// ============================================================
extern "C" void kernel_launch(void* const* d_in, const int* in_sizes, int n_in,
                              void* d_out, int out_size, void* d_ws, size_t ws_size,
                              hipStream_t stream)
{
    const float* train  = (const float*)d_in[0];
    const float* label  = (const float*)d_in[1];
    const float* test   = (const float*)d_in[2];
    const float* c1w = (const float*)d_in[3];  const float* c1b = (const float*)d_in[4];
    const float* c2w = (const float*)d_in[5];  const float* c2b = (const float*)d_in[6];
    const float* c3w = (const float*)d_in[7];  const float* c3b = (const float*)d_in[8];
    const float* elw = (const float*)d_in[9];  const float* elb = (const float*)d_in[10];
    const float* tyw = (const float*)d_in[11]; const float* tyb = (const float*)d_in[12];
    const float* ew1 = (const float*)d_in[13]; const float* eb1 = (const float*)d_in[14];
    const float* ew2 = (const float*)d_in[15]; const float* eb2 = (const float*)d_in[16];
    const float* ew3 = (const float*)d_in[17]; const float* eb3 = (const float*)d_in[18];
    const float* wq  = (const float*)d_in[19]; const float* wqb = (const float*)d_in[20];
    const float* wk  = (const float*)d_in[21]; const float* wkb = (const float*)d_in[22];
    const float* wv  = (const float*)d_in[23]; const float* wvb = (const float*)d_in[24];
    const float* wow = (const float*)d_in[25]; const float* wob = (const float*)d_in[26];
    const float* rzw = (const float*)d_in[27]; const float* rzb = (const float*)d_in[28];
    const float* dw1 = (const float*)d_in[29]; const float* db1 = (const float*)d_in[30];
    const float* dw2 = (const float*)d_in[31]; const float* db2 = (const float*)d_in[32];
    const float* dw3 = (const float*)d_in[33]; const float* db3 = (const float*)d_in[34];
    const float* proj= (const float*)d_in[35];

    float* wsf = (float*)d_ws;
    unsigned short* usw = (unsigned short*)d_ws;
    float* out = (float*)d_out;

    unsigned short* A_pool = usw;                 // pool at ush offset 0 (dead after conv3m)
    float* x_ctx  = wsf + OFF_XCTX;
    float* x_qry  = wsf + OFF_XQRY;
    float* xcat   = wsf + OFF_XCAT;
    float* h1     = wsf + OFF_H1;
    float* h2     = wsf + OFF_H2;
    float* rs     = wsf + OFF_RS;
    float* v_all  = wsf + OFF_VA;
    float* rep    = wsf + OFF_REP;
    float* xz     = wsf + OFF_XZ;
    float* dh1    = wsf + OFF_DH1;
    float* dh2    = wsf + OFF_DH2;
    float* xd_q   = wsf + OFF_XDQ;
    float* xd_k   = wsf + OFF_XDK;
    float* enc_t  = wsf + OFF_ENCT;
    float* rep_t  = wsf + OFF_REPT;
    float* pA     = wsf + OFF_PA;
    float* dqv    = wsf + OFF_MD;
    unsigned* mqe = (unsigned*)(wsf + OFF_MD + 4096);
    float* dkv    = wsf + OFF_MD + 8192;
    unsigned* mke = (unsigned*)(wsf + OFF_MD + 12288);
    unsigned* mdw = (unsigned*)(wsf + OFF_MD);
    unsigned short* Aw  = (unsigned short*)(wsf + OFF_AW);
    unsigned short* Aw3 = (unsigned short*)(wsf + OFF_AW3);
    unsigned short* Aw1 = (unsigned short*)(wsf + OFF_AW1);

    unsigned short* Wqkv = usw + U_WQH;
    unsigned short* Ph  = usw + U_PH;  unsigned short* Pl  = usw + U_PL;
    unsigned short* XCh = usw + U_XCH; unsigned short* XCl = usw + U_XCL;
    unsigned short* RSh = usw + U_RSH; unsigned short* RSl = usw + U_RSL;
    unsigned short* C3h = usw + U_C3H; unsigned short* C3l = usw + U_C3L;
    unsigned short* Qh  = usw + U_QH;  unsigned short* Ql  = usw + U_QL;
    unsigned short* Kh  = usw + U_KH;  unsigned short* Kl  = usw + U_KL;
    unsigned short* ELh = usw + U_ELH; unsigned short* ELl = usw + U_ELL;
    unsigned short* WOh = usw + U_WOH; unsigned short* WOl = usw + U_WOL;
    unsigned short* REPh= usw + U_REPH;unsigned short* REPl= usw + U_REPL;

    // 1. prep A: Aw/Aw1/Aw3/EL (non-pool regions only)
    k_wprepA<<<4442, 256, 0, stream>>>(c2w, c1w, c3w, elw, Aw, Aw1, Aw3, ELh, ELl);

    // 2-3. encoder convs
    k_conv12m<<<dim3(8, 1024), 512, 0, stream>>>(train, test, c1b, Aw, Aw1, c2b, A_pool);
    k_conv3m<<<1024, 512, 0, stream>>>(A_pool, Aw3, c3b, C3h, C3l);

    // 4. prep B: P + WQKV planes into the now-dead pool region
    k_wprepB<<<7616, 256, 0, stream>>>(proj, wq, wk, wv, Ph, Pl, Wqkv);

    // 5-6. enc linear split-K=8 into temps, then fused reduce (+bias, planes,
    //      xcat copy) + label embed + wo planes + MD zero (Aw dead after step 3)
    mgemm<3><<<dim3(4, 16, 8), 256, 0, stream>>>(
        C3h, C3l, ELh, ELl, nullptr, enc_t, nullptr, nullptr,
        1024, 256, 4096, 256, 1.f, 0, 0, 0, 262144, 512, nullptr, nullptr);
    k_red_enc<<<3249, 256, 0, stream>>>(enc_t, elb, x_ctx, XCh, XCl, xcat,
                                        label, tyw, tyb, wow, WOh, WOl, mdw);

    // 7-9. er MLP -> rs (last layer also emits RS planes)
    gemm_k<32,32,32,1,false,false><<<dim3(8, 16), 256, 0, stream>>>(xcat, ew1, eb1, h1, 512, 256, 320, 256, nullptr, nullptr);
    gemm_k<32,32,32,1,false,false><<<dim3(8, 16), 256, 0, stream>>>(h1, ew2, eb2, h2, 512, 256, 256, 256, nullptr, nullptr);
    gemm_k<32,32,32,0,false,true ><<<dim3(8, 16), 256, 0, stream>>>(h2, ew3, eb3, rs, 512, 256, 256, 256, RSh, RSl);

    // 10. q/k/v projections in one launch (+fused diag for Q/K)
    k_qkv<<<dim3(4, 8, 24), 256, 0, stream>>>(XCh, XCl, RSh, RSl, Wqkv,
                                              wqb, wkb, wvb, Qh, Ql, Kh, Kl,
                                              v_all, dqv, dkv);

    // 11. performer features (z=2), RAW xd + fused row/tile max
    mgemm<5><<<dim3(23, 64, 2), 256, 0, stream>>>(
        Qh, Ql, Ph, Pl, nullptr, xd_q, nullptr, nullptr,
        4096, F_FEAT, 256, F_FEAT, DN, 2097152, 0, 0, 5812224, 0, mqe, mke);

    // 12-13. attention: feature-split QK^T (fused exp) -> partial A; reduce+PV
    k_attn1<<<dim3(NSPLIT, 128), 256, 0, stream>>>(xd_q, xd_k, dqv, mqe, dkv, mke, pA);
    k_attn2<<<dim3(4, 128), 256, 0, stream>>>(pA, v_all, REPh, REPl);

    // 14-15. rep = rep_in @ wo^T + b : split-K=8 temps + fused reduce + xz copy
    mgemm<3><<<dim3(4, 8, 8), 256, 0, stream>>>(
        REPh, REPl, WOh, WOl, nullptr, rep_t, nullptr, nullptr,
        512, 256, 2048, 256, 1.f, 0, 0, 0, 131072, 256, nullptr, nullptr);
    k_red_rep<<<1024, 256, 0, stream>>>(rep_t, wob, rep, x_qry, xz);

    // 16. xz cols 256..383 = rep @ rz^T + b
    gemm_k<32,32,32,0,false,false><<<dim3(4, 16), 256, 0, stream>>>(rep, rzw, rzb, xz + 256, 512, 128, 256, 384, nullptr, nullptr);

    // 17-19. decoder (k_fin folded into the last GEMM)
    gemm_k<32,32,32,1,false,false><<<dim3(4, 16), 256, 0, stream>>>(xz, dw1, db1, dh1, 512, 100, 384, 100, nullptr, nullptr);
    gemm_k<32,32,32,1,false,false><<<dim3(4, 16), 256, 0, stream>>>(dh1, dw2, db2, dh2, 512, 100, 100, 100, nullptr, nullptr);
    gemm_k<32,32,32,2,true ,false><<<dim3(1, 16), 256, 0, stream>>>(dh2, dw3, db3, out, 512, 2, 100, 2, nullptr, nullptr);
}

// Round 10
// 649.924 us; speedup vs baseline: 1.0603x; 1.0603x over previous
//
#include <hip/hip_runtime.h>
#include <math.h>

// ---------------- problem constants ----------------
// T=16, NC=NQ=32, DW=256, DR=256, DZ=128, NH=8, F=1419
#define F_FEAT 1419
static constexpr float DN    = 0.25f;                 // 256^-0.25

typedef short short8 __attribute__((ext_vector_type(8)));
typedef float f32x4  __attribute__((ext_vector_type(4)));

// ---------------- workspace layout ----------------
// floats offsets unless noted "ush"
static constexpr long OFF_XDQ  = 0;                  // [4096][1419] f32 (performer phase, RAW)
static constexpr long OFF_XDK  = 5812224;            // [4096][1419] f32 (RAW)
static constexpr long U_WQH = 0;                     // W planes ush — POOL REGION: write only AFTER conv3m
static constexpr long U_WQL = 524288;
static constexpr long U_WKH = 1048576;
static constexpr long U_WKL = 1572864;
static constexpr long U_WVH = 2097152;
static constexpr long U_WVL = 2621440;               // ends ush 3,145,728
static constexpr long OFF_ENCT = 4000000;            // enc split-K temp: 8 x 262144 f32 (xd region, time-disjoint)
static constexpr long OFF_REPT = 6200000;            // rep split-K temp: 8 x 131072 f32 (xd dead by then)
static constexpr long OFF_PA   = 11624448;           // partial A: [128][4][1024] f32 (dead region after step 13)
static constexpr long U_PH  = 23248896;              // [1472][256] ush — POOL REGION: after conv3m
static constexpr long U_PL  = 23625728;
static constexpr long U_XCH = 24002560;              // [1024][256] ush — pool region, written step 5
static constexpr long U_XCL = 24264704;
static constexpr long U_RSH = 24526848;              // [512][256] ush
static constexpr long U_RSL = 24657920;
static constexpr long U_C3H = 25165824;              // [1024][4096] ush (starts at pool end)
static constexpr long U_C3L = 29360128;
static constexpr long U_WOH = 25165824;              // wo planes reuse C3 region after enc GEMM
static constexpr long U_WOL = 25690112;
static constexpr long BASE     = 16777216;
static constexpr long OFF_XCTX = BASE + 0;           // [1024][256] f32 (ctx rows 0..511, qry 512..1023)
static constexpr long OFF_XQRY = BASE + 131072;
static constexpr long OFF_XCAT = BASE + 262144;      // [512][320]
static constexpr long OFF_H1   = BASE + 425984;      // [512][256]
static constexpr long OFF_H2   = BASE + 557056;      // [512][256]
static constexpr long OFF_RS   = BASE + 688128;      // [512][256]
static constexpr long U_QH  = (BASE + 819200) * 2;   // Q planes ush
static constexpr long U_QL  = U_QH + 1048576;
static constexpr long U_KH  = (BASE + 1867776) * 2;  // K planes ush (Q->K stride 2,097,152 ush)
static constexpr long U_KL  = U_KH + 1048576;
static constexpr long OFF_VA   = BASE + 2916352;     // [8][512][256] f32
static constexpr long OFF_AW1  = BASE + 3964928;     // Aw1 (1024 ush)
static constexpr long U_ELH = (BASE + 3977344) * 2;  // EL planes ush (REPIN region); REP planes reuse
static constexpr long U_ELL = U_ELH + 1048576;
static constexpr long U_REPH = U_ELH;                // [512][2048] ush
static constexpr long U_REPL = U_ELL;
static constexpr long OFF_REP  = BASE + 5025920;     // [512][256]
static constexpr long OFF_XZ   = BASE + 5156992;     // [512][384]
static constexpr long OFF_DH1  = BASE + 5353600;     // [512][100]
static constexpr long OFF_DH2  = BASE + 5404800;     // [512][100]
static constexpr long OFF_MD   = BASE + 5456000;     // dq[4096] mqe[4096u] dk[4096] mke[128u] (dead Aw region)
static constexpr long OFF_AW   = 22233216;           // conv2 A-weights (13824 ush)
static constexpr long OFF_AW3  = 22240128;           // conv3 A-weights (73728 ush)

__device__ inline unsigned short f2bf(float f) {
    unsigned int x = __float_as_uint(f);
    unsigned int r = x + 0x7fffu + ((x >> 16) & 1u);
    return (unsigned short)(r >> 16);
}
__device__ inline float bf2f(unsigned short h) {
    return __uint_as_float((unsigned int)h << 16);
}
// packed RNE f32->bf16 pair: low16 = bf16(a), high16 = bf16(b)  (gfx950)
__device__ inline unsigned int cvtpk(float a, float b) {
    unsigned int r;
    asm("v_cvt_pk_bf16_f32 %0, %1, %2" : "=v"(r) : "v"(a), "v"(b));
    return r;
}
// monotonic f32 <-> u32 encoding for atomicMax over signed floats
__device__ inline unsigned encf(float f) {
    unsigned u = __float_as_uint(f);
    return (u & 0x80000000u) ? ~u : (u | 0x80000000u);
}
__device__ inline float decf(unsigned u) {
    return __uint_as_float((u & 0x80000000u) ? (u & 0x7fffffffu) : ~u);
}

// ============================================================
// Prep A (runs FIRST — only touches non-pool regions):
// Aw(conv2), Aw1(conv1), Aw3(conv3 hi/lo), EL planes.
// ============================================================
static constexpr int NA1 = 13824;                 // Aw
static constexpr int NA2 = NA1 + 1024;            // Aw1
static constexpr int NA3 = NA2 + 73728;           // Aw3
static constexpr int NA4 = NA3 + 1048576;         // EL

__global__ void k_wprepA(const float* __restrict__ w2, const float* __restrict__ w1,
                         const float* __restrict__ w3, const float* __restrict__ elw,
                         unsigned short* __restrict__ Aw, unsigned short* __restrict__ Aw1,
                         unsigned short* __restrict__ Aw3,
                         unsigned short* __restrict__ ELh, unsigned short* __restrict__ ELl)
{
    int i = blockIdx.x * 256 + threadIdx.x;
    if (i < NA1) {
        int ic  = i & 31;
        int m16 = (i >> 5) & 15;
        int emt = i >> 9;
        int mt  = emt % 3, e = emt / 3;
        Aw[i] = f2bf(w2[((mt * 16 + m16) * 32 + ic) * 9 + e]);
    } else if (i < NA2) {
        int j = i - NA1;
        int k = j & 31, m = (j >> 5) & 15, mt = j >> 9;
        Aw1[j] = (k < 9) ? f2bf(w1[(mt * 16 + m) * 9 + k]) : (unsigned short)0;
    } else if (i < NA3) {
        int j = i - NA2;
        int k  = j & 63;
        int m  = (j >> 6) & 15;
        int hl = (j >> 10) & 1;
        int mt = (j >> 11) & 3;
        int e  = j >> 13;
        unsigned short v = 0;
        if (k < 48) {
            float w = w3[((mt * 16 + m) * 48 + k) * 9 + e];
            unsigned short hi = f2bf(w);
            v = hl == 0 ? hi : f2bf(w - bf2f(hi));
        }
        Aw3[j] = v;
    } else if (i < NA4) {
        int j = i - NA3;
        float v = elw[j];
        unsigned short h = f2bf(v);
        ELh[j] = h; ELl[j] = f2bf(v - bf2f(h));
    }
}

// ============================================================
// Prep B (runs AFTER conv3m — targets live in the then-dead pool region):
// P planes (padded to 1472 rows), WQ/WK/WV planes.
// ============================================================
static constexpr int NB1 = 376832;                // P
static constexpr int NB2 = NB1 + 1572864;         // WQ/WK/WV

__global__ void k_wprepB(const float* __restrict__ proj,
                         const float* __restrict__ wq, const float* __restrict__ wk,
                         const float* __restrict__ wv,
                         unsigned short* __restrict__ Ph, unsigned short* __restrict__ Pl,
                         unsigned short* __restrict__ Wqkv)
{
    int i = blockIdx.x * 256 + threadIdx.x;
    if (i < NB1) {
        float v = (i < 363264) ? proj[i] : 0.f;
        unsigned short h = f2bf(v);
        Ph[i] = h; Pl[i] = f2bf(v - bf2f(h));
    } else if (i < NB2) {
        int j = i - NB1;
        int y = j / 524288, jj = j % 524288;
        const float* s = (y == 0) ? wq : (y == 1) ? wk : wv;
        float v = s[jj];
        unsigned short h = f2bf(v);
        Wqkv[(long)y * 1048576 + jj] = h;
        Wqkv[(long)y * 1048576 + 524288 + jj] = f2bf(v - bf2f(h));
    }
}

// ============================================================
// Fused conv1 (MFMA, LDS-staged im2col) -> bf16 ring -> conv2 MFMA
// -> in-register bias/relu/maxpool -> bf16 hi/lo pool.
// R10: REVERTED to the R7 256-thread version. R9's 8-wave split raised
// occupancy 31->64% but duplicated per-wave A-frag loads/epilogue work
// (+2 barriers) and ran 37% SLOWER — with R2 this kills both occupancy
// levers: the kernel's floor is the serial stage->conv1->conv2 chain at
// 3 LDS-capped blocks/CU; issue count is what matters (R3's diet win).
// ============================================================
#define TP 136
__launch_bounds__(256)
__global__ void k_conv12m(const float* __restrict__ train, const float* __restrict__ test,
                          const float* __restrict__ b1,
                          const unsigned short* __restrict__ Aw,
                          const unsigned short* __restrict__ Aw1,
                          const float* __restrict__ b2,
                          unsigned short* __restrict__ pool_out)
{
    const int g   = blockIdx.x;    // 0..7 (pool rows 2g, 2g+1; conv2 rows 4g..4g+3)
    const int img = blockIdx.y;
    const float* in = (img < 512) ? (train + (long)img * 16384)
                                  : (test  + (long)(img - 512) * 16384);

    __shared__ unsigned short ring[9 * 66 * 40];   // 47520 B
    __shared__ unsigned short tile[19 * TP];       // 5168 B: input rows 16g-3..16g+15

    const int t = threadIdx.x;

    for (int i = t; i < 9 * 40; i += 256) {
        int sl = i / 40, icp = i % 40;
        ring[(sl * 66 + 0) * 40 + icp] = 0;
    }
    if (g == 0)
        for (int i = t; i < 66 * 40; i += 256) ring[i] = 0;
    // zero the left halo (cols -2,-1 at tc 2,3) for all 19 rows
    if (t < 19) *(unsigned int*)&tile[t * TP + 2] = 0u;

    // ---- stage: 19 rows x 32 float4 (cols 0..127), packed bf16 ----
    {
        const float4 z4 = make_float4(0.f, 0.f, 0.f, 0.f);
        for (int u = t; u < 19 * 32; u += 256) {
            int row = u >> 5, k = u & 31;
            int r2 = 16 * g - 3 + row;             // never > 127
            float4 v = (r2 >= 0) ? *(const float4*)(in + r2 * 128 + k * 4) : z4;
            uint2 d;
            d.x = cvtpk(v.x, v.y);
            d.y = cvtpk(v.z, v.w);
            *(uint2*)&tile[row * TP + 4 + k * 4] = d;   // tc = c+4, 8B aligned
        }
    }
    __syncthreads();

    const int w    = t >> 6;
    const int lane = t & 63;
    const int cn   = lane & 15;
    const int quad = lane >> 4;

    // conv1 A-frags + per-lane biases (vector loads)
    short8 a1f0 = *(const short8*)&Aw1[(0 * 16 + cn) * 32 + quad * 8];
    short8 a1f1 = *(const short8*)&Aw1[(16 + cn) * 32 + quad * 8];
    float4 bsa = *(const float4*)&b1[quad * 4];
    float4 bsb = *(const float4*)&b1[16 + quad * 4];

    // ---- conv1 rows via MFMA (B-frag from tile; slice sl = conv1 row 8g+sl-1) ----
    const int px2 = w * 16 + cn;
    const int tb  = 2 * px2 + 2;                   // tc of input col 2px-2 (even)
    auto do_slice = [&](int sl) {
        const int rb = 2 * sl * TP + tb;
        uint4 pk = make_uint4(0u, 0u, 0u, 0u);
        if (quad == 0) {
            unsigned int w00 = *(const unsigned int*)&tile[rb];
            unsigned int w10 = *(const unsigned int*)&tile[rb + 2];
            unsigned int w01 = *(const unsigned int*)&tile[rb + TP];
            unsigned int w11 = *(const unsigned int*)&tile[rb + TP + 2];
            unsigned int w02 = *(const unsigned int*)&tile[rb + 2 * TP];
            unsigned int w12 = *(const unsigned int*)&tile[rb + 2 * TP + 2];
            pk.x = (w00 >> 16) | (w10 << 16);              // taps (0,0),(0,1)
            pk.y = (w10 >> 16) | (w01 & 0xffff0000u);      // taps (0,2),(1,0)
            pk.z = w11;                                    // taps (1,1),(1,2)
            pk.w = (w02 >> 16) | (w12 << 16);              // taps (2,0),(2,1)
        } else if (quad == 1) {
            pk.x = (*(const unsigned int*)&tile[rb + 2 * TP + 2]) >> 16;  // tap (2,2)
        }                                          // quads 2,3: taps 16..31 zero
        short8 bfr = *(const short8*)&pk;
        f32x4 z = (f32x4){0.f, 0.f, 0.f, 0.f};
        f32x4 c0 = __builtin_amdgcn_mfma_f32_16x16x32_bf16(a1f0, bfr, z, 0, 0, 0);
        f32x4 c1 = __builtin_amdgcn_mfma_f32_16x16x32_bf16(a1f1, bfr, z, 0, 0, 0);
        uint2 u0, u1;
        u0.x = cvtpk(fmaxf(c0[0] + bsa.x, 0.f), fmaxf(c0[1] + bsa.y, 0.f));
        u0.y = cvtpk(fmaxf(c0[2] + bsa.z, 0.f), fmaxf(c0[3] + bsa.w, 0.f));
        u1.x = cvtpk(fmaxf(c1[0] + bsb.x, 0.f), fmaxf(c1[1] + bsb.y, 0.f));
        u1.y = cvtpk(fmaxf(c1[2] + bsb.z, 0.f), fmaxf(c1[3] + bsb.w, 0.f));
        *(uint2*)&ring[(sl * 66 + px2 + 1) * 40 + quad * 4]      = u0;
        *(uint2*)&ring[(sl * 66 + px2 + 1) * 40 + 16 + quad * 4] = u1;
    };
    if (g > 0) do_slice(0);
    #pragma unroll
    for (int sl = 1; sl < 9; sl++) do_slice(sl);

    // issue e=0 conv2 A-frag loads before the barrier (overlap barrier wait)
    short8 ca0 = *(const short8*)&Aw[((0 * 3 + 0) * 16 + cn) * 32 + quad * 8];
    short8 ca1 = *(const short8*)&Aw[((0 * 3 + 1) * 16 + cn) * 32 + quad * 8];
    short8 ca2 = *(const short8*)&Aw[((0 * 3 + 2) * 16 + cn) * 32 + quad * 8];
    __syncthreads();

    // ---- conv2 MFMA: wave w -> pool row pr=w>>1, half xh=w&1,
    //      both conv2 rows of that pool row; A-frags prefetched 1 e ahead ----
    const int pr = w >> 1, xh = w & 1;
    f32x4 acc[3][2];
    #pragma unroll
    for (int mt = 0; mt < 3; mt++) {
        acc[mt][0] = (f32x4){0.f, 0.f, 0.f, 0.f};
        acc[mt][1] = (f32x4){0.f, 0.f, 0.f, 0.f};
    }

    #pragma unroll
    for (int e = 0; e < 9; e++) {
        int dy = e / 3, dx = e - 3 * dy;
        int c  = 2 * (xh * 16 + cn) + dx;
        int s0 = 4 * pr + dy;
        short8 b0  = *(const short8*)&ring[(s0 * 66 + c) * 40 + quad * 8];
        short8 b1f = *(const short8*)&ring[((s0 + 2) * 66 + c) * 40 + quad * 8];
        short8 na0, na1, na2;
        if (e < 8) {
            na0 = *(const short8*)&Aw[(((e + 1) * 3 + 0) * 16 + cn) * 32 + quad * 8];
            na1 = *(const short8*)&Aw[(((e + 1) * 3 + 1) * 16 + cn) * 32 + quad * 8];
            na2 = *(const short8*)&Aw[(((e + 1) * 3 + 2) * 16 + cn) * 32 + quad * 8];
        }
        acc[0][0] = __builtin_amdgcn_mfma_f32_16x16x32_bf16(ca0, b0,  acc[0][0], 0, 0, 0);
        acc[1][0] = __builtin_amdgcn_mfma_f32_16x16x32_bf16(ca1, b0,  acc[1][0], 0, 0, 0);
        acc[2][0] = __builtin_amdgcn_mfma_f32_16x16x32_bf16(ca2, b0,  acc[2][0], 0, 0, 0);
        acc[0][1] = __builtin_amdgcn_mfma_f32_16x16x32_bf16(ca0, b1f, acc[0][1], 0, 0, 0);
        acc[1][1] = __builtin_amdgcn_mfma_f32_16x16x32_bf16(ca1, b1f, acc[1][1], 0, 0, 0);
        acc[2][1] = __builtin_amdgcn_mfma_f32_16x16x32_bf16(ca2, b1f, acc[2][1], 0, 0, 0);
        if (e < 8) { ca0 = na0; ca1 = na1; ca2 = na2; }
    }

    // ---- in-register bias/relu/2x2-maxpool -> packed hi/lo stores ----
    {
        const int prow = 2 * g + pr;               // pool row 0..15
        const int ppx  = xh * 8 + (cn >> 1);       // pool px 0..15
        unsigned short* pb = pool_out + ((long)img * 256 + prow * 16 + ppx) * 96
                           + ((cn & 1) ? 48 : 0);
        #pragma unroll
        for (int mt = 0; mt < 3; mt++) {
            float4 bv = *(const float4*)&b2[mt * 16 + quad * 4];
            float m0, m1, m2, m3;
            {
                float v;
                v = fmaxf(fmaxf(acc[mt][0][0] + bv.x, acc[mt][1][0] + bv.x), 0.f);
                m0 = fmaxf(v, __shfl_xor(v, 1));
                v = fmaxf(fmaxf(acc[mt][0][1] + bv.y, acc[mt][1][1] + bv.y), 0.f);
                m1 = fmaxf(v, __shfl_xor(v, 1));
                v = fmaxf(fmaxf(acc[mt][0][2] + bv.z, acc[mt][1][2] + bv.z), 0.f);
                m2 = fmaxf(v, __shfl_xor(v, 1));
                v = fmaxf(fmaxf(acc[mt][0][3] + bv.w, acc[mt][1][3] + bv.w), 0.f);
                m3 = fmaxf(v, __shfl_xor(v, 1));
            }
            uint2 hv;
            hv.x = cvtpk(m0, m1);
            hv.y = cvtpk(m2, m3);
            uint2 sv = hv;
            if (cn & 1) {   // odd lane of the pair stores the lo plane
                float d0 = m0 - bf2f((unsigned short)(hv.x & 0xffffu));
                float d1 = m1 - bf2f((unsigned short)(hv.x >> 16));
                float d2 = m2 - bf2f((unsigned short)(hv.y & 0xffffu));
                float d3 = m3 - bf2f((unsigned short)(hv.y >> 16));
                sv.x = cvtpk(d0, d1);
                sv.y = cvtpk(d2, d3);
            }
            *(uint2*)&pb[mt * 16 + quad * 4] = sv;
        }
    }
}

// ============================================================
// conv3 via MFMA hi/lo -> bf16 hi/lo planes [1024][4096]
// ============================================================
#define C3PITCH 104
__launch_bounds__(512)
__global__ void k_conv3m(const unsigned short* __restrict__ pool,
                         const unsigned short* __restrict__ Aw3,
                         const float* __restrict__ b3,
                         unsigned short* __restrict__ C3h, unsigned short* __restrict__ C3l)
{
    const int img = blockIdx.x;
    __shared__ unsigned short s_in[30120];
    const int t = threadIdx.x;

    uint4* s4 = (uint4*)s_in;
    const uint4 zz = make_uint4(0, 0, 0, 0);
    for (int i = t; i < 3765; i += 512) s4[i] = zz;
    __syncthreads();
    {
        int p = t >> 1, half = t & 1;
        const uint4* src = (const uint4*)(pool + ((long)img * 256 + p) * 96 + half * 48);
        int r = p >> 4, c = p & 15;
        uint4* dst = (uint4*)(s_in + ((r + 1) * 17 + (c + 1)) * C3PITCH + half * 48);
        #pragma unroll
        for (int j = 0; j < 6; j++) dst[j] = src[j];
    }
    __syncthreads();

    const int w = t >> 6, lane = t & 63;
    const int n = lane & 15, quad = lane >> 4;
    const int mt = w >> 1, ntb = (w & 1) * 2;

    f32x4 acc[2];
    acc[0] = (f32x4){0.f, 0.f, 0.f, 0.f};
    acc[1] = (f32x4){0.f, 0.f, 0.f, 0.f};

    for (int e = 0; e < 9; e++) {
        int dy = e / 3, dx = e - 3 * dy;
        const unsigned short* A0 = Aw3 + (long)(((e * 4 + mt) * 2 + 0) * 16 + n) * 64 + quad * 8;
        const unsigned short* A1 = Aw3 + (long)(((e * 4 + mt) * 2 + 1) * 16 + n) * 64 + quad * 8;
        short8 ah0 = *(const short8*)(A0);
        short8 ah1 = *(const short8*)(A0 + 32);
        short8 al0 = *(const short8*)(A1);
        short8 al1 = *(const short8*)(A1 + 32);
        #pragma unroll
        for (int j = 0; j < 2; j++) {
            int p = (ntb + j) * 16 + n;
            int y = p >> 3, x = p & 7;
            const unsigned short* Bp = s_in + ((2 * y + dy) * 17 + (2 * x + dx)) * C3PITCH + quad * 8;
            short8 bh0 = *(const short8*)(Bp);
            short8 bh1 = *(const short8*)(Bp + 32);
            short8 bl0 = *(const short8*)(Bp + 48);
            short8 bl1 = *(const short8*)(Bp + 48 + 32);
            acc[j] = __builtin_amdgcn_mfma_f32_16x16x32_bf16(ah0, bh0, acc[j], 0, 0, 0);
            acc[j] = __builtin_amdgcn_mfma_f32_16x16x32_bf16(ah1, bh1, acc[j], 0, 0, 0);
            acc[j] = __builtin_amdgcn_mfma_f32_16x16x32_bf16(ah0, bl0, acc[j], 0, 0, 0);
            acc[j] = __builtin_amdgcn_mfma_f32_16x16x32_bf16(ah1, bl1, acc[j], 0, 0, 0);
            acc[j] = __builtin_amdgcn_mfma_f32_16x16x32_bf16(al0, bh0, acc[j], 0, 0, 0);
            acc[j] = __builtin_amdgcn_mfma_f32_16x16x32_bf16(al1, bh1, acc[j], 0, 0, 0);
        }
    }

    unsigned short* oh = C3h + (long)img * 4096;
    unsigned short* ol = C3l + (long)img * 4096;
    #pragma unroll
    for (int reg = 0; reg < 4; reg++) {
        int oc = mt * 16 + quad * 4 + reg;
        float bias = b3[oc];
        #pragma unroll
        for (int j = 0; j < 2; j++) {
            int p = (ntb + j) * 16 + n;
            float v = fmaxf(acc[j][reg] + bias, 0.f);
            unsigned short h = f2bf(v);
            oh[oc * 64 + p] = h;
            ol[oc * 64 + p] = f2bf(v - bf2f(h));
        }
    }
}

// ============================================================
// bf16 hi/lo MFMA GEMM (3-term, ~fp32). OUTMODE 0: f32 out (z-batch over
// X/W/B/Y strides); 1: hi/lo plane out (z-batch); 3: split-K chunks;
// 5: f32 out + fused max (z=0: per-row -> mqe; z=1: per-32row-tile -> mke).
// ============================================================
template<int OUTMODE>
__launch_bounds__(256)
__global__ void mgemm(const unsigned short* __restrict__ Xh0, const unsigned short* __restrict__ Xl0,
                      const unsigned short* __restrict__ Wph, const unsigned short* __restrict__ Wpl,
                      const float* __restrict__ Bb, float* __restrict__ Yf,
                      unsigned short* __restrict__ Yh, unsigned short* __restrict__ Yl,
                      int M, int N, int K, int ldY, float scale,
                      long sX, long sW, long sB, long sY, int kChunk,
                      unsigned* __restrict__ mqe, unsigned* __restrict__ mke)
{
    const int z = blockIdx.z;
    const unsigned short* Xh = Xh0 + (OUTMODE == 3 ? 0 : (long)z * sX);
    const unsigned short* Xl = Xl0 + (OUTMODE == 3 ? 0 : (long)z * sX);
    const unsigned short* Wh = Wph + (OUTMODE == 3 ? 0 : (long)z * sW);
    const unsigned short* Wl = Wpl + (OUTMODE == 3 ? 0 : (long)z * sW);
    const float* B = Bb ? (Bb + (OUTMODE == 3 ? 0 : (long)z * sB)) : nullptr;
    int k0 = 0, k1 = K;
    if (OUTMODE == 3) { k0 = z * kChunk; k1 = min(K, k0 + kChunk); }

    __shared__ unsigned short sAh[64 * 40], sAl[64 * 40], sBh[64 * 40], sBl[64 * 40];

    const int t = threadIdx.x;
    const int m0 = blockIdx.y * 64, n0 = blockIdx.x * 64;
    const int r = t >> 2, kq = (t & 3) * 8;

    const int w = t >> 6, lane = t & 63;
    const int wm = (w & 1) * 32, wn = (w >> 1) * 32;
    const int cn = lane & 15, quad = lane >> 4;

    f32x4 acc[2][2];
    acc[0][0] = acc[0][1] = acc[1][0] = acc[1][1] = (f32x4){0.f, 0.f, 0.f, 0.f};

    for (int kb = k0; kb < k1; kb += 32) {
        *(uint4*)&sAh[r * 40 + kq] = *(const uint4*)&Xh[(long)(m0 + r) * K + kb + kq];
        *(uint4*)&sAl[r * 40 + kq] = *(const uint4*)&Xl[(long)(m0 + r) * K + kb + kq];
        *(uint4*)&sBh[r * 40 + kq] = *(const uint4*)&Wh[(long)(n0 + r) * K + kb + kq];
        *(uint4*)&sBl[r * 40 + kq] = *(const uint4*)&Wl[(long)(n0 + r) * K + kb + kq];
        __syncthreads();
        short8 axh[2], axl[2], bxh[2], bxl[2];
        #pragma unroll
        for (int i = 0; i < 2; i++) {
            axh[i] = *(const short8*)&sAh[(wm + i * 16 + cn) * 40 + quad * 8];
            axl[i] = *(const short8*)&sAl[(wm + i * 16 + cn) * 40 + quad * 8];
            bxh[i] = *(const short8*)&sBh[(wn + i * 16 + cn) * 40 + quad * 8];
            bxl[i] = *(const short8*)&sBl[(wn + i * 16 + cn) * 40 + quad * 8];
        }
        #pragma unroll
        for (int i = 0; i < 2; i++)
            #pragma unroll
            for (int j = 0; j < 2; j++) {
                acc[i][j] = __builtin_amdgcn_mfma_f32_16x16x32_bf16(axh[i], bxh[j], acc[i][j], 0, 0, 0);
                acc[i][j] = __builtin_amdgcn_mfma_f32_16x16x32_bf16(axh[i], bxl[j], acc[i][j], 0, 0, 0);
                acc[i][j] = __builtin_amdgcn_mfma_f32_16x16x32_bf16(axl[i], bxh[j], acc[i][j], 0, 0, 0);
            }
        __syncthreads();
    }

    float gmax = -3e38f;
    #pragma unroll
    for (int i = 0; i < 2; i++) {
        #pragma unroll
        for (int reg = 0; reg < 4; reg++) {
            int row = m0 + wm + i * 16 + quad * 4 + reg;
            float rmax = -3e38f;
            #pragma unroll
            for (int j = 0; j < 2; j++) {
                int col = n0 + wn + j * 16 + cn;
                if (col >= N) continue;
                float v = acc[i][j][reg] * scale;
                if (OUTMODE == 3) {
                    (Yf + (long)z * sY)[(long)row * ldY + col] = v;
                } else if (OUTMODE == 0 || OUTMODE == 5) {
                    if (B) v += B[col];
                    (Yf + (long)z * sY)[(long)row * ldY + col] = v;
                    if (OUTMODE == 5) rmax = fmaxf(rmax, v);
                } else {
                    if (B) v += B[col];
                    unsigned short h = f2bf(v);
                    (Yh + (long)z * sY)[(long)row * ldY + col] = h;
                    (Yl + (long)z * sY)[(long)row * ldY + col] = f2bf(v - bf2f(h));
                }
            }
            if (OUTMODE == 5) {
                if (z == 0) {
                    rmax = fmaxf(rmax, __shfl_xor(rmax, 1));
                    rmax = fmaxf(rmax, __shfl_xor(rmax, 2));
                    rmax = fmaxf(rmax, __shfl_xor(rmax, 4));
                    rmax = fmaxf(rmax, __shfl_xor(rmax, 8));
                    if (cn == 0) atomicMax(&mqe[row], encf(rmax));
                } else {
                    gmax = fmaxf(gmax, rmax);
                }
            }
        }
    }
    if (OUTMODE == 5 && z == 1) {
        for (int d = 1; d < 64; d <<= 1) gmax = fmaxf(gmax, __shfl_xor(gmax, d));
        if (lane == 0) atomicMax(&mke[(m0 + wm) >> 5], encf(gmax));
    }
}

// ============================================================
// k_qkv: Q/K/V projections in ONE launch, grid (4, 8, 24).
// z 0..7 = Q heads (x_qry, planes out + diag), 8..15 = K heads (x_ctx,
// planes + diag), 16..23 = V heads (rs, f32 out). diag = sum(v^2)/32
// atomicAdd'd per token row (MD region zeroed in k_red_enc).
// ============================================================
__launch_bounds__(256)
__global__ void k_qkv(const unsigned short* __restrict__ XCh, const unsigned short* __restrict__ XCl,
                      const unsigned short* __restrict__ RSh, const unsigned short* __restrict__ RSl,
                      const unsigned short* __restrict__ Wqkv,
                      const float* __restrict__ wqb, const float* __restrict__ wkb,
                      const float* __restrict__ wvb,
                      unsigned short* __restrict__ Qh, unsigned short* __restrict__ Ql,
                      unsigned short* __restrict__ Kh, unsigned short* __restrict__ Kl,
                      float* __restrict__ v_all, float* __restrict__ dq, float* __restrict__ dk)
{
    const int z = blockIdx.z, y = z >> 3, zh = z & 7;
    const unsigned short* Xh = (y == 0) ? XCh + 512 * 256 : (y == 1) ? XCh : RSh;
    const unsigned short* Xl = (y == 0) ? XCl + 512 * 256 : (y == 1) ? XCl : RSl;
    const unsigned short* Wh = Wqkv + (long)y * 1048576 + (long)zh * 65536;
    const unsigned short* Wl = Wh + 524288;
    const float* B = ((y == 0) ? wqb : (y == 1) ? wkb : wvb) + zh * 256;

    __shared__ unsigned short sAh[64 * 40], sAl[64 * 40], sBh[64 * 40], sBl[64 * 40];

    const int t = threadIdx.x;
    const int m0 = blockIdx.y * 64, n0 = blockIdx.x * 64;
    const int r = t >> 2, kq = (t & 3) * 8;
    const int w = t >> 6, lane = t & 63;
    const int wm = (w & 1) * 32, wn = (w >> 1) * 32;
    const int cn = lane & 15, quad = lane >> 4;

    f32x4 acc[2][2];
    acc[0][0] = acc[0][1] = acc[1][0] = acc[1][1] = (f32x4){0.f, 0.f, 0.f, 0.f};

    for (int kb = 0; kb < 256; kb += 32) {
        *(uint4*)&sAh[r * 40 + kq] = *(const uint4*)&Xh[(long)(m0 + r) * 256 + kb + kq];
        *(uint4*)&sAl[r * 40 + kq] = *(const uint4*)&Xl[(long)(m0 + r) * 256 + kb + kq];
        *(uint4*)&sBh[r * 40 + kq] = *(const uint4*)&Wh[(long)(n0 + r) * 256 + kb + kq];
        *(uint4*)&sBl[r * 40 + kq] = *(const uint4*)&Wl[(long)(n0 + r) * 256 + kb + kq];
        __syncthreads();
        short8 axh[2], axl[2], bxh[2], bxl[2];
        #pragma unroll
        for (int i = 0; i < 2; i++) {
            axh[i] = *(const short8*)&sAh[(wm + i * 16 + cn) * 40 + quad * 8];
            axl[i] = *(const short8*)&sAl[(wm + i * 16 + cn) * 40 + quad * 8];
            bxh[i] = *(const short8*)&sBh[(wn + i * 16 + cn) * 40 + quad * 8];
            bxl[i] = *(const short8*)&sBl[(wn + i * 16 + cn) * 40 + quad * 8];
        }
        #pragma unroll
        for (int i = 0; i < 2; i++)
            #pragma unroll
            for (int j = 0; j < 2; j++) {
                acc[i][j] = __builtin_amdgcn_mfma_f32_16x16x32_bf16(axh[i], bxh[j], acc[i][j], 0, 0, 0);
                acc[i][j] = __builtin_amdgcn_mfma_f32_16x16x32_bf16(axh[i], bxl[j], acc[i][j], 0, 0, 0);
                acc[i][j] = __builtin_amdgcn_mfma_f32_16x16x32_bf16(axl[i], bxh[j], acc[i][j], 0, 0, 0);
            }
        __syncthreads();
    }

    unsigned short* Yh = ((y == 0) ? Qh : Kh) + (long)zh * 131072;
    unsigned short* Yl = ((y == 0) ? Ql : Kl) + (long)zh * 131072;
    float* Yf = v_all + (long)zh * 131072;
    float* dacc = ((y == 0) ? dq : dk) + zh * 512;

    #pragma unroll
    for (int i = 0; i < 2; i++) {
        #pragma unroll
        for (int reg = 0; reg < 4; reg++) {
            int row = m0 + wm + i * 16 + quad * 4 + reg;
            float s = 0.f;
            #pragma unroll
            for (int j = 0; j < 2; j++) {
                int col = n0 + wn + j * 16 + cn;
                float v = acc[i][j][reg] + B[col];
                if (y == 2) {
                    Yf[(long)row * 256 + col] = v;
                } else {
                    unsigned short h = f2bf(v);
                    Yh[(long)row * 256 + col] = h;
                    Yl[(long)row * 256 + col] = f2bf(v - bf2f(h));
                    s += v * v;
                }
            }
            if (y < 2) {
                s += __shfl_xor(s, 1); s += __shfl_xor(s, 2);
                s += __shfl_xor(s, 4); s += __shfl_xor(s, 8);
                if (cn == 0) atomicAdd(&dacc[row], s * (1.f / 32.f));
            }
        }
    }
}

// ============================================================
// reducers for split-K temps (fused with small jobs to cut launches)
// k_red_enc grid 3249: [0,1024) enc reduce; [1024,1152) label embed;
// [1152,3200) wo -> hi/lo planes; [3200,3249) zero MD (diag/max buffers).
// ============================================================
__global__ void k_red_enc(const float* __restrict__ tmp, const float* __restrict__ elb,
                          float* __restrict__ x_ctx, unsigned short* __restrict__ XCh,
                          unsigned short* __restrict__ XCl, float* __restrict__ xcat,
                          const float* __restrict__ label, const float* __restrict__ tyw,
                          const float* __restrict__ tyb,
                          const float* __restrict__ wow, unsigned short* __restrict__ WOh,
                          unsigned short* __restrict__ WOl, unsigned* __restrict__ md)
{
    int b = blockIdx.x;
    int tt = threadIdx.x;
    if (b < 1024) {
        int i = b * 256 + tt;                 // 262144
        int r = i >> 8, c = i & 255;
        float v = elb[c];
        #pragma unroll
        for (int z = 0; z < 8; z++) v += tmp[(long)z * 262144 + i];
        x_ctx[i] = v;
        unsigned short h = f2bf(v);
        XCh[i] = h; XCl[i] = f2bf(v - bf2f(h));
        if (r < 512) xcat[r * 320 + c] = v;
    } else if (b < 1152) {
        int i = (b - 1024) * 256 + tt;        // 32768
        int r = i >> 6, e = i & 63;
        xcat[r * 320 + 256 + e] = tyb[e] + label[r * 2] * tyw[e * 2] + label[r * 2 + 1] * tyw[e * 2 + 1];
    } else if (b < 3200) {
        int i = (b - 1152) * 256 + tt;        // 524288
        float v = wow[i];
        unsigned short h = f2bf(v);
        WOh[i] = h; WOl[i] = f2bf(v - bf2f(h));
    } else {
        int i = (b - 3200) * 256 + tt;        // 12416 (dq,mqe,dk,mke)
        if (i < 12416) md[i] = 0u;
    }
}

// k_red_rep grid 1024: [0,512) rep reduce (8 chunks); [512,1024) xz col copy.
__global__ void k_red_rep(const float* __restrict__ tmp, const float* __restrict__ wob,
                          float* __restrict__ rep,
                          const float* __restrict__ xq, float* __restrict__ xz)
{
    int b = blockIdx.x;
    int tt = threadIdx.x;
    if (b < 512) {
        int i = b * 256 + tt;                 // 131072
        int c = i & 255;
        float v = wob[c];
        #pragma unroll
        for (int z = 0; z < 8; z++) v += tmp[(long)z * 131072 + i];
        rep[i] = v;
    } else {
        int i = (b - 512) * 256 + tt;         // 131072
        int r = i >> 8, c = i & 255;
        xz[r * 384 + c] = xq[i];
    }
}

// ============================================================
// Generic fp32 GEMM (small layers), float2 inner loads.
// WP: also emit bf16 hi/lo planes of the output (used for rs).
// ============================================================
template<int BM, int BN, int BK, int ACT, bool FIN, bool WP>
__launch_bounds__(256)
__global__ void gemm_k(const float* __restrict__ X, const float* __restrict__ W,
                       const float* __restrict__ B, float* __restrict__ Y,
                       int M, int N, int K, int ldY,
                       unsigned short* __restrict__ Ph2, unsigned short* __restrict__ Pl2)
{
    __shared__ float As[BK][BM + 4];
    __shared__ float Bs[BK][BN + 4];
    const int t = threadIdx.x;
    const int tx = t & 15, ty = t >> 4;
    const int m0 = blockIdx.y * BM, n0 = blockIdx.x * BN;
    float acc[2][2] = {{0.f, 0.f}, {0.f, 0.f}};

    for (int kb = 0; kb < K; kb += BK) {
        for (int i = t; i < BM * BK; i += 256) {
            int rr = i / BK, c = i % BK;
            int mm = m0 + rr, kk = kb + c;
            As[c][rr] = (mm < M && kk < K) ? X[(long)mm * K + kk] : 0.f;
        }
        for (int i = t; i < BN * BK; i += 256) {
            int rr = i / BK, c = i % BK;
            int nn = n0 + rr, kk = kb + c;
            Bs[c][rr] = (nn < N && kk < K) ? W[(long)nn * K + kk] : 0.f;
        }
        __syncthreads();
        #pragma unroll
        for (int kk = 0; kk < BK; kk++) {
            float2 a2 = *(const float2*)&As[kk][ty * 2];
            float2 b2 = *(const float2*)&Bs[kk][tx * 2];
            acc[0][0] += a2.x * b2.x; acc[0][1] += a2.x * b2.y;
            acc[1][0] += a2.y * b2.x; acc[1][1] += a2.y * b2.y;
        }
        __syncthreads();
    }

    #pragma unroll
    for (int i = 0; i < 2; i++) {
        int mm = m0 + ty * 2 + i;
        if (mm >= M) continue;
        #pragma unroll
        for (int j = 0; j < 2; j++) {
            int nn = n0 + tx * 2 + j;
            if (nn >= N) continue;
            float v = acc[i][j] + (B ? B[nn] : 0.f);
            if (ACT == 1) v = fmaxf(v, 0.f);
            if (ACT == 2) v = tanhf(v);
            Y[(long)mm * ldY + nn] = v;
            if (WP) {
                unsigned short h = f2bf(v);
                Ph2[(long)mm * ldY + nn] = h;
                Pl2[(long)mm * ldY + nn] = f2bf(v - bf2f(h));
            }
        }
    }
    if (FIN && t == 0 && blockIdx.x == 0 && blockIdx.y == 0) Y[1024] = 0.f;
}

// ============================================================
// k_attn1: feature-split QK^T with fused exp. grid (NSPLIT=4, 128).
// Each block: features [s*355, min(1419,(s+1)*355)) of one (h,t) tile;
// partial A[32][32] -> pA[kb][s][1024]. LDS pitch 65 (conflict-free).
// shifts: dq + decode(mqe) per q-row; dk + decode(mke[kb]) per k-row.
// ============================================================
#define NSPLIT 4
#define FCH 355
__launch_bounds__(256)
__global__ void k_attn1(const float* __restrict__ qp, const float* __restrict__ kp,
                        const float* __restrict__ dq, const unsigned* __restrict__ mqe,
                        const float* __restrict__ dk, const unsigned* __restrict__ mke,
                        float* __restrict__ pA)
{
    const int s  = blockIdx.x;        // 0..3 feature split
    const int kb = blockIdx.y;        // 0..127 tile
    const long row0 = (long)kb * 32;
    const int f0 = s * FCH;
    const int f1 = min(F_FEAT, f0 + FCH);

    __shared__ float s_q[32 * 65];
    __shared__ float s_k[32 * 65];
    __shared__ float s_cq[32], s_ck[32];

    const int t = threadIdx.x;
    const int n = t >> 3;
    const int mq_ = (t & 7) * 4;

    if (t < 32) {
        s_cq[t] = dq[row0 + t] + decf(mqe[row0 + t]);
        s_ck[t] = dk[row0 + t] + decf(mke[kb]);
    }
    __syncthreads();

    float acc[4] = {0.f, 0.f, 0.f, 0.f};
    for (int fc = f0; fc < f1; fc += 64) {
        for (int i = t; i < 2048; i += 256) {
            int rr = i >> 6, ff = i & 63;
            int fg = fc + ff;
            float qv = 0.f, kv = 0.f;
            if (fg < f1) {
                qv = __expf(qp[(row0 + rr) * F_FEAT + fg] - s_cq[rr]) + 1e-4f;
                kv = __expf(kp[(row0 + rr) * F_FEAT + fg] - s_ck[rr]) + 1e-4f;
            }
            s_q[rr * 65 + ff] = qv;
            s_k[rr * 65 + ff] = kv;
        }
        __syncthreads();
        #pragma unroll 8
        for (int ff = 0; ff < 64; ff++) {
            float a = s_q[n * 65 + ff];
            #pragma unroll
            for (int j = 0; j < 4; j++) acc[j] += a * s_k[(mq_ + j) * 65 + ff];
        }
        __syncthreads();
    }

    float* dst = pA + ((long)kb * NSPLIT + s) * 1024;
    #pragma unroll
    for (int j = 0; j < 4; j++) dst[n * 32 + mq_ + j] = acc[j];
}

// ============================================================
// k_attn2: reduce partial A + rowsum + PV chunk -> REP planes.
// grid (4 e-chunks, 128 tiles).
// ============================================================
__launch_bounds__(256)
__global__ void k_attn2(const float* __restrict__ pA, const float* __restrict__ va,
                        unsigned short* __restrict__ REPh, unsigned short* __restrict__ REPl)
{
    const int ec = blockIdx.x;        // 0..3, 64 output cols each
    const int kb = blockIdx.y;        // 0..127
    const int h = kb >> 4, tt = kb & 15;
    const long row0 = (long)kb * 32;

    __shared__ float s_A[32][33];
    __shared__ float s_di[32];
    __shared__ float s_v[32 * 64];

    const int t = threadIdx.x;

    // reduce NSPLIT partials, 4 A-elements per thread (float4 loads)
    {
        const float* base = pA + (long)kb * NSPLIT * 1024 + t * 4;
        float4 v0 = *(const float4*)(base);
        float4 v1 = *(const float4*)(base + 1024);
        float4 v2 = *(const float4*)(base + 2048);
        float4 v3 = *(const float4*)(base + 3072);
        int r = t >> 3, c = (t & 7) * 4;
        s_A[r][c]     = v0.x + v1.x + v2.x + v3.x;
        s_A[r][c + 1] = v0.y + v1.y + v2.y + v3.y;
        s_A[r][c + 2] = v0.z + v1.z + v2.z + v3.z;
        s_A[r][c + 3] = v0.w + v1.w + v2.w + v3.w;
    }
    // stage V chunk (coalesced)
    for (int i = t; i < 2048; i += 256) {
        int m = i >> 6, e = i & 63;
        s_v[m * 64 + e] = va[row0 * 256 + m * 256 + ec * 64 + e];
    }
    __syncthreads();
    if (t < 32) {
        float s = 0.f;
        #pragma unroll
        for (int m = 0; m < 32; m++) s += s_A[t][m];
        s_di[t] = 1.f / s;
    }
    __syncthreads();

    const int n = t >> 3, e0 = t & 7;
    float out[8];
    #pragma unroll
    for (int j = 0; j < 8; j++) out[j] = 0.f;
    for (int m = 0; m < 32; m++) {
        float a = s_A[n][m];
        #pragma unroll
        for (int j = 0; j < 8; j++) out[j] += a * s_v[m * 64 + e0 + 8 * j];
    }
    float di = s_di[n];
    unsigned short* dsth = REPh + ((long)tt * 32 + n) * 2048;
    unsigned short* dstl = REPl + ((long)tt * 32 + n) * 2048;
    #pragma unroll
    for (int j = 0; j < 8; j++) {
        int e = ec * 64 + e0 + 8 * j;
        float val = out[j] * di;
        unsigned short hh = f2bf(val);
        dsth[e * 8 + h] = hh;
        dstl[e * 8 + h] = f2bf(val - bf2f(hh));
    }
}

// ============================================================
extern "C" void kernel_launch(void* const* d_in, const int* in_sizes, int n_in,
                              void* d_out, int out_size, void* d_ws, size_t ws_size,
                              hipStream_t stream)
{
    const float* train  = (const float*)d_in[0];
    const float* label  = (const float*)d_in[1];
    const float* test   = (const float*)d_in[2];
    const float* c1w = (const float*)d_in[3];  const float* c1b = (const float*)d_in[4];
    const float* c2w = (const float*)d_in[5];  const float* c2b = (const float*)d_in[6];
    const float* c3w = (const float*)d_in[7];  const float* c3b = (const float*)d_in[8];
    const float* elw = (const float*)d_in[9];  const float* elb = (const float*)d_in[10];
    const float* tyw = (const float*)d_in[11]; const float* tyb = (const float*)d_in[12];
    const float* ew1 = (const float*)d_in[13]; const float* eb1 = (const float*)d_in[14];
    const float* ew2 = (const float*)d_in[15]; const float* eb2 = (const float*)d_in[16];
    const float* ew3 = (const float*)d_in[17]; const float* eb3 = (const float*)d_in[18];
    const float* wq  = (const float*)d_in[19]; const float* wqb = (const float*)d_in[20];
    const float* wk  = (const float*)d_in[21]; const float* wkb = (const float*)d_in[22];
    const float* wv  = (const float*)d_in[23]; const float* wvb = (const float*)d_in[24];
    const float* wow = (const float*)d_in[25]; const float* wob = (const float*)d_in[26];
    const float* rzw = (const float*)d_in[27]; const float* rzb = (const float*)d_in[28];
    const float* dw1 = (const float*)d_in[29]; const float* db1 = (const float*)d_in[30];
    const float* dw2 = (const float*)d_in[31]; const float* db2 = (const float*)d_in[32];
    const float* dw3 = (const float*)d_in[33]; const float* db3 = (const float*)d_in[34];
    const float* proj= (const float*)d_in[35];

    float* wsf = (float*)d_ws;
    unsigned short* usw = (unsigned short*)d_ws;
    float* out = (float*)d_out;

    unsigned short* A_pool = usw;                 // pool at ush offset 0 (dead after conv3m)
    float* x_ctx  = wsf + OFF_XCTX;
    float* x_qry  = wsf + OFF_XQRY;
    float* xcat   = wsf + OFF_XCAT;
    float* h1     = wsf + OFF_H1;
    float* h2     = wsf + OFF_H2;
    float* rs     = wsf + OFF_RS;
    float* v_all  = wsf + OFF_VA;
    float* rep    = wsf + OFF_REP;
    float* xz     = wsf + OFF_XZ;
    float* dh1    = wsf + OFF_DH1;
    float* dh2    = wsf + OFF_DH2;
    float* xd_q   = wsf + OFF_XDQ;
    float* xd_k   = wsf + OFF_XDK;
    float* enc_t  = wsf + OFF_ENCT;
    float* rep_t  = wsf + OFF_REPT;
    float* pA     = wsf + OFF_PA;
    float* dqv    = wsf + OFF_MD;
    unsigned* mqe = (unsigned*)(wsf + OFF_MD + 4096);
    float* dkv    = wsf + OFF_MD + 8192;
    unsigned* mke = (unsigned*)(wsf + OFF_MD + 12288);
    unsigned* mdw = (unsigned*)(wsf + OFF_MD);
    unsigned short* Aw  = (unsigned short*)(wsf + OFF_AW);
    unsigned short* Aw3 = (unsigned short*)(wsf + OFF_AW3);
    unsigned short* Aw1 = (unsigned short*)(wsf + OFF_AW1);

    unsigned short* Wqkv = usw + U_WQH;
    unsigned short* Ph  = usw + U_PH;  unsigned short* Pl  = usw + U_PL;
    unsigned short* XCh = usw + U_XCH; unsigned short* XCl = usw + U_XCL;
    unsigned short* RSh = usw + U_RSH; unsigned short* RSl = usw + U_RSL;
    unsigned short* C3h = usw + U_C3H; unsigned short* C3l = usw + U_C3L;
    unsigned short* Qh  = usw + U_QH;  unsigned short* Ql  = usw + U_QL;
    unsigned short* Kh  = usw + U_KH;  unsigned short* Kl  = usw + U_KL;
    unsigned short* ELh = usw + U_ELH; unsigned short* ELl = usw + U_ELL;
    unsigned short* WOh = usw + U_WOH; unsigned short* WOl = usw + U_WOL;
    unsigned short* REPh= usw + U_REPH;unsigned short* REPl= usw + U_REPL;

    // 1. prep A: Aw/Aw1/Aw3/EL (non-pool regions only)
    k_wprepA<<<4442, 256, 0, stream>>>(c2w, c1w, c3w, elw, Aw, Aw1, Aw3, ELh, ELl);

    // 2-3. encoder convs
    k_conv12m<<<dim3(8, 1024), 256, 0, stream>>>(train, test, c1b, Aw, Aw1, c2b, A_pool);
    k_conv3m<<<1024, 512, 0, stream>>>(A_pool, Aw3, c3b, C3h, C3l);

    // 4. prep B: P + WQKV planes into the now-dead pool region
    k_wprepB<<<7616, 256, 0, stream>>>(proj, wq, wk, wv, Ph, Pl, Wqkv);

    // 5-6. enc linear split-K=8 into temps, then fused reduce (+bias, planes,
    //      xcat copy) + label embed + wo planes + MD zero (Aw dead after step 3)
    mgemm<3><<<dim3(4, 16, 8), 256, 0, stream>>>(
        C3h, C3l, ELh, ELl, nullptr, enc_t, nullptr, nullptr,
        1024, 256, 4096, 256, 1.f, 0, 0, 0, 262144, 512, nullptr, nullptr);
    k_red_enc<<<3249, 256, 0, stream>>>(enc_t, elb, x_ctx, XCh, XCl, xcat,
                                        label, tyw, tyb, wow, WOh, WOl, mdw);

    // 7-9. er MLP -> rs (last layer also emits RS planes)
    gemm_k<32,32,32,1,false,false><<<dim3(8, 16), 256, 0, stream>>>(xcat, ew1, eb1, h1, 512, 256, 320, 256, nullptr, nullptr);
    gemm_k<32,32,32,1,false,false><<<dim3(8, 16), 256, 0, stream>>>(h1, ew2, eb2, h2, 512, 256, 256, 256, nullptr, nullptr);
    gemm_k<32,32,32,0,false,true ><<<dim3(8, 16), 256, 0, stream>>>(h2, ew3, eb3, rs, 512, 256, 256, 256, RSh, RSl);

    // 10. q/k/v projections in one launch (+fused diag for Q/K)
    k_qkv<<<dim3(4, 8, 24), 256, 0, stream>>>(XCh, XCl, RSh, RSl, Wqkv,
                                              wqb, wkb, wvb, Qh, Ql, Kh, Kl,
                                              v_all, dqv, dkv);

    // 11. performer features (z=2), RAW xd + fused row/tile max
    mgemm<5><<<dim3(23, 64, 2), 256, 0, stream>>>(
        Qh, Ql, Ph, Pl, nullptr, xd_q, nullptr, nullptr,
        4096, F_FEAT, 256, F_FEAT, DN, 2097152, 0, 0, 5812224, 0, mqe, mke);

    // 12-13. attention: feature-split QK^T (fused exp) -> partial A; reduce+PV
    k_attn1<<<dim3(NSPLIT, 128), 256, 0, stream>>>(xd_q, xd_k, dqv, mqe, dkv, mke, pA);
    k_attn2<<<dim3(4, 128), 256, 0, stream>>>(pA, v_all, REPh, REPl);

    // 14-15. rep = rep_in @ wo^T + b : split-K=8 temps + fused reduce + xz copy
    mgemm<3><<<dim3(4, 8, 8), 256, 0, stream>>>(
        REPh, REPl, WOh, WOl, nullptr, rep_t, nullptr, nullptr,
        512, 256, 2048, 256, 1.f, 0, 0, 0, 131072, 256, nullptr, nullptr);
    k_red_rep<<<1024, 256, 0, stream>>>(rep_t, wob, rep, x_qry, xz);

    // 16. xz cols 256..383 = rep @ rz^T + b
    gemm_k<32,32,32,0,false,false><<<dim3(4, 16), 256, 0, stream>>>(rep, rzw, rzb, xz + 256, 512, 128, 256, 384, nullptr, nullptr);

    // 17-19. decoder (k_fin folded into the last GEMM)
    gemm_k<32,32,32,1,false,false><<<dim3(4, 16), 256, 0, stream>>>(xz, dw1, db1, dh1, 512, 100, 384, 100, nullptr, nullptr);
    gemm_k<32,32,32,1,false,false><<<dim3(4, 16), 256, 0, stream>>>(dh1, dw2, db2, dh2, 512, 100, 100, 100, nullptr, nullptr);
    gemm_k<32,32,32,2,true ,false><<<dim3(1, 16), 256, 0, stream>>>(dh2, dw3, db3, out, 512, 2, 100, 2, nullptr, nullptr);
}

// Round 11
// 636.697 us; speedup vs baseline: 1.0824x; 1.0208x over previous
//
#include <hip/hip_runtime.h>
#include <math.h>

// ---------------- problem constants ----------------
// T=16, NC=NQ=32, DW=256, DR=256, DZ=128, NH=8, F=1419
#define F_FEAT 1419
static constexpr float DN    = 0.25f;                 // 256^-0.25

typedef short short8 __attribute__((ext_vector_type(8)));
typedef float f32x4  __attribute__((ext_vector_type(4)));

// ---------------- workspace layout ----------------
// floats offsets unless noted "ush"
static constexpr long OFF_XDQ  = 0;                  // [4096][1419] f32 (performer phase, RAW)
static constexpr long OFF_XDK  = 5812224;            // [4096][1419] f32 (RAW)
static constexpr long U_WQH = 0;                     // W planes ush — POOL REGION: write only AFTER conv3m
static constexpr long U_WQL = 524288;
static constexpr long U_WKH = 1048576;
static constexpr long U_WKL = 1572864;
static constexpr long U_WVH = 2097152;
static constexpr long U_WVL = 2621440;               // ends ush 3,145,728
static constexpr long OFF_ENCT = 4000000;            // enc split-K temp: 8 x 262144 f32 (xd region, time-disjoint)
static constexpr long OFF_REPT = 6200000;            // rep split-K temp: 8 x 131072 f32 (xd dead by then)
static constexpr long OFF_PA   = 11624448;           // partial A: [128][4][1024] f32 (dead region after step 13)
static constexpr long U_PH  = 23248896;              // [1536][256] ush — POOL REGION: after conv3m (padded for 128-tile)
static constexpr long U_PL  = 23642112;
static constexpr long U_XCH = 24035328;              // [1024][256] ush — pool region, written step 5
static constexpr long U_XCL = 24297472;
static constexpr long U_RSH = 24559616;              // [512][256] ush
static constexpr long U_RSL = 24690688;              // ends 24,821,760 < C3 start
static constexpr long U_C3H = 25165824;              // [1024][4096] ush (starts at pool end)
static constexpr long U_C3L = 29360128;
static constexpr long U_WOH = 25165824;              // wo planes reuse C3 region after enc GEMM
static constexpr long U_WOL = 25690112;
static constexpr long BASE     = 16777216;
static constexpr long OFF_XCTX = BASE + 0;           // [1024][256] f32 (ctx rows 0..511, qry 512..1023)
static constexpr long OFF_XQRY = BASE + 131072;
static constexpr long OFF_XCAT = BASE + 262144;      // [512][320]
static constexpr long OFF_H1   = BASE + 425984;      // [512][256]
static constexpr long OFF_H2   = BASE + 557056;      // [512][256]
static constexpr long OFF_RS   = BASE + 688128;      // [512][256]
static constexpr long U_QH  = (BASE + 819200) * 2;   // Q planes ush
static constexpr long U_QL  = U_QH + 1048576;
static constexpr long U_KH  = (BASE + 1867776) * 2;  // K planes ush (Q->K stride 2,097,152 ush)
static constexpr long U_KL  = U_KH + 1048576;
static constexpr long OFF_VA   = BASE + 2916352;     // [8][512][256] f32
static constexpr long OFF_AW1  = BASE + 3964928;     // Aw1 (1024 ush)
static constexpr long U_ELH = (BASE + 3977344) * 2;  // EL planes ush (REPIN region); REP planes reuse
static constexpr long U_ELL = U_ELH + 1048576;
static constexpr long U_REPH = U_ELH;                // [512][2048] ush
static constexpr long U_REPL = U_ELL;
static constexpr long OFF_REP  = BASE + 5025920;     // [512][256]
static constexpr long OFF_XZ   = BASE + 5156992;     // [512][384]
static constexpr long OFF_DH1  = BASE + 5353600;     // [512][100]
static constexpr long OFF_DH2  = BASE + 5404800;     // [512][100]
static constexpr long OFF_MD   = BASE + 5456000;     // dq[4096] mqe[4096u] dk[4096] mke[128u] (dead Aw region)
static constexpr long OFF_AW   = 22233216;           // conv2 A-weights (13824 ush)
static constexpr long OFF_AW3  = 22240128;           // conv3 A-weights (73728 ush)

__device__ inline unsigned short f2bf(float f) {
    unsigned int x = __float_as_uint(f);
    unsigned int r = x + 0x7fffu + ((x >> 16) & 1u);
    return (unsigned short)(r >> 16);
}
__device__ inline float bf2f(unsigned short h) {
    return __uint_as_float((unsigned int)h << 16);
}
// packed RNE f32->bf16 pair: low16 = bf16(a), high16 = bf16(b)  (gfx950)
__device__ inline unsigned int cvtpk(float a, float b) {
    unsigned int r;
    asm("v_cvt_pk_bf16_f32 %0, %1, %2" : "=v"(r) : "v"(a), "v"(b));
    return r;
}
// monotonic f32 <-> u32 encoding for atomicMax over signed floats
__device__ inline unsigned encf(float f) {
    unsigned u = __float_as_uint(f);
    return (u & 0x80000000u) ? ~u : (u | 0x80000000u);
}
__device__ inline float decf(unsigned u) {
    return __uint_as_float((u & 0x80000000u) ? (u & 0x7fffffffu) : ~u);
}

// ============================================================
// Prep A (runs FIRST — only touches non-pool regions):
// Aw(conv2), Aw1(conv1), Aw3(conv3 hi/lo), EL planes.
// ============================================================
static constexpr int NA1 = 13824;                 // Aw
static constexpr int NA2 = NA1 + 1024;            // Aw1
static constexpr int NA3 = NA2 + 73728;           // Aw3
static constexpr int NA4 = NA3 + 1048576;         // EL

__global__ void k_wprepA(const float* __restrict__ w2, const float* __restrict__ w1,
                         const float* __restrict__ w3, const float* __restrict__ elw,
                         unsigned short* __restrict__ Aw, unsigned short* __restrict__ Aw1,
                         unsigned short* __restrict__ Aw3,
                         unsigned short* __restrict__ ELh, unsigned short* __restrict__ ELl)
{
    int i = blockIdx.x * 256 + threadIdx.x;
    if (i < NA1) {
        int ic  = i & 31;
        int m16 = (i >> 5) & 15;
        int emt = i >> 9;
        int mt  = emt % 3, e = emt / 3;
        Aw[i] = f2bf(w2[((mt * 16 + m16) * 32 + ic) * 9 + e]);
    } else if (i < NA2) {
        int j = i - NA1;
        int k = j & 31, m = (j >> 5) & 15, mt = j >> 9;
        Aw1[j] = (k < 9) ? f2bf(w1[(mt * 16 + m) * 9 + k]) : (unsigned short)0;
    } else if (i < NA3) {
        int j = i - NA2;
        int k  = j & 63;
        int m  = (j >> 6) & 15;
        int hl = (j >> 10) & 1;
        int mt = (j >> 11) & 3;
        int e  = j >> 13;
        unsigned short v = 0;
        if (k < 48) {
            float w = w3[((mt * 16 + m) * 48 + k) * 9 + e];
            unsigned short hi = f2bf(w);
            v = hl == 0 ? hi : f2bf(w - bf2f(hi));
        }
        Aw3[j] = v;
    } else if (i < NA4) {
        int j = i - NA3;
        float v = elw[j];
        unsigned short h = f2bf(v);
        ELh[j] = h; ELl[j] = f2bf(v - bf2f(h));
    }
}

// ============================================================
// Prep B (runs AFTER conv3m — targets live in the then-dead pool region):
// P planes (padded to 1536 rows for the 128-tile performer GEMM),
// WQ/WK/WV planes.
// ============================================================
static constexpr int NB1 = 393216;                // P (1536 x 256)
static constexpr int NB2 = NB1 + 1572864;         // WQ/WK/WV

__global__ void k_wprepB(const float* __restrict__ proj,
                         const float* __restrict__ wq, const float* __restrict__ wk,
                         const float* __restrict__ wv,
                         unsigned short* __restrict__ Ph, unsigned short* __restrict__ Pl,
                         unsigned short* __restrict__ Wqkv)
{
    int i = blockIdx.x * 256 + threadIdx.x;
    if (i < NB1) {
        float v = (i < 363264) ? proj[i] : 0.f;
        unsigned short h = f2bf(v);
        Ph[i] = h; Pl[i] = f2bf(v - bf2f(h));
    } else if (i < NB2) {
        int j = i - NB1;
        int y = j / 524288, jj = j % 524288;
        const float* s = (y == 0) ? wq : (y == 1) ? wk : wv;
        float v = s[jj];
        unsigned short h = f2bf(v);
        Wqkv[(long)y * 1048576 + jj] = h;
        Wqkv[(long)y * 1048576 + 524288 + jj] = f2bf(v - bf2f(h));
    }
}

// ============================================================
// Fused conv1 (MFMA, LDS-staged im2col) -> bf16 ring -> conv2 MFMA
// -> in-register bias/relu/maxpool -> bf16 hi/lo pool. (R7 version —
// best measured; R2/R9 proved both occupancy levers net-negative.)
// ============================================================
#define TP 136
__launch_bounds__(256)
__global__ void k_conv12m(const float* __restrict__ train, const float* __restrict__ test,
                          const float* __restrict__ b1,
                          const unsigned short* __restrict__ Aw,
                          const unsigned short* __restrict__ Aw1,
                          const float* __restrict__ b2,
                          unsigned short* __restrict__ pool_out)
{
    const int g   = blockIdx.x;    // 0..7 (pool rows 2g, 2g+1; conv2 rows 4g..4g+3)
    const int img = blockIdx.y;
    const float* in = (img < 512) ? (train + (long)img * 16384)
                                  : (test  + (long)(img - 512) * 16384);

    __shared__ unsigned short ring[9 * 66 * 40];   // 47520 B
    __shared__ unsigned short tile[19 * TP];       // 5168 B: input rows 16g-3..16g+15

    const int t = threadIdx.x;

    for (int i = t; i < 9 * 40; i += 256) {
        int sl = i / 40, icp = i % 40;
        ring[(sl * 66 + 0) * 40 + icp] = 0;
    }
    if (g == 0)
        for (int i = t; i < 66 * 40; i += 256) ring[i] = 0;
    // zero the left halo (cols -2,-1 at tc 2,3) for all 19 rows
    if (t < 19) *(unsigned int*)&tile[t * TP + 2] = 0u;

    // ---- stage: 19 rows x 32 float4 (cols 0..127), packed bf16 ----
    {
        const float4 z4 = make_float4(0.f, 0.f, 0.f, 0.f);
        for (int u = t; u < 19 * 32; u += 256) {
            int row = u >> 5, k = u & 31;
            int r2 = 16 * g - 3 + row;             // never > 127
            float4 v = (r2 >= 0) ? *(const float4*)(in + r2 * 128 + k * 4) : z4;
            uint2 d;
            d.x = cvtpk(v.x, v.y);
            d.y = cvtpk(v.z, v.w);
            *(uint2*)&tile[row * TP + 4 + k * 4] = d;   // tc = c+4, 8B aligned
        }
    }
    __syncthreads();

    const int w    = t >> 6;
    const int lane = t & 63;
    const int cn   = lane & 15;
    const int quad = lane >> 4;

    // conv1 A-frags + per-lane biases (vector loads)
    short8 a1f0 = *(const short8*)&Aw1[(0 * 16 + cn) * 32 + quad * 8];
    short8 a1f1 = *(const short8*)&Aw1[(16 + cn) * 32 + quad * 8];
    float4 bsa = *(const float4*)&b1[quad * 4];
    float4 bsb = *(const float4*)&b1[16 + quad * 4];

    // ---- conv1 rows via MFMA (B-frag from tile; slice sl = conv1 row 8g+sl-1) ----
    const int px2 = w * 16 + cn;
    const int tb  = 2 * px2 + 2;                   // tc of input col 2px-2 (even)
    auto do_slice = [&](int sl) {
        const int rb = 2 * sl * TP + tb;
        uint4 pk = make_uint4(0u, 0u, 0u, 0u);
        if (quad == 0) {
            unsigned int w00 = *(const unsigned int*)&tile[rb];
            unsigned int w10 = *(const unsigned int*)&tile[rb + 2];
            unsigned int w01 = *(const unsigned int*)&tile[rb + TP];
            unsigned int w11 = *(const unsigned int*)&tile[rb + TP + 2];
            unsigned int w02 = *(const unsigned int*)&tile[rb + 2 * TP];
            unsigned int w12 = *(const unsigned int*)&tile[rb + 2 * TP + 2];
            pk.x = (w00 >> 16) | (w10 << 16);              // taps (0,0),(0,1)
            pk.y = (w10 >> 16) | (w01 & 0xffff0000u);      // taps (0,2),(1,0)
            pk.z = w11;                                    // taps (1,1),(1,2)
            pk.w = (w02 >> 16) | (w12 << 16);              // taps (2,0),(2,1)
        } else if (quad == 1) {
            pk.x = (*(const unsigned int*)&tile[rb + 2 * TP + 2]) >> 16;  // tap (2,2)
        }                                          // quads 2,3: taps 16..31 zero
        short8 bfr = *(const short8*)&pk;
        f32x4 z = (f32x4){0.f, 0.f, 0.f, 0.f};
        f32x4 c0 = __builtin_amdgcn_mfma_f32_16x16x32_bf16(a1f0, bfr, z, 0, 0, 0);
        f32x4 c1 = __builtin_amdgcn_mfma_f32_16x16x32_bf16(a1f1, bfr, z, 0, 0, 0);
        uint2 u0, u1;
        u0.x = cvtpk(fmaxf(c0[0] + bsa.x, 0.f), fmaxf(c0[1] + bsa.y, 0.f));
        u0.y = cvtpk(fmaxf(c0[2] + bsa.z, 0.f), fmaxf(c0[3] + bsa.w, 0.f));
        u1.x = cvtpk(fmaxf(c1[0] + bsb.x, 0.f), fmaxf(c1[1] + bsb.y, 0.f));
        u1.y = cvtpk(fmaxf(c1[2] + bsb.z, 0.f), fmaxf(c1[3] + bsb.w, 0.f));
        *(uint2*)&ring[(sl * 66 + px2 + 1) * 40 + quad * 4]      = u0;
        *(uint2*)&ring[(sl * 66 + px2 + 1) * 40 + 16 + quad * 4] = u1;
    };
    if (g > 0) do_slice(0);
    #pragma unroll
    for (int sl = 1; sl < 9; sl++) do_slice(sl);

    // issue e=0 conv2 A-frag loads before the barrier (overlap barrier wait)
    short8 ca0 = *(const short8*)&Aw[((0 * 3 + 0) * 16 + cn) * 32 + quad * 8];
    short8 ca1 = *(const short8*)&Aw[((0 * 3 + 1) * 16 + cn) * 32 + quad * 8];
    short8 ca2 = *(const short8*)&Aw[((0 * 3 + 2) * 16 + cn) * 32 + quad * 8];
    __syncthreads();

    // ---- conv2 MFMA: wave w -> pool row pr=w>>1, half xh=w&1,
    //      both conv2 rows of that pool row; A-frags prefetched 1 e ahead ----
    const int pr = w >> 1, xh = w & 1;
    f32x4 acc[3][2];
    #pragma unroll
    for (int mt = 0; mt < 3; mt++) {
        acc[mt][0] = (f32x4){0.f, 0.f, 0.f, 0.f};
        acc[mt][1] = (f32x4){0.f, 0.f, 0.f, 0.f};
    }

    #pragma unroll
    for (int e = 0; e < 9; e++) {
        int dy = e / 3, dx = e - 3 * dy;
        int c  = 2 * (xh * 16 + cn) + dx;
        int s0 = 4 * pr + dy;
        short8 b0  = *(const short8*)&ring[(s0 * 66 + c) * 40 + quad * 8];
        short8 b1f = *(const short8*)&ring[((s0 + 2) * 66 + c) * 40 + quad * 8];
        short8 na0, na1, na2;
        if (e < 8) {
            na0 = *(const short8*)&Aw[(((e + 1) * 3 + 0) * 16 + cn) * 32 + quad * 8];
            na1 = *(const short8*)&Aw[(((e + 1) * 3 + 1) * 16 + cn) * 32 + quad * 8];
            na2 = *(const short8*)&Aw[(((e + 1) * 3 + 2) * 16 + cn) * 32 + quad * 8];
        }
        acc[0][0] = __builtin_amdgcn_mfma_f32_16x16x32_bf16(ca0, b0,  acc[0][0], 0, 0, 0);
        acc[1][0] = __builtin_amdgcn_mfma_f32_16x16x32_bf16(ca1, b0,  acc[1][0], 0, 0, 0);
        acc[2][0] = __builtin_amdgcn_mfma_f32_16x16x32_bf16(ca2, b0,  acc[2][0], 0, 0, 0);
        acc[0][1] = __builtin_amdgcn_mfma_f32_16x16x32_bf16(ca0, b1f, acc[0][1], 0, 0, 0);
        acc[1][1] = __builtin_amdgcn_mfma_f32_16x16x32_bf16(ca1, b1f, acc[1][1], 0, 0, 0);
        acc[2][1] = __builtin_amdgcn_mfma_f32_16x16x32_bf16(ca2, b1f, acc[2][1], 0, 0, 0);
        if (e < 8) { ca0 = na0; ca1 = na1; ca2 = na2; }
    }

    // ---- in-register bias/relu/2x2-maxpool -> packed hi/lo stores ----
    {
        const int prow = 2 * g + pr;               // pool row 0..15
        const int ppx  = xh * 8 + (cn >> 1);       // pool px 0..15
        unsigned short* pb = pool_out + ((long)img * 256 + prow * 16 + ppx) * 96
                           + ((cn & 1) ? 48 : 0);
        #pragma unroll
        for (int mt = 0; mt < 3; mt++) {
            float4 bv = *(const float4*)&b2[mt * 16 + quad * 4];
            float m0, m1, m2, m3;
            {
                float v;
                v = fmaxf(fmaxf(acc[mt][0][0] + bv.x, acc[mt][1][0] + bv.x), 0.f);
                m0 = fmaxf(v, __shfl_xor(v, 1));
                v = fmaxf(fmaxf(acc[mt][0][1] + bv.y, acc[mt][1][1] + bv.y), 0.f);
                m1 = fmaxf(v, __shfl_xor(v, 1));
                v = fmaxf(fmaxf(acc[mt][0][2] + bv.z, acc[mt][1][2] + bv.z), 0.f);
                m2 = fmaxf(v, __shfl_xor(v, 1));
                v = fmaxf(fmaxf(acc[mt][0][3] + bv.w, acc[mt][1][3] + bv.w), 0.f);
                m3 = fmaxf(v, __shfl_xor(v, 1));
            }
            uint2 hv;
            hv.x = cvtpk(m0, m1);
            hv.y = cvtpk(m2, m3);
            uint2 sv = hv;
            if (cn & 1) {   // odd lane of the pair stores the lo plane
                float d0 = m0 - bf2f((unsigned short)(hv.x & 0xffffu));
                float d1 = m1 - bf2f((unsigned short)(hv.x >> 16));
                float d2 = m2 - bf2f((unsigned short)(hv.y & 0xffffu));
                float d3 = m3 - bf2f((unsigned short)(hv.y >> 16));
                sv.x = cvtpk(d0, d1);
                sv.y = cvtpk(d2, d3);
            }
            *(uint2*)&pb[mt * 16 + quad * 4] = sv;
        }
    }
}

// ============================================================
// conv3 via MFMA hi/lo -> bf16 hi/lo planes [1024][4096]
// ============================================================
#define C3PITCH 104
__launch_bounds__(512)
__global__ void k_conv3m(const unsigned short* __restrict__ pool,
                         const unsigned short* __restrict__ Aw3,
                         const float* __restrict__ b3,
                         unsigned short* __restrict__ C3h, unsigned short* __restrict__ C3l)
{
    const int img = blockIdx.x;
    __shared__ unsigned short s_in[30120];
    const int t = threadIdx.x;

    uint4* s4 = (uint4*)s_in;
    const uint4 zz = make_uint4(0, 0, 0, 0);
    for (int i = t; i < 3765; i += 512) s4[i] = zz;
    __syncthreads();
    {
        int p = t >> 1, half = t & 1;
        const uint4* src = (const uint4*)(pool + ((long)img * 256 + p) * 96 + half * 48);
        int r = p >> 4, c = p & 15;
        uint4* dst = (uint4*)(s_in + ((r + 1) * 17 + (c + 1)) * C3PITCH + half * 48);
        #pragma unroll
        for (int j = 0; j < 6; j++) dst[j] = src[j];
    }
    __syncthreads();

    const int w = t >> 6, lane = t & 63;
    const int n = lane & 15, quad = lane >> 4;
    const int mt = w >> 1, ntb = (w & 1) * 2;

    f32x4 acc[2];
    acc[0] = (f32x4){0.f, 0.f, 0.f, 0.f};
    acc[1] = (f32x4){0.f, 0.f, 0.f, 0.f};

    for (int e = 0; e < 9; e++) {
        int dy = e / 3, dx = e - 3 * dy;
        const unsigned short* A0 = Aw3 + (long)(((e * 4 + mt) * 2 + 0) * 16 + n) * 64 + quad * 8;
        const unsigned short* A1 = Aw3 + (long)(((e * 4 + mt) * 2 + 1) * 16 + n) * 64 + quad * 8;
        short8 ah0 = *(const short8*)(A0);
        short8 ah1 = *(const short8*)(A0 + 32);
        short8 al0 = *(const short8*)(A1);
        short8 al1 = *(const short8*)(A1 + 32);
        #pragma unroll
        for (int j = 0; j < 2; j++) {
            int p = (ntb + j) * 16 + n;
            int y = p >> 3, x = p & 7;
            const unsigned short* Bp = s_in + ((2 * y + dy) * 17 + (2 * x + dx)) * C3PITCH + quad * 8;
            short8 bh0 = *(const short8*)(Bp);
            short8 bh1 = *(const short8*)(Bp + 32);
            short8 bl0 = *(const short8*)(Bp + 48);
            short8 bl1 = *(const short8*)(Bp + 48 + 32);
            acc[j] = __builtin_amdgcn_mfma_f32_16x16x32_bf16(ah0, bh0, acc[j], 0, 0, 0);
            acc[j] = __builtin_amdgcn_mfma_f32_16x16x32_bf16(ah1, bh1, acc[j], 0, 0, 0);
            acc[j] = __builtin_amdgcn_mfma_f32_16x16x32_bf16(ah0, bl0, acc[j], 0, 0, 0);
            acc[j] = __builtin_amdgcn_mfma_f32_16x16x32_bf16(ah1, bl1, acc[j], 0, 0, 0);
            acc[j] = __builtin_amdgcn_mfma_f32_16x16x32_bf16(al0, bh0, acc[j], 0, 0, 0);
            acc[j] = __builtin_amdgcn_mfma_f32_16x16x32_bf16(al1, bh1, acc[j], 0, 0, 0);
        }
    }

    unsigned short* oh = C3h + (long)img * 4096;
    unsigned short* ol = C3l + (long)img * 4096;
    #pragma unroll
    for (int reg = 0; reg < 4; reg++) {
        int oc = mt * 16 + quad * 4 + reg;
        float bias = b3[oc];
        #pragma unroll
        for (int j = 0; j < 2; j++) {
            int p = (ntb + j) * 16 + n;
            float v = fmaxf(acc[j][reg] + bias, 0.f);
            unsigned short h = f2bf(v);
            oh[oc * 64 + p] = h;
            ol[oc * 64 + p] = f2bf(v - bf2f(h));
        }
    }
}

// ============================================================
// bf16 hi/lo MFMA GEMM (3-term, ~fp32). OUTMODE 0: f32 out (z-batch over
// X/W/B/Y strides); 1: hi/lo plane out (z-batch); 3: split-K chunks.
// ============================================================
template<int OUTMODE>
__launch_bounds__(256)
__global__ void mgemm(const unsigned short* __restrict__ Xh0, const unsigned short* __restrict__ Xl0,
                      const unsigned short* __restrict__ Wph, const unsigned short* __restrict__ Wpl,
                      const float* __restrict__ Bb, float* __restrict__ Yf,
                      unsigned short* __restrict__ Yh, unsigned short* __restrict__ Yl,
                      int M, int N, int K, int ldY, float scale,
                      long sX, long sW, long sB, long sY, int kChunk)
{
    const int z = blockIdx.z;
    const unsigned short* Xh = Xh0 + (OUTMODE == 3 ? 0 : (long)z * sX);
    const unsigned short* Xl = Xl0 + (OUTMODE == 3 ? 0 : (long)z * sX);
    const unsigned short* Wh = Wph + (OUTMODE == 3 ? 0 : (long)z * sW);
    const unsigned short* Wl = Wpl + (OUTMODE == 3 ? 0 : (long)z * sW);
    const float* B = Bb ? (Bb + (OUTMODE == 3 ? 0 : (long)z * sB)) : nullptr;
    int k0 = 0, k1 = K;
    if (OUTMODE == 3) { k0 = z * kChunk; k1 = min(K, k0 + kChunk); }

    __shared__ unsigned short sAh[64 * 40], sAl[64 * 40], sBh[64 * 40], sBl[64 * 40];

    const int t = threadIdx.x;
    const int m0 = blockIdx.y * 64, n0 = blockIdx.x * 64;
    const int r = t >> 2, kq = (t & 3) * 8;

    const int w = t >> 6, lane = t & 63;
    const int wm = (w & 1) * 32, wn = (w >> 1) * 32;
    const int cn = lane & 15, quad = lane >> 4;

    f32x4 acc[2][2];
    acc[0][0] = acc[0][1] = acc[1][0] = acc[1][1] = (f32x4){0.f, 0.f, 0.f, 0.f};

    for (int kb = k0; kb < k1; kb += 32) {
        *(uint4*)&sAh[r * 40 + kq] = *(const uint4*)&Xh[(long)(m0 + r) * K + kb + kq];
        *(uint4*)&sAl[r * 40 + kq] = *(const uint4*)&Xl[(long)(m0 + r) * K + kb + kq];
        *(uint4*)&sBh[r * 40 + kq] = *(const uint4*)&Wh[(long)(n0 + r) * K + kb + kq];
        *(uint4*)&sBl[r * 40 + kq] = *(const uint4*)&Wl[(long)(n0 + r) * K + kb + kq];
        __syncthreads();
        short8 axh[2], axl[2], bxh[2], bxl[2];
        #pragma unroll
        for (int i = 0; i < 2; i++) {
            axh[i] = *(const short8*)&sAh[(wm + i * 16 + cn) * 40 + quad * 8];
            axl[i] = *(const short8*)&sAl[(wm + i * 16 + cn) * 40 + quad * 8];
            bxh[i] = *(const short8*)&sBh[(wn + i * 16 + cn) * 40 + quad * 8];
            bxl[i] = *(const short8*)&sBl[(wn + i * 16 + cn) * 40 + quad * 8];
        }
        #pragma unroll
        for (int i = 0; i < 2; i++)
            #pragma unroll
            for (int j = 0; j < 2; j++) {
                acc[i][j] = __builtin_amdgcn_mfma_f32_16x16x32_bf16(axh[i], bxh[j], acc[i][j], 0, 0, 0);
                acc[i][j] = __builtin_amdgcn_mfma_f32_16x16x32_bf16(axh[i], bxl[j], acc[i][j], 0, 0, 0);
                acc[i][j] = __builtin_amdgcn_mfma_f32_16x16x32_bf16(axl[i], bxh[j], acc[i][j], 0, 0, 0);
            }
        __syncthreads();
    }

    #pragma unroll
    for (int i = 0; i < 2; i++) {
        #pragma unroll
        for (int reg = 0; reg < 4; reg++) {
            int row = m0 + wm + i * 16 + quad * 4 + reg;
            #pragma unroll
            for (int j = 0; j < 2; j++) {
                int col = n0 + wn + j * 16 + cn;
                if (col >= N) continue;
                float v = acc[i][j][reg] * scale;
                if (OUTMODE == 3) {
                    (Yf + (long)z * sY)[(long)row * ldY + col] = v;
                } else if (OUTMODE == 0) {
                    if (B) v += B[col];
                    (Yf + (long)z * sY)[(long)row * ldY + col] = v;
                } else {
                    if (B) v += B[col];
                    unsigned short h = f2bf(v);
                    (Yh + (long)z * sY)[(long)row * ldY + col] = h;
                    (Yl + (long)z * sY)[(long)row * ldY + col] = f2bf(v - bf2f(h));
                }
            }
        }
    }
}

// ============================================================
// mgemm128: 128x128-tile 3-term bf16 hi/lo GEMM for the performer
// features (f32 out, fused row/tile max). grid (ceil(N/128), M/128, 2):
// z=0 -> q (per-row max -> mqe), z=1 -> k (per-32-row-tile max -> mke).
// Per wave/K-step: 16 ds_read_b128 feed 48 MFMAs (3:1, vs 1.5:1 at 64²).
// W rows padded to 1536 (wprepB) so B-tile staging never reads OOB.
// ============================================================
__launch_bounds__(256)
__global__ void mgemm128(const unsigned short* __restrict__ Xh0, const unsigned short* __restrict__ Xl0,
                         const unsigned short* __restrict__ Wh, const unsigned short* __restrict__ Wl,
                         float* __restrict__ Yf, int M, int N, int K, int ldY, float scale,
                         long sX, long sY,
                         unsigned* __restrict__ mqe, unsigned* __restrict__ mke)
{
    const int z = blockIdx.z;
    const unsigned short* Xh = Xh0 + (long)z * sX;
    const unsigned short* Xl = Xl0 + (long)z * sX;

    __shared__ unsigned short sAh[128 * 40], sAl[128 * 40], sBh[128 * 40], sBl[128 * 40];

    const int t = threadIdx.x;
    const int m0 = blockIdx.y * 128, n0 = blockIdx.x * 128;
    const int r = t >> 1, kq = (t & 1) * 16;       // each thread: 16 ush (2 uint4) of one row

    const int w = t >> 6, lane = t & 63;
    const int wm = (w & 1) * 64, wn = (w >> 1) * 64;
    const int cn = lane & 15, quad = lane >> 4;

    f32x4 acc[4][4];
    #pragma unroll
    for (int i = 0; i < 4; i++)
        #pragma unroll
        for (int j = 0; j < 4; j++) acc[i][j] = (f32x4){0.f, 0.f, 0.f, 0.f};

    for (int kb = 0; kb < K; kb += 32) {
        *(uint4*)&sAh[r * 40 + kq]     = *(const uint4*)&Xh[(long)(m0 + r) * K + kb + kq];
        *(uint4*)&sAh[r * 40 + kq + 8] = *(const uint4*)&Xh[(long)(m0 + r) * K + kb + kq + 8];
        *(uint4*)&sAl[r * 40 + kq]     = *(const uint4*)&Xl[(long)(m0 + r) * K + kb + kq];
        *(uint4*)&sAl[r * 40 + kq + 8] = *(const uint4*)&Xl[(long)(m0 + r) * K + kb + kq + 8];
        *(uint4*)&sBh[r * 40 + kq]     = *(const uint4*)&Wh[(long)(n0 + r) * K + kb + kq];
        *(uint4*)&sBh[r * 40 + kq + 8] = *(const uint4*)&Wh[(long)(n0 + r) * K + kb + kq + 8];
        *(uint4*)&sBl[r * 40 + kq]     = *(const uint4*)&Wl[(long)(n0 + r) * K + kb + kq];
        *(uint4*)&sBl[r * 40 + kq + 8] = *(const uint4*)&Wl[(long)(n0 + r) * K + kb + kq + 8];
        __syncthreads();
        short8 axh[4], axl[4], bxh[4], bxl[4];
        #pragma unroll
        for (int i = 0; i < 4; i++) {
            axh[i] = *(const short8*)&sAh[(wm + i * 16 + cn) * 40 + quad * 8];
            axl[i] = *(const short8*)&sAl[(wm + i * 16 + cn) * 40 + quad * 8];
            bxh[i] = *(const short8*)&sBh[(wn + i * 16 + cn) * 40 + quad * 8];
            bxl[i] = *(const short8*)&sBl[(wn + i * 16 + cn) * 40 + quad * 8];
        }
        #pragma unroll
        for (int i = 0; i < 4; i++)
            #pragma unroll
            for (int j = 0; j < 4; j++) {
                acc[i][j] = __builtin_amdgcn_mfma_f32_16x16x32_bf16(axh[i], bxh[j], acc[i][j], 0, 0, 0);
                acc[i][j] = __builtin_amdgcn_mfma_f32_16x16x32_bf16(axh[i], bxl[j], acc[i][j], 0, 0, 0);
                acc[i][j] = __builtin_amdgcn_mfma_f32_16x16x32_bf16(axl[i], bxh[j], acc[i][j], 0, 0, 0);
            }
        __syncthreads();
    }

    float gmax0 = -3e38f, gmax1 = -3e38f;          // per 32-row half of the wave's 64 rows
    #pragma unroll
    for (int i = 0; i < 4; i++) {
        #pragma unroll
        for (int reg = 0; reg < 4; reg++) {
            int row = m0 + wm + i * 16 + quad * 4 + reg;
            float rmax = -3e38f;
            #pragma unroll
            for (int j = 0; j < 4; j++) {
                int col = n0 + wn + j * 16 + cn;
                if (col >= N) continue;
                float v = acc[i][j][reg] * scale;
                (Yf + (long)z * sY)[(long)row * ldY + col] = v;
                rmax = fmaxf(rmax, v);
            }
            if (z == 0) {
                rmax = fmaxf(rmax, __shfl_xor(rmax, 1));
                rmax = fmaxf(rmax, __shfl_xor(rmax, 2));
                rmax = fmaxf(rmax, __shfl_xor(rmax, 4));
                rmax = fmaxf(rmax, __shfl_xor(rmax, 8));
                if (cn == 0) atomicMax(&mqe[row], encf(rmax));
            } else {
                if (i < 2) gmax0 = fmaxf(gmax0, rmax);
                else       gmax1 = fmaxf(gmax1, rmax);
            }
        }
    }
    if (z == 1) {
        for (int d = 1; d < 64; d <<= 1) {
            gmax0 = fmaxf(gmax0, __shfl_xor(gmax0, d));
            gmax1 = fmaxf(gmax1, __shfl_xor(gmax1, d));
        }
        if (lane == 0) {
            atomicMax(&mke[(m0 + wm) >> 5],       encf(gmax0));
            atomicMax(&mke[((m0 + wm) >> 5) + 1], encf(gmax1));
        }
    }
}

// ============================================================
// k_qkv: Q/K/V projections in ONE launch, grid (4, 8, 24).
// z 0..7 = Q heads (x_qry, planes out + diag), 8..15 = K heads (x_ctx,
// planes + diag), 16..23 = V heads (rs, f32 out). diag = sum(v^2)/32
// atomicAdd'd per token row (MD region zeroed in k_red_enc).
// ============================================================
__launch_bounds__(256)
__global__ void k_qkv(const unsigned short* __restrict__ XCh, const unsigned short* __restrict__ XCl,
                      const unsigned short* __restrict__ RSh, const unsigned short* __restrict__ RSl,
                      const unsigned short* __restrict__ Wqkv,
                      const float* __restrict__ wqb, const float* __restrict__ wkb,
                      const float* __restrict__ wvb,
                      unsigned short* __restrict__ Qh, unsigned short* __restrict__ Ql,
                      unsigned short* __restrict__ Kh, unsigned short* __restrict__ Kl,
                      float* __restrict__ v_all, float* __restrict__ dq, float* __restrict__ dk)
{
    const int z = blockIdx.z, y = z >> 3, zh = z & 7;
    const unsigned short* Xh = (y == 0) ? XCh + 512 * 256 : (y == 1) ? XCh : RSh;
    const unsigned short* Xl = (y == 0) ? XCl + 512 * 256 : (y == 1) ? XCl : RSl;
    const unsigned short* Wh = Wqkv + (long)y * 1048576 + (long)zh * 65536;
    const unsigned short* Wl = Wh + 524288;
    const float* B = ((y == 0) ? wqb : (y == 1) ? wkb : wvb) + zh * 256;

    __shared__ unsigned short sAh[64 * 40], sAl[64 * 40], sBh[64 * 40], sBl[64 * 40];

    const int t = threadIdx.x;
    const int m0 = blockIdx.y * 64, n0 = blockIdx.x * 64;
    const int r = t >> 2, kq = (t & 3) * 8;
    const int w = t >> 6, lane = t & 63;
    const int wm = (w & 1) * 32, wn = (w >> 1) * 32;
    const int cn = lane & 15, quad = lane >> 4;

    f32x4 acc[2][2];
    acc[0][0] = acc[0][1] = acc[1][0] = acc[1][1] = (f32x4){0.f, 0.f, 0.f, 0.f};

    for (int kb = 0; kb < 256; kb += 32) {
        *(uint4*)&sAh[r * 40 + kq] = *(const uint4*)&Xh[(long)(m0 + r) * 256 + kb + kq];
        *(uint4*)&sAl[r * 40 + kq] = *(const uint4*)&Xl[(long)(m0 + r) * 256 + kb + kq];
        *(uint4*)&sBh[r * 40 + kq] = *(const uint4*)&Wh[(long)(n0 + r) * 256 + kb + kq];
        *(uint4*)&sBl[r * 40 + kq] = *(const uint4*)&Wl[(long)(n0 + r) * 256 + kb + kq];
        __syncthreads();
        short8 axh[2], axl[2], bxh[2], bxl[2];
        #pragma unroll
        for (int i = 0; i < 2; i++) {
            axh[i] = *(const short8*)&sAh[(wm + i * 16 + cn) * 40 + quad * 8];
            axl[i] = *(const short8*)&sAl[(wm + i * 16 + cn) * 40 + quad * 8];
            bxh[i] = *(const short8*)&sBh[(wn + i * 16 + cn) * 40 + quad * 8];
            bxl[i] = *(const short8*)&sBl[(wn + i * 16 + cn) * 40 + quad * 8];
        }
        #pragma unroll
        for (int i = 0; i < 2; i++)
            #pragma unroll
            for (int j = 0; j < 2; j++) {
                acc[i][j] = __builtin_amdgcn_mfma_f32_16x16x32_bf16(axh[i], bxh[j], acc[i][j], 0, 0, 0);
                acc[i][j] = __builtin_amdgcn_mfma_f32_16x16x32_bf16(axh[i], bxl[j], acc[i][j], 0, 0, 0);
                acc[i][j] = __builtin_amdgcn_mfma_f32_16x16x32_bf16(axl[i], bxh[j], acc[i][j], 0, 0, 0);
            }
        __syncthreads();
    }

    unsigned short* Yh = ((y == 0) ? Qh : Kh) + (long)zh * 131072;
    unsigned short* Yl = ((y == 0) ? Ql : Kl) + (long)zh * 131072;
    float* Yf = v_all + (long)zh * 131072;
    float* dacc = ((y == 0) ? dq : dk) + zh * 512;

    #pragma unroll
    for (int i = 0; i < 2; i++) {
        #pragma unroll
        for (int reg = 0; reg < 4; reg++) {
            int row = m0 + wm + i * 16 + quad * 4 + reg;
            float s = 0.f;
            #pragma unroll
            for (int j = 0; j < 2; j++) {
                int col = n0 + wn + j * 16 + cn;
                float v = acc[i][j][reg] + B[col];
                if (y == 2) {
                    Yf[(long)row * 256 + col] = v;
                } else {
                    unsigned short h = f2bf(v);
                    Yh[(long)row * 256 + col] = h;
                    Yl[(long)row * 256 + col] = f2bf(v - bf2f(h));
                    s += v * v;
                }
            }
            if (y < 2) {
                s += __shfl_xor(s, 1); s += __shfl_xor(s, 2);
                s += __shfl_xor(s, 4); s += __shfl_xor(s, 8);
                if (cn == 0) atomicAdd(&dacc[row], s * (1.f / 32.f));
            }
        }
    }
}

// ============================================================
// reducers for split-K temps (fused with small jobs to cut launches)
// k_red_enc grid 3249: [0,1024) enc reduce; [1024,1152) label embed;
// [1152,3200) wo -> hi/lo planes; [3200,3249) zero MD (diag/max buffers).
// ============================================================
__global__ void k_red_enc(const float* __restrict__ tmp, const float* __restrict__ elb,
                          float* __restrict__ x_ctx, unsigned short* __restrict__ XCh,
                          unsigned short* __restrict__ XCl, float* __restrict__ xcat,
                          const float* __restrict__ label, const float* __restrict__ tyw,
                          const float* __restrict__ tyb,
                          const float* __restrict__ wow, unsigned short* __restrict__ WOh,
                          unsigned short* __restrict__ WOl, unsigned* __restrict__ md)
{
    int b = blockIdx.x;
    int tt = threadIdx.x;
    if (b < 1024) {
        int i = b * 256 + tt;                 // 262144
        int r = i >> 8, c = i & 255;
        float v = elb[c];
        #pragma unroll
        for (int z = 0; z < 8; z++) v += tmp[(long)z * 262144 + i];
        x_ctx[i] = v;
        unsigned short h = f2bf(v);
        XCh[i] = h; XCl[i] = f2bf(v - bf2f(h));
        if (r < 512) xcat[r * 320 + c] = v;
    } else if (b < 1152) {
        int i = (b - 1024) * 256 + tt;        // 32768
        int r = i >> 6, e = i & 63;
        xcat[r * 320 + 256 + e] = tyb[e] + label[r * 2] * tyw[e * 2] + label[r * 2 + 1] * tyw[e * 2 + 1];
    } else if (b < 3200) {
        int i = (b - 1152) * 256 + tt;        // 524288
        float v = wow[i];
        unsigned short h = f2bf(v);
        WOh[i] = h; WOl[i] = f2bf(v - bf2f(h));
    } else {
        int i = (b - 3200) * 256 + tt;        // 12416 (dq,mqe,dk,mke)
        if (i < 12416) md[i] = 0u;
    }
}

// k_red_rep grid 1024: [0,512) rep reduce (8 chunks); [512,1024) xz col copy.
__global__ void k_red_rep(const float* __restrict__ tmp, const float* __restrict__ wob,
                          float* __restrict__ rep,
                          const float* __restrict__ xq, float* __restrict__ xz)
{
    int b = blockIdx.x;
    int tt = threadIdx.x;
    if (b < 512) {
        int i = b * 256 + tt;                 // 131072
        int c = i & 255;
        float v = wob[c];
        #pragma unroll
        for (int z = 0; z < 8; z++) v += tmp[(long)z * 131072 + i];
        rep[i] = v;
    } else {
        int i = (b - 512) * 256 + tt;         // 131072
        int r = i >> 8, c = i & 255;
        xz[r * 384 + c] = xq[i];
    }
}

// ============================================================
// Generic fp32 GEMM (small layers), float2 inner loads.
// WP: also emit bf16 hi/lo planes of the output (used for rs).
// ============================================================
template<int BM, int BN, int BK, int ACT, bool FIN, bool WP>
__launch_bounds__(256)
__global__ void gemm_k(const float* __restrict__ X, const float* __restrict__ W,
                       const float* __restrict__ B, float* __restrict__ Y,
                       int M, int N, int K, int ldY,
                       unsigned short* __restrict__ Ph2, unsigned short* __restrict__ Pl2)
{
    __shared__ float As[BK][BM + 4];
    __shared__ float Bs[BK][BN + 4];
    const int t = threadIdx.x;
    const int tx = t & 15, ty = t >> 4;
    const int m0 = blockIdx.y * BM, n0 = blockIdx.x * BN;
    float acc[2][2] = {{0.f, 0.f}, {0.f, 0.f}};

    for (int kb = 0; kb < K; kb += BK) {
        for (int i = t; i < BM * BK; i += 256) {
            int rr = i / BK, c = i % BK;
            int mm = m0 + rr, kk = kb + c;
            As[c][rr] = (mm < M && kk < K) ? X[(long)mm * K + kk] : 0.f;
        }
        for (int i = t; i < BN * BK; i += 256) {
            int rr = i / BK, c = i % BK;
            int nn = n0 + rr, kk = kb + c;
            Bs[c][rr] = (nn < N && kk < K) ? W[(long)nn * K + kk] : 0.f;
        }
        __syncthreads();
        #pragma unroll
        for (int kk = 0; kk < BK; kk++) {
            float2 a2 = *(const float2*)&As[kk][ty * 2];
            float2 b2 = *(const float2*)&Bs[kk][tx * 2];
            acc[0][0] += a2.x * b2.x; acc[0][1] += a2.x * b2.y;
            acc[1][0] += a2.y * b2.x; acc[1][1] += a2.y * b2.y;
        }
        __syncthreads();
    }

    #pragma unroll
    for (int i = 0; i < 2; i++) {
        int mm = m0 + ty * 2 + i;
        if (mm >= M) continue;
        #pragma unroll
        for (int j = 0; j < 2; j++) {
            int nn = n0 + tx * 2 + j;
            if (nn >= N) continue;
            float v = acc[i][j] + (B ? B[nn] : 0.f);
            if (ACT == 1) v = fmaxf(v, 0.f);
            if (ACT == 2) v = tanhf(v);
            Y[(long)mm * ldY + nn] = v;
            if (WP) {
                unsigned short h = f2bf(v);
                Ph2[(long)mm * ldY + nn] = h;
                Pl2[(long)mm * ldY + nn] = f2bf(v - bf2f(h));
            }
        }
    }
    if (FIN && t == 0 && blockIdx.x == 0 && blockIdx.y == 0) Y[1024] = 0.f;
}

// ============================================================
// k_attn1: feature-split QK^T with fused exp. grid (NSPLIT=4, 128).
// Each block: features [s*355, min(1419,(s+1)*355)) of one (h,t) tile;
// partial A[32][32] -> pA[kb][s][1024]. LDS pitch 65 (conflict-free).
// shifts: dq + decode(mqe) per q-row; dk + decode(mke[kb]) per k-row.
// ============================================================
#define NSPLIT 4
#define FCH 355
__launch_bounds__(256)
__global__ void k_attn1(const float* __restrict__ qp, const float* __restrict__ kp,
                        const float* __restrict__ dq, const unsigned* __restrict__ mqe,
                        const float* __restrict__ dk, const unsigned* __restrict__ mke,
                        float* __restrict__ pA)
{
    const int s  = blockIdx.x;        // 0..3 feature split
    const int kb = blockIdx.y;        // 0..127 tile
    const long row0 = (long)kb * 32;
    const int f0 = s * FCH;
    const int f1 = min(F_FEAT, f0 + FCH);

    __shared__ float s_q[32 * 65];
    __shared__ float s_k[32 * 65];
    __shared__ float s_cq[32], s_ck[32];

    const int t = threadIdx.x;
    const int n = t >> 3;
    const int mq_ = (t & 7) * 4;

    if (t < 32) {
        s_cq[t] = dq[row0 + t] + decf(mqe[row0 + t]);
        s_ck[t] = dk[row0 + t] + decf(mke[kb]);
    }
    __syncthreads();

    float acc[4] = {0.f, 0.f, 0.f, 0.f};
    for (int fc = f0; fc < f1; fc += 64) {
        for (int i = t; i < 2048; i += 256) {
            int rr = i >> 6, ff = i & 63;
            int fg = fc + ff;
            float qv = 0.f, kv = 0.f;
            if (fg < f1) {
                qv = __expf(qp[(row0 + rr) * F_FEAT + fg] - s_cq[rr]) + 1e-4f;
                kv = __expf(kp[(row0 + rr) * F_FEAT + fg] - s_ck[rr]) + 1e-4f;
            }
            s_q[rr * 65 + ff] = qv;
            s_k[rr * 65 + ff] = kv;
        }
        __syncthreads();
        #pragma unroll 8
        for (int ff = 0; ff < 64; ff++) {
            float a = s_q[n * 65 + ff];
            #pragma unroll
            for (int j = 0; j < 4; j++) acc[j] += a * s_k[(mq_ + j) * 65 + ff];
        }
        __syncthreads();
    }

    float* dst = pA + ((long)kb * NSPLIT + s) * 1024;
    #pragma unroll
    for (int j = 0; j < 4; j++) dst[n * 32 + mq_ + j] = acc[j];
}

// ============================================================
// k_attn2: reduce partial A + rowsum + PV chunk -> REP planes.
// grid (4 e-chunks, 128 tiles).
// ============================================================
__launch_bounds__(256)
__global__ void k_attn2(const float* __restrict__ pA, const float* __restrict__ va,
                        unsigned short* __restrict__ REPh, unsigned short* __restrict__ REPl)
{
    const int ec = blockIdx.x;        // 0..3, 64 output cols each
    const int kb = blockIdx.y;        // 0..127
    const int h = kb >> 4, tt = kb & 15;
    const long row0 = (long)kb * 32;

    __shared__ float s_A[32][33];
    __shared__ float s_di[32];
    __shared__ float s_v[32 * 64];

    const int t = threadIdx.x;

    // reduce NSPLIT partials, 4 A-elements per thread (float4 loads)
    {
        const float* base = pA + (long)kb * NSPLIT * 1024 + t * 4;
        float4 v0 = *(const float4*)(base);
        float4 v1 = *(const float4*)(base + 1024);
        float4 v2 = *(const float4*)(base + 2048);
        float4 v3 = *(const float4*)(base + 3072);
        int r = t >> 3, c = (t & 7) * 4;
        s_A[r][c]     = v0.x + v1.x + v2.x + v3.x;
        s_A[r][c + 1] = v0.y + v1.y + v2.y + v3.y;
        s_A[r][c + 2] = v0.z + v1.z + v2.z + v3.z;
        s_A[r][c + 3] = v0.w + v1.w + v2.w + v3.w;
    }
    // stage V chunk (coalesced)
    for (int i = t; i < 2048; i += 256) {
        int m = i >> 6, e = i & 63;
        s_v[m * 64 + e] = va[row0 * 256 + m * 256 + ec * 64 + e];
    }
    __syncthreads();
    if (t < 32) {
        float s = 0.f;
        #pragma unroll
        for (int m = 0; m < 32; m++) s += s_A[t][m];
        s_di[t] = 1.f / s;
    }
    __syncthreads();

    const int n = t >> 3, e0 = t & 7;
    float out[8];
    #pragma unroll
    for (int j = 0; j < 8; j++) out[j] = 0.f;
    for (int m = 0; m < 32; m++) {
        float a = s_A[n][m];
        #pragma unroll
        for (int j = 0; j < 8; j++) out[j] += a * s_v[m * 64 + e0 + 8 * j];
    }
    float di = s_di[n];
    unsigned short* dsth = REPh + ((long)tt * 32 + n) * 2048;
    unsigned short* dstl = REPl + ((long)tt * 32 + n) * 2048;
    #pragma unroll
    for (int j = 0; j < 8; j++) {
        int e = ec * 64 + e0 + 8 * j;
        float val = out[j] * di;
        unsigned short hh = f2bf(val);
        dsth[e * 8 + h] = hh;
        dstl[e * 8 + h] = f2bf(val - bf2f(hh));
    }
}

// ============================================================
extern "C" void kernel_launch(void* const* d_in, const int* in_sizes, int n_in,
                              void* d_out, int out_size, void* d_ws, size_t ws_size,
                              hipStream_t stream)
{
    const float* train  = (const float*)d_in[0];
    const float* label  = (const float*)d_in[1];
    const float* test   = (const float*)d_in[2];
    const float* c1w = (const float*)d_in[3];  const float* c1b = (const float*)d_in[4];
    const float* c2w = (const float*)d_in[5];  const float* c2b = (const float*)d_in[6];
    const float* c3w = (const float*)d_in[7];  const float* c3b = (const float*)d_in[8];
    const float* elw = (const float*)d_in[9];  const float* elb = (const float*)d_in[10];
    const float* tyw = (const float*)d_in[11]; const float* tyb = (const float*)d_in[12];
    const float* ew1 = (const float*)d_in[13]; const float* eb1 = (const float*)d_in[14];
    const float* ew2 = (const float*)d_in[15]; const float* eb2 = (const float*)d_in[16];
    const float* ew3 = (const float*)d_in[17]; const float* eb3 = (const float*)d_in[18];
    const float* wq  = (const float*)d_in[19]; const float* wqb = (const float*)d_in[20];
    const float* wk  = (const float*)d_in[21]; const float* wkb = (const float*)d_in[22];
    const float* wv  = (const float*)d_in[23]; const float* wvb = (const float*)d_in[24];
    const float* wow = (const float*)d_in[25]; const float* wob = (const float*)d_in[26];
    const float* rzw = (const float*)d_in[27]; const float* rzb = (const float*)d_in[28];
    const float* dw1 = (const float*)d_in[29]; const float* db1 = (const float*)d_in[30];
    const float* dw2 = (const float*)d_in[31]; const float* db2 = (const float*)d_in[32];
    const float* dw3 = (const float*)d_in[33]; const float* db3 = (const float*)d_in[34];
    const float* proj= (const float*)d_in[35];

    float* wsf = (float*)d_ws;
    unsigned short* usw = (unsigned short*)d_ws;
    float* out = (float*)d_out;

    unsigned short* A_pool = usw;                 // pool at ush offset 0 (dead after conv3m)
    float* x_ctx  = wsf + OFF_XCTX;
    float* x_qry  = wsf + OFF_XQRY;
    float* xcat   = wsf + OFF_XCAT;
    float* h1     = wsf + OFF_H1;
    float* h2     = wsf + OFF_H2;
    float* rs     = wsf + OFF_RS;
    float* v_all  = wsf + OFF_VA;
    float* rep    = wsf + OFF_REP;
    float* xz     = wsf + OFF_XZ;
    float* dh1    = wsf + OFF_DH1;
    float* dh2    = wsf + OFF_DH2;
    float* xd_q   = wsf + OFF_XDQ;
    float* xd_k   = wsf + OFF_XDK;
    float* enc_t  = wsf + OFF_ENCT;
    float* rep_t  = wsf + OFF_REPT;
    float* pA     = wsf + OFF_PA;
    float* dqv    = wsf + OFF_MD;
    unsigned* mqe = (unsigned*)(wsf + OFF_MD + 4096);
    float* dkv    = wsf + OFF_MD + 8192;
    unsigned* mke = (unsigned*)(wsf + OFF_MD + 12288);
    unsigned* mdw = (unsigned*)(wsf + OFF_MD);
    unsigned short* Aw  = (unsigned short*)(wsf + OFF_AW);
    unsigned short* Aw3 = (unsigned short*)(wsf + OFF_AW3);
    unsigned short* Aw1 = (unsigned short*)(wsf + OFF_AW1);

    unsigned short* Wqkv = usw + U_WQH;
    unsigned short* Ph  = usw + U_PH;  unsigned short* Pl  = usw + U_PL;
    unsigned short* XCh = usw + U_XCH; unsigned short* XCl = usw + U_XCL;
    unsigned short* RSh = usw + U_RSH; unsigned short* RSl = usw + U_RSL;
    unsigned short* C3h = usw + U_C3H; unsigned short* C3l = usw + U_C3L;
    unsigned short* Qh  = usw + U_QH;  unsigned short* Ql  = usw + U_QL;
    unsigned short* Kh  = usw + U_KH;  unsigned short* Kl  = usw + U_KL;
    unsigned short* ELh = usw + U_ELH; unsigned short* ELl = usw + U_ELL;
    unsigned short* WOh = usw + U_WOH; unsigned short* WOl = usw + U_WOL;
    unsigned short* REPh= usw + U_REPH;unsigned short* REPl= usw + U_REPL;

    // 1. prep A: Aw/Aw1/Aw3/EL (non-pool regions only)
    k_wprepA<<<4442, 256, 0, stream>>>(c2w, c1w, c3w, elw, Aw, Aw1, Aw3, ELh, ELl);

    // 2-3. encoder convs
    k_conv12m<<<dim3(8, 1024), 256, 0, stream>>>(train, test, c1b, Aw, Aw1, c2b, A_pool);
    k_conv3m<<<1024, 512, 0, stream>>>(A_pool, Aw3, c3b, C3h, C3l);

    // 4. prep B: P (padded 1536 rows) + WQKV planes into the dead pool region
    k_wprepB<<<7680, 256, 0, stream>>>(proj, wq, wk, wv, Ph, Pl, Wqkv);

    // 5-6. enc linear split-K=8 into temps, then fused reduce (+bias, planes,
    //      xcat copy) + label embed + wo planes + MD zero (Aw dead after step 3)
    mgemm<3><<<dim3(4, 16, 8), 256, 0, stream>>>(
        C3h, C3l, ELh, ELl, nullptr, enc_t, nullptr, nullptr,
        1024, 256, 4096, 256, 1.f, 0, 0, 0, 262144, 512);
    k_red_enc<<<3249, 256, 0, stream>>>(enc_t, elb, x_ctx, XCh, XCl, xcat,
                                        label, tyw, tyb, wow, WOh, WOl, mdw);

    // 7-9. er MLP -> rs (last layer also emits RS planes)
    gemm_k<32,32,32,1,false,false><<<dim3(8, 16), 256, 0, stream>>>(xcat, ew1, eb1, h1, 512, 256, 320, 256, nullptr, nullptr);
    gemm_k<32,32,32,1,false,false><<<dim3(8, 16), 256, 0, stream>>>(h1, ew2, eb2, h2, 512, 256, 256, 256, nullptr, nullptr);
    gemm_k<32,32,32,0,false,true ><<<dim3(8, 16), 256, 0, stream>>>(h2, ew3, eb3, rs, 512, 256, 256, 256, RSh, RSl);

    // 10. q/k/v projections in one launch (+fused diag for Q/K)
    k_qkv<<<dim3(4, 8, 24), 256, 0, stream>>>(XCh, XCl, RSh, RSl, Wqkv,
                                              wqb, wkb, wvb, Qh, Ql, Kh, Kl,
                                              v_all, dqv, dkv);

    // 11. performer features (z=2), 128x128-tile GEMM + fused row/tile max
    mgemm128<<<dim3(12, 32, 2), 256, 0, stream>>>(
        Qh, Ql, Ph, Pl, xd_q,
        4096, F_FEAT, 256, F_FEAT, DN, 2097152, 5812224, mqe, mke);

    // 12-13. attention: feature-split QK^T (fused exp) -> partial A; reduce+PV
    k_attn1<<<dim3(NSPLIT, 128), 256, 0, stream>>>(xd_q, xd_k, dqv, mqe, dkv, mke, pA);
    k_attn2<<<dim3(4, 128), 256, 0, stream>>>(pA, v_all, REPh, REPl);

    // 14-15. rep = rep_in @ wo^T + b : split-K=8 temps + fused reduce + xz copy
    mgemm<3><<<dim3(4, 8, 8), 256, 0, stream>>>(
        REPh, REPl, WOh, WOl, nullptr, rep_t, nullptr, nullptr,
        512, 256, 2048, 256, 1.f, 0, 0, 0, 131072, 256);
    k_red_rep<<<1024, 256, 0, stream>>>(rep_t, wob, rep, x_qry, xz);

    // 16. xz cols 256..383 = rep @ rz^T + b
    gemm_k<32,32,32,0,false,false><<<dim3(4, 16), 256, 0, stream>>>(rep, rzw, rzb, xz + 256, 512, 128, 256, 384, nullptr, nullptr);

    // 17-19. decoder (k_fin folded into the last GEMM)
    gemm_k<32,32,32,1,false,false><<<dim3(4, 16), 256, 0, stream>>>(xz, dw1, db1, dh1, 512, 100, 384, 100, nullptr, nullptr);
    gemm_k<32,32,32,1,false,false><<<dim3(4, 16), 256, 0, stream>>>(dh1, dw2, db2, dh2, 512, 100, 100, 100, nullptr, nullptr);
    gemm_k<32,32,32,2,true ,false><<<dim3(1, 16), 256, 0, stream>>>(dh2, dw3, db3, out, 512, 2, 100, 2, nullptr, nullptr);
}

// Round 12
// 633.948 us; speedup vs baseline: 1.0870x; 1.0043x over previous
//
#include <hip/hip_runtime.h>
#include <math.h>

// ---------------- problem constants ----------------
// T=16, NC=NQ=32, DW=256, DR=256, DZ=128, NH=8, F=1419
#define F_FEAT 1419
static constexpr float DN    = 0.25f;                 // 256^-0.25

typedef short short8 __attribute__((ext_vector_type(8)));
typedef float f32x4  __attribute__((ext_vector_type(4)));

// ---------------- workspace layout ----------------
// floats offsets unless noted "ush"
static constexpr long OFF_XDQ  = 0;                  // [4096][1419] f32 (performer phase, RAW)
static constexpr long OFF_XDK  = 5812224;            // [4096][1419] f32 (RAW)
static constexpr long U_WQH = 0;                     // W planes ush — POOL REGION: write only AFTER conv3m
static constexpr long U_WQL = 524288;
static constexpr long U_WKH = 1048576;
static constexpr long U_WKL = 1572864;
static constexpr long U_WVH = 2097152;
static constexpr long U_WVL = 2621440;               // ends ush 3,145,728
static constexpr long OFF_ENCT = 4000000;            // enc split-K temp: 16 x 262144 f32 (xd region, time-disjoint)
static constexpr long OFF_REPT = 8400000;            // rep split-K temp: 8 x 131072 f32 (xd dead by then; after enc_t end 8,194,304)
static constexpr long OFF_PA   = 11624448;           // partial A: [128][4][1024] f32 (dead region after step 13)
static constexpr long U_PH  = 23248896;              // [1536][256] ush — POOL REGION: after conv3m (padded for 128-tile)
static constexpr long U_PL  = 23642112;
static constexpr long U_XCH = 24035328;              // [1024][256] ush — pool region, written step 5
static constexpr long U_XCL = 24297472;
static constexpr long U_RSH = 24559616;              // [512][256] ush
static constexpr long U_RSL = 24690688;              // ends 24,821,760 < C3 start
static constexpr long U_C3H = 25165824;              // [1024][4096] ush (starts at pool end)
static constexpr long U_C3L = 29360128;
static constexpr long U_WOH = 25165824;              // wo planes reuse C3 region after enc GEMM
static constexpr long U_WOL = 25690112;
static constexpr long BASE     = 16777216;
static constexpr long OFF_XCTX = BASE + 0;           // [1024][256] f32 (ctx rows 0..511, qry 512..1023)
static constexpr long OFF_XQRY = BASE + 131072;
static constexpr long OFF_XCAT = BASE + 262144;      // [512][320]
static constexpr long OFF_H1   = BASE + 425984;      // [512][256]
static constexpr long OFF_H2   = BASE + 557056;      // [512][256]
static constexpr long OFF_RS   = BASE + 688128;      // [512][256]
static constexpr long U_QH  = (BASE + 819200) * 2;   // Q planes ush
static constexpr long U_QL  = U_QH + 1048576;
static constexpr long U_KH  = (BASE + 1867776) * 2;  // K planes ush (Q->K stride 2,097,152 ush)
static constexpr long U_KL  = U_KH + 1048576;
static constexpr long OFF_VA   = BASE + 2916352;     // [8][512][256] f32
static constexpr long OFF_AW1  = BASE + 3964928;     // Aw1 (1024 ush)
static constexpr long U_ELH = (BASE + 3977344) * 2;  // EL planes ush (REPIN region); REP planes reuse
static constexpr long U_ELL = U_ELH + 1048576;
static constexpr long U_REPH = U_ELH;                // [512][2048] ush
static constexpr long U_REPL = U_ELL;
static constexpr long OFF_REP  = BASE + 5025920;     // [512][256]
static constexpr long OFF_XZ   = BASE + 5156992;     // [512][384]
static constexpr long OFF_DH1  = BASE + 5353600;     // [512][100]
static constexpr long OFF_DH2  = BASE + 5404800;     // [512][100]
static constexpr long OFF_MD   = BASE + 5456000;     // dq[4096] mqe[4096u] dk[4096] mke[128u] (dead Aw region)
static constexpr long OFF_AW   = 22233216;           // conv2 A-weights (13824 ush)
static constexpr long OFF_AW3  = 22240128;           // conv3 A-weights (73728 ush)

__device__ inline unsigned short f2bf(float f) {
    unsigned int x = __float_as_uint(f);
    unsigned int r = x + 0x7fffu + ((x >> 16) & 1u);
    return (unsigned short)(r >> 16);
}
__device__ inline float bf2f(unsigned short h) {
    return __uint_as_float((unsigned int)h << 16);
}
// packed RNE f32->bf16 pair: low16 = bf16(a), high16 = bf16(b)  (gfx950)
__device__ inline unsigned int cvtpk(float a, float b) {
    unsigned int r;
    asm("v_cvt_pk_bf16_f32 %0, %1, %2" : "=v"(r) : "v"(a), "v"(b));
    return r;
}
// monotonic f32 <-> u32 encoding for atomicMax over signed floats
__device__ inline unsigned encf(float f) {
    unsigned u = __float_as_uint(f);
    return (u & 0x80000000u) ? ~u : (u | 0x80000000u);
}
__device__ inline float decf(unsigned u) {
    return __uint_as_float((u & 0x80000000u) ? (u & 0x7fffffffu) : ~u);
}

// ============================================================
// Prep A (runs FIRST — only touches non-pool regions):
// Aw(conv2), Aw1(conv1), Aw3(conv3 hi/lo), EL planes.
// ============================================================
static constexpr int NA1 = 13824;                 // Aw
static constexpr int NA2 = NA1 + 1024;            // Aw1
static constexpr int NA3 = NA2 + 73728;           // Aw3
static constexpr int NA4 = NA3 + 1048576;         // EL

__global__ void k_wprepA(const float* __restrict__ w2, const float* __restrict__ w1,
                         const float* __restrict__ w3, const float* __restrict__ elw,
                         unsigned short* __restrict__ Aw, unsigned short* __restrict__ Aw1,
                         unsigned short* __restrict__ Aw3,
                         unsigned short* __restrict__ ELh, unsigned short* __restrict__ ELl)
{
    int i = blockIdx.x * 256 + threadIdx.x;
    if (i < NA1) {
        int ic  = i & 31;
        int m16 = (i >> 5) & 15;
        int emt = i >> 9;
        int mt  = emt % 3, e = emt / 3;
        Aw[i] = f2bf(w2[((mt * 16 + m16) * 32 + ic) * 9 + e]);
    } else if (i < NA2) {
        int j = i - NA1;
        int k = j & 31, m = (j >> 5) & 15, mt = j >> 9;
        Aw1[j] = (k < 9) ? f2bf(w1[(mt * 16 + m) * 9 + k]) : (unsigned short)0;
    } else if (i < NA3) {
        int j = i - NA2;
        int k  = j & 63;
        int m  = (j >> 6) & 15;
        int hl = (j >> 10) & 1;
        int mt = (j >> 11) & 3;
        int e  = j >> 13;
        unsigned short v = 0;
        if (k < 48) {
            float w = w3[((mt * 16 + m) * 48 + k) * 9 + e];
            unsigned short hi = f2bf(w);
            v = hl == 0 ? hi : f2bf(w - bf2f(hi));
        }
        Aw3[j] = v;
    } else if (i < NA4) {
        int j = i - NA3;
        float v = elw[j];
        unsigned short h = f2bf(v);
        ELh[j] = h; ELl[j] = f2bf(v - bf2f(h));
    }
}

// ============================================================
// Prep B (runs AFTER conv3m — targets live in the then-dead pool region):
// P planes (padded to 1536 rows for the 128-tile performer GEMM),
// WQ/WK/WV planes.
// ============================================================
static constexpr int NB1 = 393216;                // P (1536 x 256)
static constexpr int NB2 = NB1 + 1572864;         // WQ/WK/WV

__global__ void k_wprepB(const float* __restrict__ proj,
                         const float* __restrict__ wq, const float* __restrict__ wk,
                         const float* __restrict__ wv,
                         unsigned short* __restrict__ Ph, unsigned short* __restrict__ Pl,
                         unsigned short* __restrict__ Wqkv)
{
    int i = blockIdx.x * 256 + threadIdx.x;
    if (i < NB1) {
        float v = (i < 363264) ? proj[i] : 0.f;
        unsigned short h = f2bf(v);
        Ph[i] = h; Pl[i] = f2bf(v - bf2f(h));
    } else if (i < NB2) {
        int j = i - NB1;
        int y = j / 524288, jj = j % 524288;
        const float* s = (y == 0) ? wq : (y == 1) ? wk : wv;
        float v = s[jj];
        unsigned short h = f2bf(v);
        Wqkv[(long)y * 1048576 + jj] = h;
        Wqkv[(long)y * 1048576 + 524288 + jj] = f2bf(v - bf2f(h));
    }
}

// ============================================================
// Fused conv1 (MFMA, LDS-staged im2col) -> bf16 ring -> conv2 MFMA
// -> in-register bias/relu/maxpool -> bf16 hi/lo pool. (R7 version —
// best measured; R2/R9 proved both occupancy levers net-negative.)
// ============================================================
#define TP 136
__launch_bounds__(256)
__global__ void k_conv12m(const float* __restrict__ train, const float* __restrict__ test,
                          const float* __restrict__ b1,
                          const unsigned short* __restrict__ Aw,
                          const unsigned short* __restrict__ Aw1,
                          const float* __restrict__ b2,
                          unsigned short* __restrict__ pool_out)
{
    const int g   = blockIdx.x;    // 0..7 (pool rows 2g, 2g+1; conv2 rows 4g..4g+3)
    const int img = blockIdx.y;
    const float* in = (img < 512) ? (train + (long)img * 16384)
                                  : (test  + (long)(img - 512) * 16384);

    __shared__ unsigned short ring[9 * 66 * 40];   // 47520 B
    __shared__ unsigned short tile[19 * TP];       // 5168 B: input rows 16g-3..16g+15

    const int t = threadIdx.x;

    for (int i = t; i < 9 * 40; i += 256) {
        int sl = i / 40, icp = i % 40;
        ring[(sl * 66 + 0) * 40 + icp] = 0;
    }
    if (g == 0)
        for (int i = t; i < 66 * 40; i += 256) ring[i] = 0;
    // zero the left halo (cols -2,-1 at tc 2,3) for all 19 rows
    if (t < 19) *(unsigned int*)&tile[t * TP + 2] = 0u;

    // ---- stage: 19 rows x 32 float4 (cols 0..127), packed bf16 ----
    {
        const float4 z4 = make_float4(0.f, 0.f, 0.f, 0.f);
        for (int u = t; u < 19 * 32; u += 256) {
            int row = u >> 5, k = u & 31;
            int r2 = 16 * g - 3 + row;             // never > 127
            float4 v = (r2 >= 0) ? *(const float4*)(in + r2 * 128 + k * 4) : z4;
            uint2 d;
            d.x = cvtpk(v.x, v.y);
            d.y = cvtpk(v.z, v.w);
            *(uint2*)&tile[row * TP + 4 + k * 4] = d;   // tc = c+4, 8B aligned
        }
    }
    __syncthreads();

    const int w    = t >> 6;
    const int lane = t & 63;
    const int cn   = lane & 15;
    const int quad = lane >> 4;

    // conv1 A-frags + per-lane biases (vector loads)
    short8 a1f0 = *(const short8*)&Aw1[(0 * 16 + cn) * 32 + quad * 8];
    short8 a1f1 = *(const short8*)&Aw1[(16 + cn) * 32 + quad * 8];
    float4 bsa = *(const float4*)&b1[quad * 4];
    float4 bsb = *(const float4*)&b1[16 + quad * 4];

    // ---- conv1 rows via MFMA (B-frag from tile; slice sl = conv1 row 8g+sl-1) ----
    const int px2 = w * 16 + cn;
    const int tb  = 2 * px2 + 2;                   // tc of input col 2px-2 (even)
    auto do_slice = [&](int sl) {
        const int rb = 2 * sl * TP + tb;
        uint4 pk = make_uint4(0u, 0u, 0u, 0u);
        if (quad == 0) {
            unsigned int w00 = *(const unsigned int*)&tile[rb];
            unsigned int w10 = *(const unsigned int*)&tile[rb + 2];
            unsigned int w01 = *(const unsigned int*)&tile[rb + TP];
            unsigned int w11 = *(const unsigned int*)&tile[rb + TP + 2];
            unsigned int w02 = *(const unsigned int*)&tile[rb + 2 * TP];
            unsigned int w12 = *(const unsigned int*)&tile[rb + 2 * TP + 2];
            pk.x = (w00 >> 16) | (w10 << 16);              // taps (0,0),(0,1)
            pk.y = (w10 >> 16) | (w01 & 0xffff0000u);      // taps (0,2),(1,0)
            pk.z = w11;                                    // taps (1,1),(1,2)
            pk.w = (w02 >> 16) | (w12 << 16);              // taps (2,0),(2,1)
        } else if (quad == 1) {
            pk.x = (*(const unsigned int*)&tile[rb + 2 * TP + 2]) >> 16;  // tap (2,2)
        }                                          // quads 2,3: taps 16..31 zero
        short8 bfr = *(const short8*)&pk;
        f32x4 z = (f32x4){0.f, 0.f, 0.f, 0.f};
        f32x4 c0 = __builtin_amdgcn_mfma_f32_16x16x32_bf16(a1f0, bfr, z, 0, 0, 0);
        f32x4 c1 = __builtin_amdgcn_mfma_f32_16x16x32_bf16(a1f1, bfr, z, 0, 0, 0);
        uint2 u0, u1;
        u0.x = cvtpk(fmaxf(c0[0] + bsa.x, 0.f), fmaxf(c0[1] + bsa.y, 0.f));
        u0.y = cvtpk(fmaxf(c0[2] + bsa.z, 0.f), fmaxf(c0[3] + bsa.w, 0.f));
        u1.x = cvtpk(fmaxf(c1[0] + bsb.x, 0.f), fmaxf(c1[1] + bsb.y, 0.f));
        u1.y = cvtpk(fmaxf(c1[2] + bsb.z, 0.f), fmaxf(c1[3] + bsb.w, 0.f));
        *(uint2*)&ring[(sl * 66 + px2 + 1) * 40 + quad * 4]      = u0;
        *(uint2*)&ring[(sl * 66 + px2 + 1) * 40 + 16 + quad * 4] = u1;
    };
    if (g > 0) do_slice(0);
    #pragma unroll
    for (int sl = 1; sl < 9; sl++) do_slice(sl);

    // issue e=0 conv2 A-frag loads before the barrier (overlap barrier wait)
    short8 ca0 = *(const short8*)&Aw[((0 * 3 + 0) * 16 + cn) * 32 + quad * 8];
    short8 ca1 = *(const short8*)&Aw[((0 * 3 + 1) * 16 + cn) * 32 + quad * 8];
    short8 ca2 = *(const short8*)&Aw[((0 * 3 + 2) * 16 + cn) * 32 + quad * 8];
    __syncthreads();

    // ---- conv2 MFMA: wave w -> pool row pr=w>>1, half xh=w&1,
    //      both conv2 rows of that pool row; A-frags prefetched 1 e ahead ----
    const int pr = w >> 1, xh = w & 1;
    f32x4 acc[3][2];
    #pragma unroll
    for (int mt = 0; mt < 3; mt++) {
        acc[mt][0] = (f32x4){0.f, 0.f, 0.f, 0.f};
        acc[mt][1] = (f32x4){0.f, 0.f, 0.f, 0.f};
    }

    #pragma unroll
    for (int e = 0; e < 9; e++) {
        int dy = e / 3, dx = e - 3 * dy;
        int c  = 2 * (xh * 16 + cn) + dx;
        int s0 = 4 * pr + dy;
        short8 b0  = *(const short8*)&ring[(s0 * 66 + c) * 40 + quad * 8];
        short8 b1f = *(const short8*)&ring[((s0 + 2) * 66 + c) * 40 + quad * 8];
        short8 na0, na1, na2;
        if (e < 8) {
            na0 = *(const short8*)&Aw[(((e + 1) * 3 + 0) * 16 + cn) * 32 + quad * 8];
            na1 = *(const short8*)&Aw[(((e + 1) * 3 + 1) * 16 + cn) * 32 + quad * 8];
            na2 = *(const short8*)&Aw[(((e + 1) * 3 + 2) * 16 + cn) * 32 + quad * 8];
        }
        acc[0][0] = __builtin_amdgcn_mfma_f32_16x16x32_bf16(ca0, b0,  acc[0][0], 0, 0, 0);
        acc[1][0] = __builtin_amdgcn_mfma_f32_16x16x32_bf16(ca1, b0,  acc[1][0], 0, 0, 0);
        acc[2][0] = __builtin_amdgcn_mfma_f32_16x16x32_bf16(ca2, b0,  acc[2][0], 0, 0, 0);
        acc[0][1] = __builtin_amdgcn_mfma_f32_16x16x32_bf16(ca0, b1f, acc[0][1], 0, 0, 0);
        acc[1][1] = __builtin_amdgcn_mfma_f32_16x16x32_bf16(ca1, b1f, acc[1][1], 0, 0, 0);
        acc[2][1] = __builtin_amdgcn_mfma_f32_16x16x32_bf16(ca2, b1f, acc[2][1], 0, 0, 0);
        if (e < 8) { ca0 = na0; ca1 = na1; ca2 = na2; }
    }

    // ---- in-register bias/relu/2x2-maxpool -> packed hi/lo stores ----
    {
        const int prow = 2 * g + pr;               // pool row 0..15
        const int ppx  = xh * 8 + (cn >> 1);       // pool px 0..15
        unsigned short* pb = pool_out + ((long)img * 256 + prow * 16 + ppx) * 96
                           + ((cn & 1) ? 48 : 0);
        #pragma unroll
        for (int mt = 0; mt < 3; mt++) {
            float4 bv = *(const float4*)&b2[mt * 16 + quad * 4];
            float m0, m1, m2, m3;
            {
                float v;
                v = fmaxf(fmaxf(acc[mt][0][0] + bv.x, acc[mt][1][0] + bv.x), 0.f);
                m0 = fmaxf(v, __shfl_xor(v, 1));
                v = fmaxf(fmaxf(acc[mt][0][1] + bv.y, acc[mt][1][1] + bv.y), 0.f);
                m1 = fmaxf(v, __shfl_xor(v, 1));
                v = fmaxf(fmaxf(acc[mt][0][2] + bv.z, acc[mt][1][2] + bv.z), 0.f);
                m2 = fmaxf(v, __shfl_xor(v, 1));
                v = fmaxf(fmaxf(acc[mt][0][3] + bv.w, acc[mt][1][3] + bv.w), 0.f);
                m3 = fmaxf(v, __shfl_xor(v, 1));
            }
            uint2 hv;
            hv.x = cvtpk(m0, m1);
            hv.y = cvtpk(m2, m3);
            uint2 sv = hv;
            if (cn & 1) {   // odd lane of the pair stores the lo plane
                float d0 = m0 - bf2f((unsigned short)(hv.x & 0xffffu));
                float d1 = m1 - bf2f((unsigned short)(hv.x >> 16));
                float d2 = m2 - bf2f((unsigned short)(hv.y & 0xffffu));
                float d3 = m3 - bf2f((unsigned short)(hv.y >> 16));
                sv.x = cvtpk(d0, d1);
                sv.y = cvtpk(d2, d3);
            }
            *(uint2*)&pb[mt * 16 + quad * 4] = sv;
        }
    }
}

// ============================================================
// conv3 via MFMA hi/lo -> bf16 hi/lo planes [1024][4096]
// ============================================================
#define C3PITCH 104
__launch_bounds__(512)
__global__ void k_conv3m(const unsigned short* __restrict__ pool,
                         const unsigned short* __restrict__ Aw3,
                         const float* __restrict__ b3,
                         unsigned short* __restrict__ C3h, unsigned short* __restrict__ C3l)
{
    const int img = blockIdx.x;
    __shared__ unsigned short s_in[30120];
    const int t = threadIdx.x;

    uint4* s4 = (uint4*)s_in;
    const uint4 zz = make_uint4(0, 0, 0, 0);
    for (int i = t; i < 3765; i += 512) s4[i] = zz;
    __syncthreads();
    {
        int p = t >> 1, half = t & 1;
        const uint4* src = (const uint4*)(pool + ((long)img * 256 + p) * 96 + half * 48);
        int r = p >> 4, c = p & 15;
        uint4* dst = (uint4*)(s_in + ((r + 1) * 17 + (c + 1)) * C3PITCH + half * 48);
        #pragma unroll
        for (int j = 0; j < 6; j++) dst[j] = src[j];
    }
    __syncthreads();

    const int w = t >> 6, lane = t & 63;
    const int n = lane & 15, quad = lane >> 4;
    const int mt = w >> 1, ntb = (w & 1) * 2;

    f32x4 acc[2];
    acc[0] = (f32x4){0.f, 0.f, 0.f, 0.f};
    acc[1] = (f32x4){0.f, 0.f, 0.f, 0.f};

    for (int e = 0; e < 9; e++) {
        int dy = e / 3, dx = e - 3 * dy;
        const unsigned short* A0 = Aw3 + (long)(((e * 4 + mt) * 2 + 0) * 16 + n) * 64 + quad * 8;
        const unsigned short* A1 = Aw3 + (long)(((e * 4 + mt) * 2 + 1) * 16 + n) * 64 + quad * 8;
        short8 ah0 = *(const short8*)(A0);
        short8 ah1 = *(const short8*)(A0 + 32);
        short8 al0 = *(const short8*)(A1);
        short8 al1 = *(const short8*)(A1 + 32);
        #pragma unroll
        for (int j = 0; j < 2; j++) {
            int p = (ntb + j) * 16 + n;
            int y = p >> 3, x = p & 7;
            const unsigned short* Bp = s_in + ((2 * y + dy) * 17 + (2 * x + dx)) * C3PITCH + quad * 8;
            short8 bh0 = *(const short8*)(Bp);
            short8 bh1 = *(const short8*)(Bp + 32);
            short8 bl0 = *(const short8*)(Bp + 48);
            short8 bl1 = *(const short8*)(Bp + 48 + 32);
            acc[j] = __builtin_amdgcn_mfma_f32_16x16x32_bf16(ah0, bh0, acc[j], 0, 0, 0);
            acc[j] = __builtin_amdgcn_mfma_f32_16x16x32_bf16(ah1, bh1, acc[j], 0, 0, 0);
            acc[j] = __builtin_amdgcn_mfma_f32_16x16x32_bf16(ah0, bl0, acc[j], 0, 0, 0);
            acc[j] = __builtin_amdgcn_mfma_f32_16x16x32_bf16(ah1, bl1, acc[j], 0, 0, 0);
            acc[j] = __builtin_amdgcn_mfma_f32_16x16x32_bf16(al0, bh0, acc[j], 0, 0, 0);
            acc[j] = __builtin_amdgcn_mfma_f32_16x16x32_bf16(al1, bh1, acc[j], 0, 0, 0);
        }
    }

    unsigned short* oh = C3h + (long)img * 4096;
    unsigned short* ol = C3l + (long)img * 4096;
    #pragma unroll
    for (int reg = 0; reg < 4; reg++) {
        int oc = mt * 16 + quad * 4 + reg;
        float bias = b3[oc];
        #pragma unroll
        for (int j = 0; j < 2; j++) {
            int p = (ntb + j) * 16 + n;
            float v = fmaxf(acc[j][reg] + bias, 0.f);
            unsigned short h = f2bf(v);
            oh[oc * 64 + p] = h;
            ol[oc * 64 + p] = f2bf(v - bf2f(h));
        }
    }
}

// ============================================================
// bf16 hi/lo MFMA GEMM (3-term, ~fp32). OUTMODE 0: f32 out (z-batch over
// X/W/B/Y strides); 1: hi/lo plane out (z-batch); 3: split-K chunks.
// ============================================================
template<int OUTMODE>
__launch_bounds__(256)
__global__ void mgemm(const unsigned short* __restrict__ Xh0, const unsigned short* __restrict__ Xl0,
                      const unsigned short* __restrict__ Wph, const unsigned short* __restrict__ Wpl,
                      const float* __restrict__ Bb, float* __restrict__ Yf,
                      unsigned short* __restrict__ Yh, unsigned short* __restrict__ Yl,
                      int M, int N, int K, int ldY, float scale,
                      long sX, long sW, long sB, long sY, int kChunk)
{
    const int z = blockIdx.z;
    const unsigned short* Xh = Xh0 + (OUTMODE == 3 ? 0 : (long)z * sX);
    const unsigned short* Xl = Xl0 + (OUTMODE == 3 ? 0 : (long)z * sX);
    const unsigned short* Wh = Wph + (OUTMODE == 3 ? 0 : (long)z * sW);
    const unsigned short* Wl = Wpl + (OUTMODE == 3 ? 0 : (long)z * sW);
    const float* B = Bb ? (Bb + (OUTMODE == 3 ? 0 : (long)z * sB)) : nullptr;
    int k0 = 0, k1 = K;
    if (OUTMODE == 3) { k0 = z * kChunk; k1 = min(K, k0 + kChunk); }

    __shared__ unsigned short sAh[64 * 40], sAl[64 * 40], sBh[64 * 40], sBl[64 * 40];

    const int t = threadIdx.x;
    const int m0 = blockIdx.y * 64, n0 = blockIdx.x * 64;
    const int r = t >> 2, kq = (t & 3) * 8;

    const int w = t >> 6, lane = t & 63;
    const int wm = (w & 1) * 32, wn = (w >> 1) * 32;
    const int cn = lane & 15, quad = lane >> 4;

    f32x4 acc[2][2];
    acc[0][0] = acc[0][1] = acc[1][0] = acc[1][1] = (f32x4){0.f, 0.f, 0.f, 0.f};

    for (int kb = k0; kb < k1; kb += 32) {
        *(uint4*)&sAh[r * 40 + kq] = *(const uint4*)&Xh[(long)(m0 + r) * K + kb + kq];
        *(uint4*)&sAl[r * 40 + kq] = *(const uint4*)&Xl[(long)(m0 + r) * K + kb + kq];
        *(uint4*)&sBh[r * 40 + kq] = *(const uint4*)&Wh[(long)(n0 + r) * K + kb + kq];
        *(uint4*)&sBl[r * 40 + kq] = *(const uint4*)&Wl[(long)(n0 + r) * K + kb + kq];
        __syncthreads();
        short8 axh[2], axl[2], bxh[2], bxl[2];
        #pragma unroll
        for (int i = 0; i < 2; i++) {
            axh[i] = *(const short8*)&sAh[(wm + i * 16 + cn) * 40 + quad * 8];
            axl[i] = *(const short8*)&sAl[(wm + i * 16 + cn) * 40 + quad * 8];
            bxh[i] = *(const short8*)&sBh[(wn + i * 16 + cn) * 40 + quad * 8];
            bxl[i] = *(const short8*)&sBl[(wn + i * 16 + cn) * 40 + quad * 8];
        }
        #pragma unroll
        for (int i = 0; i < 2; i++)
            #pragma unroll
            for (int j = 0; j < 2; j++) {
                acc[i][j] = __builtin_amdgcn_mfma_f32_16x16x32_bf16(axh[i], bxh[j], acc[i][j], 0, 0, 0);
                acc[i][j] = __builtin_amdgcn_mfma_f32_16x16x32_bf16(axh[i], bxl[j], acc[i][j], 0, 0, 0);
                acc[i][j] = __builtin_amdgcn_mfma_f32_16x16x32_bf16(axl[i], bxh[j], acc[i][j], 0, 0, 0);
            }
        __syncthreads();
    }

    #pragma unroll
    for (int i = 0; i < 2; i++) {
        #pragma unroll
        for (int reg = 0; reg < 4; reg++) {
            int row = m0 + wm + i * 16 + quad * 4 + reg;
            #pragma unroll
            for (int j = 0; j < 2; j++) {
                int col = n0 + wn + j * 16 + cn;
                if (col >= N) continue;
                float v = acc[i][j][reg] * scale;
                if (OUTMODE == 3) {
                    (Yf + (long)z * sY)[(long)row * ldY + col] = v;
                } else if (OUTMODE == 0) {
                    if (B) v += B[col];
                    (Yf + (long)z * sY)[(long)row * ldY + col] = v;
                } else {
                    if (B) v += B[col];
                    unsigned short h = f2bf(v);
                    (Yh + (long)z * sY)[(long)row * ldY + col] = h;
                    (Yl + (long)z * sY)[(long)row * ldY + col] = f2bf(v - bf2f(h));
                }
            }
        }
    }
}

// ============================================================
// mgemm128: 128x128-tile 3-term bf16 hi/lo GEMM for the performer
// features (f32 out, fused row/tile max). grid (ceil(N/128), M/128, 2):
// z=0 -> q (per-row max -> mqe), z=1 -> k (per-32-row-tile max -> mke).
// Per wave/K-step: 16 ds_read_b128 feed 48 MFMAs (3:1, vs 1.5:1 at 64²).
// W rows padded to 1536 (wprepB) so B-tile staging never reads OOB.
// ============================================================
__launch_bounds__(256)
__global__ void mgemm128(const unsigned short* __restrict__ Xh0, const unsigned short* __restrict__ Xl0,
                         const unsigned short* __restrict__ Wh, const unsigned short* __restrict__ Wl,
                         float* __restrict__ Yf, int M, int N, int K, int ldY, float scale,
                         long sX, long sY,
                         unsigned* __restrict__ mqe, unsigned* __restrict__ mke)
{
    const int z = blockIdx.z;
    const unsigned short* Xh = Xh0 + (long)z * sX;
    const unsigned short* Xl = Xl0 + (long)z * sX;

    __shared__ unsigned short sAh[128 * 40], sAl[128 * 40], sBh[128 * 40], sBl[128 * 40];

    const int t = threadIdx.x;
    const int m0 = blockIdx.y * 128, n0 = blockIdx.x * 128;
    const int r = t >> 1, kq = (t & 1) * 16;       // each thread: 16 ush (2 uint4) of one row

    const int w = t >> 6, lane = t & 63;
    const int wm = (w & 1) * 64, wn = (w >> 1) * 64;
    const int cn = lane & 15, quad = lane >> 4;

    f32x4 acc[4][4];
    #pragma unroll
    for (int i = 0; i < 4; i++)
        #pragma unroll
        for (int j = 0; j < 4; j++) acc[i][j] = (f32x4){0.f, 0.f, 0.f, 0.f};

    for (int kb = 0; kb < K; kb += 32) {
        *(uint4*)&sAh[r * 40 + kq]     = *(const uint4*)&Xh[(long)(m0 + r) * K + kb + kq];
        *(uint4*)&sAh[r * 40 + kq + 8] = *(const uint4*)&Xh[(long)(m0 + r) * K + kb + kq + 8];
        *(uint4*)&sAl[r * 40 + kq]     = *(const uint4*)&Xl[(long)(m0 + r) * K + kb + kq];
        *(uint4*)&sAl[r * 40 + kq + 8] = *(const uint4*)&Xl[(long)(m0 + r) * K + kb + kq + 8];
        *(uint4*)&sBh[r * 40 + kq]     = *(const uint4*)&Wh[(long)(n0 + r) * K + kb + kq];
        *(uint4*)&sBh[r * 40 + kq + 8] = *(const uint4*)&Wh[(long)(n0 + r) * K + kb + kq + 8];
        *(uint4*)&sBl[r * 40 + kq]     = *(const uint4*)&Wl[(long)(n0 + r) * K + kb + kq];
        *(uint4*)&sBl[r * 40 + kq + 8] = *(const uint4*)&Wl[(long)(n0 + r) * K + kb + kq + 8];
        __syncthreads();
        short8 axh[4], axl[4], bxh[4], bxl[4];
        #pragma unroll
        for (int i = 0; i < 4; i++) {
            axh[i] = *(const short8*)&sAh[(wm + i * 16 + cn) * 40 + quad * 8];
            axl[i] = *(const short8*)&sAl[(wm + i * 16 + cn) * 40 + quad * 8];
            bxh[i] = *(const short8*)&sBh[(wn + i * 16 + cn) * 40 + quad * 8];
            bxl[i] = *(const short8*)&sBl[(wn + i * 16 + cn) * 40 + quad * 8];
        }
        #pragma unroll
        for (int i = 0; i < 4; i++)
            #pragma unroll
            for (int j = 0; j < 4; j++) {
                acc[i][j] = __builtin_amdgcn_mfma_f32_16x16x32_bf16(axh[i], bxh[j], acc[i][j], 0, 0, 0);
                acc[i][j] = __builtin_amdgcn_mfma_f32_16x16x32_bf16(axh[i], bxl[j], acc[i][j], 0, 0, 0);
                acc[i][j] = __builtin_amdgcn_mfma_f32_16x16x32_bf16(axl[i], bxh[j], acc[i][j], 0, 0, 0);
            }
        __syncthreads();
    }

    float gmax0 = -3e38f, gmax1 = -3e38f;          // per 32-row half of the wave's 64 rows
    #pragma unroll
    for (int i = 0; i < 4; i++) {
        #pragma unroll
        for (int reg = 0; reg < 4; reg++) {
            int row = m0 + wm + i * 16 + quad * 4 + reg;
            float rmax = -3e38f;
            #pragma unroll
            for (int j = 0; j < 4; j++) {
                int col = n0 + wn + j * 16 + cn;
                if (col >= N) continue;
                float v = acc[i][j][reg] * scale;
                (Yf + (long)z * sY)[(long)row * ldY + col] = v;
                rmax = fmaxf(rmax, v);
            }
            if (z == 0) {
                rmax = fmaxf(rmax, __shfl_xor(rmax, 1));
                rmax = fmaxf(rmax, __shfl_xor(rmax, 2));
                rmax = fmaxf(rmax, __shfl_xor(rmax, 4));
                rmax = fmaxf(rmax, __shfl_xor(rmax, 8));
                if (cn == 0) atomicMax(&mqe[row], encf(rmax));
            } else {
                if (i < 2) gmax0 = fmaxf(gmax0, rmax);
                else       gmax1 = fmaxf(gmax1, rmax);
            }
        }
    }
    if (z == 1) {
        for (int d = 1; d < 64; d <<= 1) {
            gmax0 = fmaxf(gmax0, __shfl_xor(gmax0, d));
            gmax1 = fmaxf(gmax1, __shfl_xor(gmax1, d));
        }
        if (lane == 0) {
            atomicMax(&mke[(m0 + wm) >> 5],       encf(gmax0));
            atomicMax(&mke[((m0 + wm) >> 5) + 1], encf(gmax1));
        }
    }
}

// ============================================================
// mgemm128s: 128x128-tile 3-term split-K GEMM (enc linear). z = K-chunk
// index; plain f32 store to Yf + z*sY. Same staging/MFMA core as
// mgemm128. Grid (N/128, M/128, nChunks).
// ============================================================
__launch_bounds__(256)
__global__ void mgemm128s(const unsigned short* __restrict__ Xh, const unsigned short* __restrict__ Xl,
                          const unsigned short* __restrict__ Wh, const unsigned short* __restrict__ Wl,
                          float* __restrict__ Yf, int M, int N, int K, int ldY,
                          long sY, int kChunk)
{
    const int z = blockIdx.z;
    const int k0 = z * kChunk, k1 = min(K, k0 + kChunk);

    __shared__ unsigned short sAh[128 * 40], sAl[128 * 40], sBh[128 * 40], sBl[128 * 40];

    const int t = threadIdx.x;
    const int m0 = blockIdx.y * 128, n0 = blockIdx.x * 128;
    const int r = t >> 1, kq = (t & 1) * 16;

    const int w = t >> 6, lane = t & 63;
    const int wm = (w & 1) * 64, wn = (w >> 1) * 64;
    const int cn = lane & 15, quad = lane >> 4;

    f32x4 acc[4][4];
    #pragma unroll
    for (int i = 0; i < 4; i++)
        #pragma unroll
        for (int j = 0; j < 4; j++) acc[i][j] = (f32x4){0.f, 0.f, 0.f, 0.f};

    for (int kb = k0; kb < k1; kb += 32) {
        *(uint4*)&sAh[r * 40 + kq]     = *(const uint4*)&Xh[(long)(m0 + r) * K + kb + kq];
        *(uint4*)&sAh[r * 40 + kq + 8] = *(const uint4*)&Xh[(long)(m0 + r) * K + kb + kq + 8];
        *(uint4*)&sAl[r * 40 + kq]     = *(const uint4*)&Xl[(long)(m0 + r) * K + kb + kq];
        *(uint4*)&sAl[r * 40 + kq + 8] = *(const uint4*)&Xl[(long)(m0 + r) * K + kb + kq + 8];
        *(uint4*)&sBh[r * 40 + kq]     = *(const uint4*)&Wh[(long)(n0 + r) * K + kb + kq];
        *(uint4*)&sBh[r * 40 + kq + 8] = *(const uint4*)&Wh[(long)(n0 + r) * K + kb + kq + 8];
        *(uint4*)&sBl[r * 40 + kq]     = *(const uint4*)&Wl[(long)(n0 + r) * K + kb + kq];
        *(uint4*)&sBl[r * 40 + kq + 8] = *(const uint4*)&Wl[(long)(n0 + r) * K + kb + kq + 8];
        __syncthreads();
        short8 axh[4], axl[4], bxh[4], bxl[4];
        #pragma unroll
        for (int i = 0; i < 4; i++) {
            axh[i] = *(const short8*)&sAh[(wm + i * 16 + cn) * 40 + quad * 8];
            axl[i] = *(const short8*)&sAl[(wm + i * 16 + cn) * 40 + quad * 8];
            bxh[i] = *(const short8*)&sBh[(wn + i * 16 + cn) * 40 + quad * 8];
            bxl[i] = *(const short8*)&sBl[(wn + i * 16 + cn) * 40 + quad * 8];
        }
        #pragma unroll
        for (int i = 0; i < 4; i++)
            #pragma unroll
            for (int j = 0; j < 4; j++) {
                acc[i][j] = __builtin_amdgcn_mfma_f32_16x16x32_bf16(axh[i], bxh[j], acc[i][j], 0, 0, 0);
                acc[i][j] = __builtin_amdgcn_mfma_f32_16x16x32_bf16(axh[i], bxl[j], acc[i][j], 0, 0, 0);
                acc[i][j] = __builtin_amdgcn_mfma_f32_16x16x32_bf16(axl[i], bxh[j], acc[i][j], 0, 0, 0);
            }
        __syncthreads();
    }

    float* Y = Yf + (long)z * sY;
    #pragma unroll
    for (int i = 0; i < 4; i++) {
        #pragma unroll
        for (int reg = 0; reg < 4; reg++) {
            int row = m0 + wm + i * 16 + quad * 4 + reg;
            #pragma unroll
            for (int j = 0; j < 4; j++) {
                int col = n0 + wn + j * 16 + cn;
                if (col >= N) continue;
                Y[(long)row * ldY + col] = acc[i][j][reg];
            }
        }
    }
}

// ============================================================
// k_qkv: Q/K/V projections in ONE launch, grid (4, 8, 24).
// z 0..7 = Q heads (x_qry, planes out + diag), 8..15 = K heads (x_ctx,
// planes + diag), 16..23 = V heads (rs, f32 out). diag = sum(v^2)/32
// atomicAdd'd per token row (MD region zeroed in k_red_enc).
// ============================================================
__launch_bounds__(256)
__global__ void k_qkv(const unsigned short* __restrict__ XCh, const unsigned short* __restrict__ XCl,
                      const unsigned short* __restrict__ RSh, const unsigned short* __restrict__ RSl,
                      const unsigned short* __restrict__ Wqkv,
                      const float* __restrict__ wqb, const float* __restrict__ wkb,
                      const float* __restrict__ wvb,
                      unsigned short* __restrict__ Qh, unsigned short* __restrict__ Ql,
                      unsigned short* __restrict__ Kh, unsigned short* __restrict__ Kl,
                      float* __restrict__ v_all, float* __restrict__ dq, float* __restrict__ dk)
{
    const int z = blockIdx.z, y = z >> 3, zh = z & 7;
    const unsigned short* Xh = (y == 0) ? XCh + 512 * 256 : (y == 1) ? XCh : RSh;
    const unsigned short* Xl = (y == 0) ? XCl + 512 * 256 : (y == 1) ? XCl : RSl;
    const unsigned short* Wh = Wqkv + (long)y * 1048576 + (long)zh * 65536;
    const unsigned short* Wl = Wh + 524288;
    const float* B = ((y == 0) ? wqb : (y == 1) ? wkb : wvb) + zh * 256;

    __shared__ unsigned short sAh[64 * 40], sAl[64 * 40], sBh[64 * 40], sBl[64 * 40];

    const int t = threadIdx.x;
    const int m0 = blockIdx.y * 64, n0 = blockIdx.x * 64;
    const int r = t >> 2, kq = (t & 3) * 8;
    const int w = t >> 6, lane = t & 63;
    const int wm = (w & 1) * 32, wn = (w >> 1) * 32;
    const int cn = lane & 15, quad = lane >> 4;

    f32x4 acc[2][2];
    acc[0][0] = acc[0][1] = acc[1][0] = acc[1][1] = (f32x4){0.f, 0.f, 0.f, 0.f};

    for (int kb = 0; kb < 256; kb += 32) {
        *(uint4*)&sAh[r * 40 + kq] = *(const uint4*)&Xh[(long)(m0 + r) * 256 + kb + kq];
        *(uint4*)&sAl[r * 40 + kq] = *(const uint4*)&Xl[(long)(m0 + r) * 256 + kb + kq];
        *(uint4*)&sBh[r * 40 + kq] = *(const uint4*)&Wh[(long)(n0 + r) * 256 + kb + kq];
        *(uint4*)&sBl[r * 40 + kq] = *(const uint4*)&Wl[(long)(n0 + r) * 256 + kb + kq];
        __syncthreads();
        short8 axh[2], axl[2], bxh[2], bxl[2];
        #pragma unroll
        for (int i = 0; i < 2; i++) {
            axh[i] = *(const short8*)&sAh[(wm + i * 16 + cn) * 40 + quad * 8];
            axl[i] = *(const short8*)&sAl[(wm + i * 16 + cn) * 40 + quad * 8];
            bxh[i] = *(const short8*)&sBh[(wn + i * 16 + cn) * 40 + quad * 8];
            bxl[i] = *(const short8*)&sBl[(wn + i * 16 + cn) * 40 + quad * 8];
        }
        #pragma unroll
        for (int i = 0; i < 2; i++)
            #pragma unroll
            for (int j = 0; j < 2; j++) {
                acc[i][j] = __builtin_amdgcn_mfma_f32_16x16x32_bf16(axh[i], bxh[j], acc[i][j], 0, 0, 0);
                acc[i][j] = __builtin_amdgcn_mfma_f32_16x16x32_bf16(axh[i], bxl[j], acc[i][j], 0, 0, 0);
                acc[i][j] = __builtin_amdgcn_mfma_f32_16x16x32_bf16(axl[i], bxh[j], acc[i][j], 0, 0, 0);
            }
        __syncthreads();
    }

    unsigned short* Yh = ((y == 0) ? Qh : Kh) + (long)zh * 131072;
    unsigned short* Yl = ((y == 0) ? Ql : Kl) + (long)zh * 131072;
    float* Yf = v_all + (long)zh * 131072;
    float* dacc = ((y == 0) ? dq : dk) + zh * 512;

    #pragma unroll
    for (int i = 0; i < 2; i++) {
        #pragma unroll
        for (int reg = 0; reg < 4; reg++) {
            int row = m0 + wm + i * 16 + quad * 4 + reg;
            float s = 0.f;
            #pragma unroll
            for (int j = 0; j < 2; j++) {
                int col = n0 + wn + j * 16 + cn;
                float v = acc[i][j][reg] + B[col];
                if (y == 2) {
                    Yf[(long)row * 256 + col] = v;
                } else {
                    unsigned short h = f2bf(v);
                    Yh[(long)row * 256 + col] = h;
                    Yl[(long)row * 256 + col] = f2bf(v - bf2f(h));
                    s += v * v;
                }
            }
            if (y < 2) {
                s += __shfl_xor(s, 1); s += __shfl_xor(s, 2);
                s += __shfl_xor(s, 4); s += __shfl_xor(s, 8);
                if (cn == 0) atomicAdd(&dacc[row], s * (1.f / 32.f));
            }
        }
    }
}

// ============================================================
// reducers for split-K temps (fused with small jobs to cut launches)
// k_red_enc grid 3249: [0,1024) enc reduce (16 chunks); [1024,1152)
// label embed; [1152,3200) wo -> hi/lo planes; [3200,3249) zero MD.
// ============================================================
__global__ void k_red_enc(const float* __restrict__ tmp, const float* __restrict__ elb,
                          float* __restrict__ x_ctx, unsigned short* __restrict__ XCh,
                          unsigned short* __restrict__ XCl, float* __restrict__ xcat,
                          const float* __restrict__ label, const float* __restrict__ tyw,
                          const float* __restrict__ tyb,
                          const float* __restrict__ wow, unsigned short* __restrict__ WOh,
                          unsigned short* __restrict__ WOl, unsigned* __restrict__ md)
{
    int b = blockIdx.x;
    int tt = threadIdx.x;
    if (b < 1024) {
        int i = b * 256 + tt;                 // 262144
        int r = i >> 8, c = i & 255;
        float v = elb[c];
        #pragma unroll
        for (int z = 0; z < 16; z++) v += tmp[(long)z * 262144 + i];
        x_ctx[i] = v;
        unsigned short h = f2bf(v);
        XCh[i] = h; XCl[i] = f2bf(v - bf2f(h));
        if (r < 512) xcat[r * 320 + c] = v;
    } else if (b < 1152) {
        int i = (b - 1024) * 256 + tt;        // 32768
        int r = i >> 6, e = i & 63;
        xcat[r * 320 + 256 + e] = tyb[e] + label[r * 2] * tyw[e * 2] + label[r * 2 + 1] * tyw[e * 2 + 1];
    } else if (b < 3200) {
        int i = (b - 1152) * 256 + tt;        // 524288
        float v = wow[i];
        unsigned short h = f2bf(v);
        WOh[i] = h; WOl[i] = f2bf(v - bf2f(h));
    } else {
        int i = (b - 3200) * 256 + tt;        // 12416 (dq,mqe,dk,mke)
        if (i < 12416) md[i] = 0u;
    }
}

// k_red_rep grid 1024: [0,512) rep reduce (8 chunks); [512,1024) xz col copy.
__global__ void k_red_rep(const float* __restrict__ tmp, const float* __restrict__ wob,
                          float* __restrict__ rep,
                          const float* __restrict__ xq, float* __restrict__ xz)
{
    int b = blockIdx.x;
    int tt = threadIdx.x;
    if (b < 512) {
        int i = b * 256 + tt;                 // 131072
        int c = i & 255;
        float v = wob[c];
        #pragma unroll
        for (int z = 0; z < 8; z++) v += tmp[(long)z * 131072 + i];
        rep[i] = v;
    } else {
        int i = (b - 512) * 256 + tt;         // 131072
        int r = i >> 8, c = i & 255;
        xz[r * 384 + c] = xq[i];
    }
}

// ============================================================
// Generic fp32 GEMM (small layers), float2 inner loads.
// WP: also emit bf16 hi/lo planes of the output (used for rs).
// ============================================================
template<int BM, int BN, int BK, int ACT, bool FIN, bool WP>
__launch_bounds__(256)
__global__ void gemm_k(const float* __restrict__ X, const float* __restrict__ W,
                       const float* __restrict__ B, float* __restrict__ Y,
                       int M, int N, int K, int ldY,
                       unsigned short* __restrict__ Ph2, unsigned short* __restrict__ Pl2)
{
    __shared__ float As[BK][BM + 4];
    __shared__ float Bs[BK][BN + 4];
    const int t = threadIdx.x;
    const int tx = t & 15, ty = t >> 4;
    const int m0 = blockIdx.y * BM, n0 = blockIdx.x * BN;
    float acc[2][2] = {{0.f, 0.f}, {0.f, 0.f}};

    for (int kb = 0; kb < K; kb += BK) {
        for (int i = t; i < BM * BK; i += 256) {
            int rr = i / BK, c = i % BK;
            int mm = m0 + rr, kk = kb + c;
            As[c][rr] = (mm < M && kk < K) ? X[(long)mm * K + kk] : 0.f;
        }
        for (int i = t; i < BN * BK; i += 256) {
            int rr = i / BK, c = i % BK;
            int nn = n0 + rr, kk = kb + c;
            Bs[c][rr] = (nn < N && kk < K) ? W[(long)nn * K + kk] : 0.f;
        }
        __syncthreads();
        #pragma unroll
        for (int kk = 0; kk < BK; kk++) {
            float2 a2 = *(const float2*)&As[kk][ty * 2];
            float2 b2 = *(const float2*)&Bs[kk][tx * 2];
            acc[0][0] += a2.x * b2.x; acc[0][1] += a2.x * b2.y;
            acc[1][0] += a2.y * b2.x; acc[1][1] += a2.y * b2.y;
        }
        __syncthreads();
    }

    #pragma unroll
    for (int i = 0; i < 2; i++) {
        int mm = m0 + ty * 2 + i;
        if (mm >= M) continue;
        #pragma unroll
        for (int j = 0; j < 2; j++) {
            int nn = n0 + tx * 2 + j;
            if (nn >= N) continue;
            float v = acc[i][j] + (B ? B[nn] : 0.f);
            if (ACT == 1) v = fmaxf(v, 0.f);
            if (ACT == 2) v = tanhf(v);
            Y[(long)mm * ldY + nn] = v;
            if (WP) {
                unsigned short h = f2bf(v);
                Ph2[(long)mm * ldY + nn] = h;
                Pl2[(long)mm * ldY + nn] = f2bf(v - bf2f(h));
            }
        }
    }
    if (FIN && t == 0 && blockIdx.x == 0 && blockIdx.y == 0) Y[1024] = 0.f;
}

// ============================================================
// k_attn1: feature-split QK^T with fused exp. grid (NSPLIT=4, 128).
// Each block: features [s*355, min(1419,(s+1)*355)) of one (h,t) tile;
// partial A[32][32] -> pA[kb][s][1024]. LDS pitch 65 (conflict-free).
// shifts: dq + decode(mqe) per q-row; dk + decode(mke[kb]) per k-row.
// ============================================================
#define NSPLIT 4
#define FCH 355
__launch_bounds__(256)
__global__ void k_attn1(const float* __restrict__ qp, const float* __restrict__ kp,
                        const float* __restrict__ dq, const unsigned* __restrict__ mqe,
                        const float* __restrict__ dk, const unsigned* __restrict__ mke,
                        float* __restrict__ pA)
{
    const int s  = blockIdx.x;        // 0..3 feature split
    const int kb = blockIdx.y;        // 0..127 tile
    const long row0 = (long)kb * 32;
    const int f0 = s * FCH;
    const int f1 = min(F_FEAT, f0 + FCH);

    __shared__ float s_q[32 * 65];
    __shared__ float s_k[32 * 65];
    __shared__ float s_cq[32], s_ck[32];

    const int t = threadIdx.x;
    const int n = t >> 3;
    const int mq_ = (t & 7) * 4;

    if (t < 32) {
        s_cq[t] = dq[row0 + t] + decf(mqe[row0 + t]);
        s_ck[t] = dk[row0 + t] + decf(mke[kb]);
    }
    __syncthreads();

    float acc[4] = {0.f, 0.f, 0.f, 0.f};
    for (int fc = f0; fc < f1; fc += 64) {
        for (int i = t; i < 2048; i += 256) {
            int rr = i >> 6, ff = i & 63;
            int fg = fc + ff;
            float qv = 0.f, kv = 0.f;
            if (fg < f1) {
                qv = __expf(qp[(row0 + rr) * F_FEAT + fg] - s_cq[rr]) + 1e-4f;
                kv = __expf(kp[(row0 + rr) * F_FEAT + fg] - s_ck[rr]) + 1e-4f;
            }
            s_q[rr * 65 + ff] = qv;
            s_k[rr * 65 + ff] = kv;
        }
        __syncthreads();
        #pragma unroll 8
        for (int ff = 0; ff < 64; ff++) {
            float a = s_q[n * 65 + ff];
            #pragma unroll
            for (int j = 0; j < 4; j++) acc[j] += a * s_k[(mq_ + j) * 65 + ff];
        }
        __syncthreads();
    }

    float* dst = pA + ((long)kb * NSPLIT + s) * 1024;
    #pragma unroll
    for (int j = 0; j < 4; j++) dst[n * 32 + mq_ + j] = acc[j];
}

// ============================================================
// k_attn2: reduce partial A + rowsum + PV chunk -> REP planes.
// grid (4 e-chunks, 128 tiles).
// ============================================================
__launch_bounds__(256)
__global__ void k_attn2(const float* __restrict__ pA, const float* __restrict__ va,
                        unsigned short* __restrict__ REPh, unsigned short* __restrict__ REPl)
{
    const int ec = blockIdx.x;        // 0..3, 64 output cols each
    const int kb = blockIdx.y;        // 0..127
    const int h = kb >> 4, tt = kb & 15;
    const long row0 = (long)kb * 32;

    __shared__ float s_A[32][33];
    __shared__ float s_di[32];
    __shared__ float s_v[32 * 64];

    const int t = threadIdx.x;

    // reduce NSPLIT partials, 4 A-elements per thread (float4 loads)
    {
        const float* base = pA + (long)kb * NSPLIT * 1024 + t * 4;
        float4 v0 = *(const float4*)(base);
        float4 v1 = *(const float4*)(base + 1024);
        float4 v2 = *(const float4*)(base + 2048);
        float4 v3 = *(const float4*)(base + 3072);
        int r = t >> 3, c = (t & 7) * 4;
        s_A[r][c]     = v0.x + v1.x + v2.x + v3.x;
        s_A[r][c + 1] = v0.y + v1.y + v2.y + v3.y;
        s_A[r][c + 2] = v0.z + v1.z + v2.z + v3.z;
        s_A[r][c + 3] = v0.w + v1.w + v2.w + v3.w;
    }
    // stage V chunk (coalesced)
    for (int i = t; i < 2048; i += 256) {
        int m = i >> 6, e = i & 63;
        s_v[m * 64 + e] = va[row0 * 256 + m * 256 + ec * 64 + e];
    }
    __syncthreads();
    if (t < 32) {
        float s = 0.f;
        #pragma unroll
        for (int m = 0; m < 32; m++) s += s_A[t][m];
        s_di[t] = 1.f / s;
    }
    __syncthreads();

    const int n = t >> 3, e0 = t & 7;
    float out[8];
    #pragma unroll
    for (int j = 0; j < 8; j++) out[j] = 0.f;
    for (int m = 0; m < 32; m++) {
        float a = s_A[n][m];
        #pragma unroll
        for (int j = 0; j < 8; j++) out[j] += a * s_v[m * 64 + e0 + 8 * j];
    }
    float di = s_di[n];
    unsigned short* dsth = REPh + ((long)tt * 32 + n) * 2048;
    unsigned short* dstl = REPl + ((long)tt * 32 + n) * 2048;
    #pragma unroll
    for (int j = 0; j < 8; j++) {
        int e = ec * 64 + e0 + 8 * j;
        float val = out[j] * di;
        unsigned short hh = f2bf(val);
        dsth[e * 8 + h] = hh;
        dstl[e * 8 + h] = f2bf(val - bf2f(hh));
    }
}

// ============================================================
extern "C" void kernel_launch(void* const* d_in, const int* in_sizes, int n_in,
                              void* d_out, int out_size, void* d_ws, size_t ws_size,
                              hipStream_t stream)
{
    const float* train  = (const float*)d_in[0];
    const float* label  = (const float*)d_in[1];
    const float* test   = (const float*)d_in[2];
    const float* c1w = (const float*)d_in[3];  const float* c1b = (const float*)d_in[4];
    const float* c2w = (const float*)d_in[5];  const float* c2b = (const float*)d_in[6];
    const float* c3w = (const float*)d_in[7];  const float* c3b = (const float*)d_in[8];
    const float* elw = (const float*)d_in[9];  const float* elb = (const float*)d_in[10];
    const float* tyw = (const float*)d_in[11]; const float* tyb = (const float*)d_in[12];
    const float* ew1 = (const float*)d_in[13]; const float* eb1 = (const float*)d_in[14];
    const float* ew2 = (const float*)d_in[15]; const float* eb2 = (const float*)d_in[16];
    const float* ew3 = (const float*)d_in[17]; const float* eb3 = (const float*)d_in[18];
    const float* wq  = (const float*)d_in[19]; const float* wqb = (const float*)d_in[20];
    const float* wk  = (const float*)d_in[21]; const float* wkb = (const float*)d_in[22];
    const float* wv  = (const float*)d_in[23]; const float* wvb = (const float*)d_in[24];
    const float* wow = (const float*)d_in[25]; const float* wob = (const float*)d_in[26];
    const float* rzw = (const float*)d_in[27]; const float* rzb = (const float*)d_in[28];
    const float* dw1 = (const float*)d_in[29]; const float* db1 = (const float*)d_in[30];
    const float* dw2 = (const float*)d_in[31]; const float* db2 = (const float*)d_in[32];
    const float* dw3 = (const float*)d_in[33]; const float* db3 = (const float*)d_in[34];
    const float* proj= (const float*)d_in[35];

    float* wsf = (float*)d_ws;
    unsigned short* usw = (unsigned short*)d_ws;
    float* out = (float*)d_out;

    unsigned short* A_pool = usw;                 // pool at ush offset 0 (dead after conv3m)
    float* x_ctx  = wsf + OFF_XCTX;
    float* x_qry  = wsf + OFF_XQRY;
    float* xcat   = wsf + OFF_XCAT;
    float* h1     = wsf + OFF_H1;
    float* h2     = wsf + OFF_H2;
    float* rs     = wsf + OFF_RS;
    float* v_all  = wsf + OFF_VA;
    float* rep    = wsf + OFF_REP;
    float* xz     = wsf + OFF_XZ;
    float* dh1    = wsf + OFF_DH1;
    float* dh2    = wsf + OFF_DH2;
    float* xd_q   = wsf + OFF_XDQ;
    float* xd_k   = wsf + OFF_XDK;
    float* enc_t  = wsf + OFF_ENCT;
    float* rep_t  = wsf + OFF_REPT;
    float* pA     = wsf + OFF_PA;
    float* dqv    = wsf + OFF_MD;
    unsigned* mqe = (unsigned*)(wsf + OFF_MD + 4096);
    float* dkv    = wsf + OFF_MD + 8192;
    unsigned* mke = (unsigned*)(wsf + OFF_MD + 12288);
    unsigned* mdw = (unsigned*)(wsf + OFF_MD);
    unsigned short* Aw  = (unsigned short*)(wsf + OFF_AW);
    unsigned short* Aw3 = (unsigned short*)(wsf + OFF_AW3);
    unsigned short* Aw1 = (unsigned short*)(wsf + OFF_AW1);

    unsigned short* Wqkv = usw + U_WQH;
    unsigned short* Ph  = usw + U_PH;  unsigned short* Pl  = usw + U_PL;
    unsigned short* XCh = usw + U_XCH; unsigned short* XCl = usw + U_XCL;
    unsigned short* RSh = usw + U_RSH; unsigned short* RSl = usw + U_RSL;
    unsigned short* C3h = usw + U_C3H; unsigned short* C3l = usw + U_C3L;
    unsigned short* Qh  = usw + U_QH;  unsigned short* Ql  = usw + U_QL;
    unsigned short* Kh  = usw + U_KH;  unsigned short* Kl  = usw + U_KL;
    unsigned short* ELh = usw + U_ELH; unsigned short* ELl = usw + U_ELL;
    unsigned short* WOh = usw + U_WOH; unsigned short* WOl = usw + U_WOL;
    unsigned short* REPh= usw + U_REPH;unsigned short* REPl= usw + U_REPL;

    // 1. prep A: Aw/Aw1/Aw3/EL (non-pool regions only)
    k_wprepA<<<4442, 256, 0, stream>>>(c2w, c1w, c3w, elw, Aw, Aw1, Aw3, ELh, ELl);

    // 2-3. encoder convs
    k_conv12m<<<dim3(8, 1024), 256, 0, stream>>>(train, test, c1b, Aw, Aw1, c2b, A_pool);
    k_conv3m<<<1024, 512, 0, stream>>>(A_pool, Aw3, c3b, C3h, C3l);

    // 4. prep B: P (padded 1536 rows) + WQKV planes into the dead pool region
    k_wprepB<<<7680, 256, 0, stream>>>(proj, wq, wk, wv, Ph, Pl, Wqkv);

    // 5-6. enc linear: 128-tile split-K=16 into temps, then fused reduce
    //      (+bias, planes, xcat copy) + label embed + wo planes + MD zero
    mgemm128s<<<dim3(2, 8, 16), 256, 0, stream>>>(
        C3h, C3l, ELh, ELl, enc_t, 1024, 256, 4096, 256, 262144, 256);
    k_red_enc<<<3249, 256, 0, stream>>>(enc_t, elb, x_ctx, XCh, XCl, xcat,
                                        label, tyw, tyb, wow, WOh, WOl, mdw);

    // 7-9. er MLP -> rs (last layer also emits RS planes)
    gemm_k<32,32,32,1,false,false><<<dim3(8, 16), 256, 0, stream>>>(xcat, ew1, eb1, h1, 512, 256, 320, 256, nullptr, nullptr);
    gemm_k<32,32,32,1,false,false><<<dim3(8, 16), 256, 0, stream>>>(h1, ew2, eb2, h2, 512, 256, 256, 256, nullptr, nullptr);
    gemm_k<32,32,32,0,false,true ><<<dim3(8, 16), 256, 0, stream>>>(h2, ew3, eb3, rs, 512, 256, 256, 256, RSh, RSl);

    // 10. q/k/v projections in one launch (+fused diag for Q/K)
    k_qkv<<<dim3(4, 8, 24), 256, 0, stream>>>(XCh, XCl, RSh, RSl, Wqkv,
                                              wqb, wkb, wvb, Qh, Ql, Kh, Kl,
                                              v_all, dqv, dkv);

    // 11. performer features (z=2), 128x128-tile GEMM + fused row/tile max
    mgemm128<<<dim3(12, 32, 2), 256, 0, stream>>>(
        Qh, Ql, Ph, Pl, xd_q,
        4096, F_FEAT, 256, F_FEAT, DN, 2097152, 5812224, mqe, mke);

    // 12-13. attention: feature-split QK^T (fused exp) -> partial A; reduce+PV
    k_attn1<<<dim3(NSPLIT, 128), 256, 0, stream>>>(xd_q, xd_k, dqv, mqe, dkv, mke, pA);
    k_attn2<<<dim3(4, 128), 256, 0, stream>>>(pA, v_all, REPh, REPl);

    // 14-15. rep = rep_in @ wo^T + b : split-K=8 temps + fused reduce + xz copy
    mgemm<3><<<dim3(4, 8, 8), 256, 0, stream>>>(
        REPh, REPl, WOh, WOl, nullptr, rep_t, nullptr, nullptr,
        512, 256, 2048, 256, 1.f, 0, 0, 0, 131072, 256);
    k_red_rep<<<1024, 256, 0, stream>>>(rep_t, wob, rep, x_qry, xz);

    // 16. xz cols 256..383 = rep @ rz^T + b
    gemm_k<32,32,32,0,false,false><<<dim3(4, 16), 256, 0, stream>>>(rep, rzw, rzb, xz + 256, 512, 128, 256, 384, nullptr, nullptr);

    // 17-19. decoder (k_fin folded into the last GEMM)
    gemm_k<32,32,32,1,false,false><<<dim3(4, 16), 256, 0, stream>>>(xz, dw1, db1, dh1, 512, 100, 384, 100, nullptr, nullptr);
    gemm_k<32,32,32,1,false,false><<<dim3(4, 16), 256, 0, stream>>>(dh1, dw2, db2, dh2, 512, 100, 100, 100, nullptr, nullptr);
    gemm_k<32,32,32,2,true ,false><<<dim3(1, 16), 256, 0, stream>>>(dh2, dw3, db3, out, 512, 2, 100, 2, nullptr, nullptr);
}